// Round 4
// baseline (1023.974 us; speedup 1.0000x reference)
//
#include <hip/hip_runtime.h>
#include <hip/hip_bf16.h>

typedef __hip_bfloat16 bf16;
typedef __attribute__((ext_vector_type(8))) short bf16x8;
typedef __attribute__((ext_vector_type(4))) float f32x4;

#define B_ 8
#define S_ 512
#define D_ 1024
#define H_ 16
#define NEGV -9.0e15f
#define WSL 1048576ull

__device__ __forceinline__ float bf2f(bf16 x) { return __bfloat162float(x); }
__device__ __forceinline__ float us2f(unsigned short u) {
  union { unsigned int i; float f; } c; c.i = ((unsigned int)u) << 16; return c.f;
}
__device__ __forceinline__ unsigned short f2us(float f) {
  bf16 h = __float2bfloat16(f);
  unsigned short u; __builtin_memcpy(&u, &h, 2); return u;
}
__device__ __forceinline__ float ldx(const void* p, size_t i, int isbf) {
  return isbf ? bf2f(((const bf16*)p)[i]) : ((const float*)p)[i];
}
struct F4 { float x, y, z, w; };
__device__ __forceinline__ F4 ld4(const void* p, size_t i, int isbf) {
  F4 r;
  if (isbf) {
    ushort4 u = *(const ushort4*)((const bf16*)p + i);
    r.x = us2f(u.x); r.y = us2f(u.y); r.z = us2f(u.z); r.w = us2f(u.w);
  } else {
    float4 d = *(const float4*)((const float*)p + i);
    r.x = d.x; r.y = d.y; r.z = d.z; r.w = d.w;
  }
  return r;
}
// 8 consecutive elements as bf16x8; converts if source is f32
__device__ __forceinline__ bf16x8 ld8bf(const void* p, size_t i, int isbf) {
  if (isbf) return *(const bf16x8*)((const bf16*)p + i);
  float4 a = *(const float4*)((const float*)p + i);
  float4 b = *(const float4*)((const float*)p + i + 4);
  bf16x8 r;
  r[0] = (short)f2us(a.x); r[1] = (short)f2us(a.y);
  r[2] = (short)f2us(a.z); r[3] = (short)f2us(a.w);
  r[4] = (short)f2us(b.x); r[5] = (short)f2us(b.y);
  r[6] = (short)f2us(b.z); r[7] = (short)f2us(b.w);
  return r;
}
__device__ __forceinline__ f32x4 mfma_bf16(bf16x8 a, bf16x8 b, f32x4 c) {
  return __builtin_amdgcn_mfma_f32_16x16x32_bf16(a, b, c, 0, 0, 0);
}

// Dtype detector (round-3 verified: picks f32 on this harness).
__global__ void detect_k(const void* __restrict__ w, int* __restrict__ flag)
{
  if (threadIdx.x == 0 && blockIdx.x == 0) {
    const unsigned short* u = (const unsigned short*)w;
    int sane = 0;
    for (int i = 0; i < 1024; i += 2) {
      float a = fabsf(us2f(u[i]));
      if (a == 0.f || (a > 9.5e-7f && a < 8.f)) sane++;
    }
    *flag = (sane > 256) ? 1 : 0;
  }
}

// ---------------------------------------------------------------------------
// ALL 13 weight transposes in one launch. slot = blockIdx.x>>8:
// 0..2 = Wq,Wk,Wv; 3..7 = gate_w srcs {0,5,1,2,3}; 8..12 = sub_w rows c.
// out[n][k] (bf16, 1024x1024) <- W[k][n] (per dflag dtype).
// ---------------------------------------------------------------------------
__global__ __launch_bounds__(256)
void wtrans_all_k(const void* __restrict__ Wq, const void* __restrict__ Wk,
                  const void* __restrict__ Wv, const void* __restrict__ gate_w,
                  const void* __restrict__ sub_w, bf16* __restrict__ Wt,
                  const int* __restrict__ dflag)
{
  const int isbf = *dflag;
  const int slot = blockIdx.x >> 8;
  const int blk = blockIdx.x & 255;
  const int gsrc[5] = {0, 5, 1, 2, 3};
  const void* W;
  size_t woff;
  if (slot < 3)      { W = slot == 0 ? Wq : (slot == 1 ? Wk : Wv); woff = 0; }
  else if (slot < 8) { W = gate_w; woff = (size_t)gsrc[slot - 3] * WSL; }
  else               { W = sub_w;  woff = (size_t)(slot - 8) * WSL; }
  bf16* out = Wt + (size_t)slot * WSL;

  __shared__ float t[64][68];
  const int tid = threadIdx.x;
  const int nt = blk & 15, kt = blk >> 4;
  {
    int r = tid >> 4, c4 = (tid & 15) * 4;
    #pragma unroll
    for (int i = 0; i < 4; i++) {
      int rr = r + i * 16;
      F4 v = ld4(W, woff + (size_t)(kt * 64 + rr) * 1024 + nt * 64 + c4, isbf);
      *(float4*)&t[rr][c4] = make_float4(v.x, v.y, v.z, v.w);
    }
  }
  __syncthreads();
  {
    int n = tid >> 4, k4 = (tid & 15) * 4;
    #pragma unroll
    for (int i = 0; i < 4; i++) {
      int nn = n + i * 16;
      ushort4 u;
      u.x = f2us(t[k4 + 0][nn]); u.y = f2us(t[k4 + 1][nn]);
      u.z = f2us(t[k4 + 2][nn]); u.w = f2us(t[k4 + 3][nn]);
      *(ushort4*)(out + (size_t)(nt * 64 + nn) * 1024 + kt * 64 + k4) = u;
    }
  }
}

// ---------------------------------------------------------------------------
// QKV projections, z-batched (z=0:q scaled, z=1:k, z=2:v transposed).
// 128x128 tile, BK=64, XOR-swizzled LDS (verified core).
// ---------------------------------------------------------------------------
__global__ __launch_bounds__(256)
void qkv_gemm_k(const void* __restrict__ Aq, const void* __restrict__ Ak,
                const void* __restrict__ Av, const bf16* __restrict__ Wt,
                const void* __restrict__ bqp, const void* __restrict__ bkp,
                const void* __restrict__ bvp, bf16* __restrict__ qbf,
                bf16* __restrict__ kbf, bf16* __restrict__ vtb,
                const int* __restrict__ dflag)
{
  const int isbf = *dflag;
  const int z = blockIdx.z;
  const void* A = z == 0 ? Aq : (z == 1 ? Ak : Av);
  const void* bias = z == 0 ? bqp : (z == 1 ? bkp : bvp);
  bf16* outB = z == 0 ? qbf : (z == 1 ? kbf : vtb);
  const bf16* Wz = Wt + (size_t)z * WSL;
  const float scale = z == 0 ? 0.125f : 1.0f;
  const int vtrans = (z == 2);

  __shared__ short As[128 * 64];
  __shared__ short Bs[128 * 64];
  const int tid = threadIdx.x;
  const int w = tid >> 6, ln = tid & 63;
  const int ln15 = ln & 15, quad = ln >> 4;
  const int wm = (w & 1) * 64, wn = (w >> 1) * 64;
  const int bm = blockIdx.x * 128, bn = blockIdx.y * 128;
  const int r0 = tid >> 3, g0 = tid & 7;
  f32x4 acc[4][4];
  #pragma unroll
  for (int mt = 0; mt < 4; mt++)
    #pragma unroll
    for (int nt = 0; nt < 4; nt++) acc[mt][nt] = (f32x4)(0.0f);

  for (int k0 = 0; k0 < 1024; k0 += 64) {
    #pragma unroll
    for (int i = 0; i < 4; i++) {
      int r = r0 + i * 32;
      int gsw = ((g0 ^ (r & 7)) * 8);
      bf16x8 av = ld8bf(A, (size_t)(bm + r) * 1024 + k0 + g0 * 8, isbf);
      *(bf16x8*)&As[r * 64 + gsw] = av;
      bf16x8 bv = *(const bf16x8*)(Wz + (size_t)(bn + r) * 1024 + k0 + g0 * 8);
      *(bf16x8*)&Bs[r * 64 + gsw] = bv;
    }
    __syncthreads();
    #pragma unroll
    for (int s = 0; s < 2; s++) {
      bf16x8 af[4], bfr[4];
      #pragma unroll
      for (int t = 0; t < 4; t++) {
        int ra = wm + t * 16 + ln15;
        af[t] = *(bf16x8*)&As[ra * 64 + (((s * 4 + quad) ^ (ra & 7)) * 8)];
        int rb = wn + t * 16 + ln15;
        bfr[t] = *(bf16x8*)&Bs[rb * 64 + (((s * 4 + quad) ^ (rb & 7)) * 8)];
      }
      #pragma unroll
      for (int mt = 0; mt < 4; mt++)
        #pragma unroll
        for (int nt = 0; nt < 4; nt++)
          acc[mt][nt] = mfma_bf16(af[mt], bfr[nt], acc[mt][nt]);
    }
    __syncthreads();
  }

  #pragma unroll
  for (int nt = 0; nt < 4; nt++) {
    int col = bn + wn + nt * 16 + ln15;
    float bv = ldx(bias, col, isbf);
    #pragma unroll
    for (int mt = 0; mt < 4; mt++) {
      #pragma unroll
      for (int r = 0; r < 4; r++) {
        int row = bm + wm + mt * 16 + quad * 4 + r;
        float v = (acc[mt][nt][r] + bv) * scale;
        int bb = row >> 9, s = row & 511;
        int h = col >> 6, d0 = col & 63;
        size_t o = vtrans ? (((size_t)(bb * 16 + h) * 64 + d0) * 512 + s)
                          : (((size_t)(bb * 16 + h) * 512 + s) * 64 + d0);
        outB[o] = __float2bfloat16(v);
      }
    }
  }
}

// ---------------------------------------------------------------------------
// Gate GEMMs, z-batched over 5 views (main + 4 edge).
// gated_z = sigmoid(ctx_z @ gate_w_z + gate_b_z) * ctx_z
// ---------------------------------------------------------------------------
__global__ __launch_bounds__(256)
void gate_gemm_k(const bf16* __restrict__ ctx5, const bf16* __restrict__ Wt,
                 const void* __restrict__ gate_b, bf16* __restrict__ gated5,
                 const int* __restrict__ dflag)
{
  const int isbf = *dflag;
  const int z = blockIdx.z;
  const int gsel[5] = {0, 5, 1, 2, 3};
  const bf16* A = ctx5 + (size_t)z * 4194304;
  bf16* outB = gated5 + (size_t)z * 4194304;
  const bf16* Wz = Wt + (size_t)(3 + z) * WSL;
  const size_t boff = (size_t)gsel[z] * 1024;

  __shared__ short As[128 * 64];
  __shared__ short Bs[128 * 64];
  const int tid = threadIdx.x;
  const int w = tid >> 6, ln = tid & 63;
  const int ln15 = ln & 15, quad = ln >> 4;
  const int wm = (w & 1) * 64, wn = (w >> 1) * 64;
  const int bm = blockIdx.x * 128, bn = blockIdx.y * 128;
  const int r0 = tid >> 3, g0 = tid & 7;
  f32x4 acc[4][4];
  #pragma unroll
  for (int mt = 0; mt < 4; mt++)
    #pragma unroll
    for (int nt = 0; nt < 4; nt++) acc[mt][nt] = (f32x4)(0.0f);

  for (int k0 = 0; k0 < 1024; k0 += 64) {
    #pragma unroll
    for (int i = 0; i < 4; i++) {
      int r = r0 + i * 32;
      int gsw = ((g0 ^ (r & 7)) * 8);
      bf16x8 av = *(const bf16x8*)(A + (size_t)(bm + r) * 1024 + k0 + g0 * 8);
      *(bf16x8*)&As[r * 64 + gsw] = av;
      bf16x8 bv = *(const bf16x8*)(Wz + (size_t)(bn + r) * 1024 + k0 + g0 * 8);
      *(bf16x8*)&Bs[r * 64 + gsw] = bv;
    }
    __syncthreads();
    #pragma unroll
    for (int s = 0; s < 2; s++) {
      bf16x8 af[4], bfr[4];
      #pragma unroll
      for (int t = 0; t < 4; t++) {
        int ra = wm + t * 16 + ln15;
        af[t] = *(bf16x8*)&As[ra * 64 + (((s * 4 + quad) ^ (ra & 7)) * 8)];
        int rb = wn + t * 16 + ln15;
        bfr[t] = *(bf16x8*)&Bs[rb * 64 + (((s * 4 + quad) ^ (rb & 7)) * 8)];
      }
      #pragma unroll
      for (int mt = 0; mt < 4; mt++)
        #pragma unroll
        for (int nt = 0; nt < 4; nt++)
          acc[mt][nt] = mfma_bf16(af[mt], bfr[nt], acc[mt][nt]);
    }
    __syncthreads();
  }

  #pragma unroll
  for (int nt = 0; nt < 4; nt++) {
    int col = bn + wn + nt * 16 + ln15;
    float bv = ldx(gate_b, boff + col, isbf);
    #pragma unroll
    for (int mt = 0; mt < 4; mt++) {
      #pragma unroll
      for (int r = 0; r < 4; r++) {
        int row = bm + wm + mt * 16 + quad * 4 + r;
        float v = acc[mt][nt][r] + bv;
        float x = bf2f(A[(size_t)row * 1024 + col]);
        outB[(size_t)row * 1024 + col] = __float2bfloat16(x / (1.f + __expf(-v)));
      }
    }
  }
}

// ---------------------------------------------------------------------------
// Final sub GEMM: out = [gated_0|...|gated_4](4096x5120) @ sub_w(5120x1024)
// + sub_b, written straight to d_out (dtype-aware).
// ---------------------------------------------------------------------------
__global__ __launch_bounds__(256)
void sub_gemm_k(const bf16* __restrict__ gated5, const bf16* __restrict__ Wt,
                const void* __restrict__ sub_b, void* __restrict__ dout,
                const int* __restrict__ dflag)
{
  const int isbf = *dflag;
  __shared__ short As[128 * 64];
  __shared__ short Bs[128 * 64];
  const int tid = threadIdx.x;
  const int w = tid >> 6, ln = tid & 63;
  const int ln15 = ln & 15, quad = ln >> 4;
  const int wm = (w & 1) * 64, wn = (w >> 1) * 64;
  const int bm = blockIdx.x * 128, bn = blockIdx.y * 128;
  const int r0 = tid >> 3, g0 = tid & 7;
  f32x4 acc[4][4];
  #pragma unroll
  for (int mt = 0; mt < 4; mt++)
    #pragma unroll
    for (int nt = 0; nt < 4; nt++) acc[mt][nt] = (f32x4)(0.0f);

  for (int k0 = 0; k0 < 5120; k0 += 64) {
    const int slot = k0 >> 10, kk = k0 & 1023;
    const bf16* Ab = gated5 + (size_t)slot * 4194304;
    const bf16* Wz = Wt + (size_t)(8 + slot) * WSL;
    #pragma unroll
    for (int i = 0; i < 4; i++) {
      int r = r0 + i * 32;
      int gsw = ((g0 ^ (r & 7)) * 8);
      bf16x8 av = *(const bf16x8*)(Ab + (size_t)(bm + r) * 1024 + kk + g0 * 8);
      *(bf16x8*)&As[r * 64 + gsw] = av;
      bf16x8 bv = *(const bf16x8*)(Wz + (size_t)(bn + r) * 1024 + kk + g0 * 8);
      *(bf16x8*)&Bs[r * 64 + gsw] = bv;
    }
    __syncthreads();
    #pragma unroll
    for (int s = 0; s < 2; s++) {
      bf16x8 af[4], bfr[4];
      #pragma unroll
      for (int t = 0; t < 4; t++) {
        int ra = wm + t * 16 + ln15;
        af[t] = *(bf16x8*)&As[ra * 64 + (((s * 4 + quad) ^ (ra & 7)) * 8)];
        int rb = wn + t * 16 + ln15;
        bfr[t] = *(bf16x8*)&Bs[rb * 64 + (((s * 4 + quad) ^ (rb & 7)) * 8)];
      }
      #pragma unroll
      for (int mt = 0; mt < 4; mt++)
        #pragma unroll
        for (int nt = 0; nt < 4; nt++)
          acc[mt][nt] = mfma_bf16(af[mt], bfr[nt], acc[mt][nt]);
    }
    __syncthreads();
  }

  #pragma unroll
  for (int nt = 0; nt < 4; nt++) {
    int col = bn + wn + nt * 16 + ln15;
    float bv = ldx(sub_b, col, isbf);
    #pragma unroll
    for (int mt = 0; mt < 4; mt++) {
      #pragma unroll
      for (int r = 0; r < 4; r++) {
        int row = bm + wm + mt * 16 + quad * 4 + r;
        float v = acc[mt][nt][r] + bv;
        size_t o = (size_t)row * 1024 + col;
        if (isbf) ((bf16*)dout)[o] = __float2bfloat16(v);
        else      ((float*)dout)[o] = v;
      }
    }
  }
}

// ---------------------------------------------------------------------------
// G[row][r] = q_row . rel_emb[r] (bf16 q). One wave per row.
// ---------------------------------------------------------------------------
__global__ __launch_bounds__(256)
void qrel_k(const bf16* __restrict__ qbf, const void* __restrict__ rel_emb,
            float* __restrict__ G, const int* __restrict__ dflag)
{
  const int isbf = *dflag;
  __shared__ float rel[33][65];
  __shared__ float qw[4][64];
  const int tid = threadIdx.x;
  for (int i = tid; i < 33 * 64; i += 256)
    rel[i >> 6][i & 63] = ldx(rel_emb, i, isbf);
  const int wv = tid >> 6, lane = tid & 63;
  const size_t row = (size_t)blockIdx.x * 4 + wv;
  qw[wv][lane] = bf2f(qbf[row * 64 + lane]);
  __syncthreads();
  if (lane < 33) {
    float s = 0.f;
    #pragma unroll
    for (int d = 0; d < 64; d++) s += qw[wv][d] * rel[lane][d];
    G[row * 33 + lane] = s;
  }
}

// ---------------------------------------------------------------------------
// Fully fused main view v2: barrier-free QK^T (Q/K fragments DIRECT from
// global — kbf [bh][s][64] rows are fragment-ready, same verified pattern as
// V in PV), softmax in-register, per-wave-private P (16 rows x 256 k half,
// 8KB/wave), k processed in 2 halves => LDS 32K P + 8.4K G + 8.4K rel = 49.7K.
// PV + diagonal-band + top_attn all wave-local, partitioned by k-half.
// rel_emb staged in LDS (fixes round-3's 132 serial scalar global loads).
// Swizzle algebra identical to round-3 (verified), in wave-local coords.
// ---------------------------------------------------------------------------
__global__ __launch_bounds__(256)
void score_fused_k(const bf16* __restrict__ qbf, const bf16* __restrict__ kbf,
                   const float* __restrict__ G, const bf16* __restrict__ vt,
                   const void* __restrict__ rel_emb, bf16* __restrict__ ctx,
                   void* __restrict__ dout, const int* __restrict__ dflag)
{
  __shared__ short Pw[4][16 * 256];   // 32 KB, per-wave private
  __shared__ float gbuf[64 * 33];     // 8448 B
  __shared__ float relbuf[33 * 64];   // 8448 B
  const int tid = threadIdx.x;
  const int w = tid >> 6, ln = tid & 63;
  const int ln15 = ln & 15, quad = ln >> 4;
  const int bh = blockIdx.x, qt = blockIdx.y;
  const size_t qrow0 = (size_t)bh * 512 + qt * 64;
  const int isbf = *dflag;

  // stage G (this block's 64 rows) + rel into LDS (one barrier, after QK)
  for (int i = tid; i < 64 * 33; i += 256) {
    int r = i / 33, c = i - r * 33;
    gbuf[i] = G[(qrow0 + r) * 33 + c];
  }
  for (int i = tid; i < 33 * 64; i += 256)
    relbuf[i] = ldx(rel_emb, i, isbf);

  // ---- QK^T: fragments straight from global, zero barriers ----
  const bf16* qrow = qbf + (qrow0 + w * 16 + ln15) * 64;
  bf16x8 af0 = *(const bf16x8*)(qrow + quad * 8);
  bf16x8 af1 = *(const bf16x8*)(qrow + 32 + quad * 8);
  const bf16* kb = kbf + (size_t)bh * 512 * 64;
  f32x4 acc[32];
  #pragma unroll
  for (int t = 0; t < 32; t++) acc[t] = (f32x4)(0.0f);
  #pragma unroll 8
  for (int t = 0; t < 32; t++) {
    const bf16* kr = kb + (size_t)(t * 16 + ln15) * 64 + quad * 8;
    bf16x8 b0 = *(const bf16x8*)kr;
    bf16x8 b1 = *(const bf16x8*)(kr + 32);
    acc[t] = mfma_bf16(af0, b0, acc[t]);
    acc[t] = mfma_bf16(af1, b1, acc[t]);
  }
  __syncthreads();   // gbuf/relbuf now valid

  // ---- rel bias + softmax (identical math to verified score_k) ----
  const int qg = qt * 64 + w * 16 + quad * 4;
  const int rowl0 = w * 16 + quad * 4;
  float mx[4], ssum[4], sle[4], sge[4];
  #pragma unroll
  for (int r = 0; r < 4; r++) mx[r] = -3.0e38f;
  for (int t = 0; t < 32; t++) {
    int k = t * 16 + ln15;
    #pragma unroll
    for (int r = 0; r < 4; r++) {
      int delta = k - (qg + r);
      int bkt = delta < -16 ? 0 : (delta > 16 ? 32 : delta + 16);
      float s = acc[t][r] + gbuf[(rowl0 + r) * 33 + bkt];
      acc[t][r] = s;
      mx[r] = fmaxf(mx[r], s);
    }
  }
  #pragma unroll
  for (int r = 0; r < 4; r++) {
    float m = mx[r];
    #pragma unroll
    for (int off = 1; off < 16; off <<= 1) m = fmaxf(m, __shfl_xor(m, off));
    mx[r] = m;
    ssum[r] = 0.f; sle[r] = 0.f; sge[r] = 0.f;
  }
  for (int t = 0; t < 32; t++) {
    int k = t * 16 + ln15;
    #pragma unroll
    for (int r = 0; r < 4; r++) {
      float p = __expf(acc[t][r] - mx[r]);
      acc[t][r] = p;
      ssum[r] += p;
      int delta = k - (qg + r);
      if (delta <= -16) sle[r] += p;
      if (delta >= 16) sge[r] += p;
    }
  }
  #pragma unroll
  for (int r = 0; r < 4; r++) {
    #pragma unroll
    for (int off = 1; off < 16; off <<= 1) {
      ssum[r] += __shfl_xor(ssum[r], off);
      sle[r] += __shfl_xor(sle[r], off);
      sge[r] += __shfl_xor(sge[r], off);
    }
  }
  float inv[4];
  #pragma unroll
  for (int r = 0; r < 4; r++) inv[r] = 1.f / ssum[r];

  // ---- per-wave P (16 rows), k in two 256-halves; PV + band + top_attn ----
  short* Pm = Pw[w];
  const bf16* vb = vt + (size_t)bh * 64 * 512;
  const int toph = ((bh & 15) == 0);
  const int bg = bh >> 4;
  f32x4 pacc[4];
  #pragma unroll
  for (int nt = 0; nt < 4; nt++) pacc[nt] = (f32x4)(0.0f);

  #pragma unroll
  for (int h = 0; h < 2; h++) {
    // store this half's P (normalized bf16), swizzled 16B groups: store-free
    #pragma unroll
    for (int t2 = 0; t2 < 16; t2++) {
      int gg = t2 * 2 + (ln15 >> 3);        // logical group = col>>3
      int slot = gg ^ (quad << 1);          // ((rowL>>2)&3)==quad for rowL=quad*4+r
      #pragma unroll
      for (int r = 0; r < 4; r++) {
        int rowL = quad * 4 + r;
        Pm[rowL * 256 + slot * 8 + (ln15 & 7)] =
            (short)f2us(acc[h * 16 + t2][r] * inv[r]);
      }
    }
    __syncthreads();

    // top_attn (head-0 blocks only): wave writes its own 16 rows, this half
    if (toph) {
      for (int i = ln; i < 16 * 32; i += 64) {
        int rowL = i >> 5, gg = i & 31;
        int slot = gg ^ (((rowL >> 2) & 3) << 1);
        bf16x8 u = *(bf16x8*)&Pm[rowL * 256 + slot * 8];
        size_t o = (size_t)4194304 + (size_t)bg * 262144 +
                   (size_t)(qt * 64 + w * 16 + rowL) * 512 + h * 256 + gg * 8;
        if (isbf) {
          *(bf16x8*)((bf16*)dout + o) = u;
        } else {
          float4 f0 = make_float4(us2f((unsigned short)u[0]), us2f((unsigned short)u[1]),
                                  us2f((unsigned short)u[2]), us2f((unsigned short)u[3]));
          float4 f1 = make_float4(us2f((unsigned short)u[4]), us2f((unsigned short)u[5]),
                                  us2f((unsigned short)u[6]), us2f((unsigned short)u[7]));
          *(float4*)((float*)dout + o) = f0;
          *(float4*)((float*)dout + o + 4) = f1;
        }
      }
    }

    // PV over this half: A from Pm (own rows), V fragments from global
    {
      const int rsw = ((ln15 >> 2) & 3) << 1;
      #pragma unroll
      for (int kk = 0; kk < 8; kk++) {
        int gg = kk * 4 + quad;
        bf16x8 a = *(bf16x8*)&Pm[ln15 * 256 + ((gg ^ rsw) * 8)];
        int k0 = h * 256 + kk * 32;
        #pragma unroll
        for (int nt = 0; nt < 4; nt++) {
          bf16x8 b = *(const bf16x8*)(vb + (size_t)(nt * 16 + ln15) * 512 + k0 + quad * 8);
          pacc[nt] = mfma_bf16(a, b, pacc[nt]);
        }
      }
    }

    // diagonal band of arel@rel for k in this half (rel from LDS)
    for (int rr = 1; rr < 32; rr++) {
      float av[4];
      #pragma unroll
      for (int r = 0; r < 4; r++) {
        int k = qg + r + rr - 16;
        av[r] = 0.f;
        if (k >= h * 256 && k < (h + 1) * 256) {
          int kl = k - h * 256;
          int rowL = quad * 4 + r;
          int slot = (kl >> 3) ^ (quad << 1);
          av[r] = us2f((unsigned short)Pm[rowL * 256 + slot * 8 + (kl & 7)]);
        }
      }
      #pragma unroll
      for (int nt = 0; nt < 4; nt++) {
        float relv = relbuf[rr * 64 + nt * 16 + ln15];
        #pragma unroll
        for (int r = 0; r < 4; r++) pacc[nt][r] += av[r] * relv;
      }
    }
    __syncthreads();   // before overwriting Pm with next half
  }

  // sle/sge terms (buckets 0 and 32)
  #pragma unroll
  for (int nt = 0; nt < 4; nt++) {
    float r0v = relbuf[nt * 16 + ln15];
    float r32v = relbuf[32 * 64 + nt * 16 + ln15];
    #pragma unroll
    for (int r = 0; r < 4; r++)
      pacc[nt][r] += sle[r] * inv[r] * r0v + sge[r] * inv[r] * r32v;
  }

  // ctx write (slot 0 layout [bl*512+s][1024])
  const int bl = bh >> 4, head = bh & 15;
  #pragma unroll
  for (int r = 0; r < 4; r++) {
    int s = qt * 64 + rowl0 + r;
    #pragma unroll
    for (int nt = 0; nt < 4; nt++)
      ctx[((size_t)bl * 512 + s) * 1024 + head * 64 + nt * 16 + ln15] =
          __float2bfloat16(pacc[nt][r]);
  }
}

// ---------------------------------------------------------------------------
// Edge h-projections, z-batched over 4 views (blockIdx.y).
// ---------------------------------------------------------------------------
__global__ __launch_bounds__(256)
void hv_k(const bf16* __restrict__ vt, const void* __restrict__ att_w,
          const void* __restrict__ att_b, float* __restrict__ h0,
          float* __restrict__ h1, const int* __restrict__ dflag)
{
  const int i0s[4] = {6, 0, 2, 4};
  const int i1s[4] = {7, 1, 3, 5};
  const int z = blockIdx.y;
  const int i0 = i0s[z], i1 = i1s[z];
  __shared__ float w0[64], w1[64];
  const int tid = threadIdx.x;
  const int bh = blockIdx.x;
  const int isbf = *dflag;
  if (tid < 64) {
    w0[tid] = ldx(att_w, i0 * 64 + tid, isbf);
    w1[tid] = ldx(att_w, i1 * 64 + tid, isbf);
  }
  __syncthreads();
  const bf16* vb = vt + (size_t)bh * 64 * 512 + tid * 2;
  float a00 = 0, a01 = 0, a10 = 0, a11 = 0;
  for (int d = 0; d < 64; d++) {
    ushort2 u = *(const ushort2*)(vb + (size_t)d * 512);
    float f0 = us2f(u.x), f1 = us2f(u.y);
    a00 += f0 * w0[d]; a10 += f1 * w0[d];
    a01 += f0 * w1[d]; a11 += f1 * w1[d];
  }
  float b0 = ldx(att_b, i0, isbf), b1 = ldx(att_b, i1, isbf);
  float* p0 = h0 + (size_t)z * 65536 + (size_t)bh * 512 + tid * 2;
  float* p1 = h1 + (size_t)z * 65536 + (size_t)bh * 512 + tid * 2;
  p0[0] = a00 + b0; p0[1] = a10 + b0;
  p1[0] = a01 + b1; p1[1] = a11 + b1;
}

// ---------------------------------------------------------------------------
// Fused edge view, z-batched over the 4 views (blockIdx.z). Verified round-2
// structure: 32 q-rows/block, 32KB LDS P, softmax per wave-row, PV with V
// fragments from global. Writes ctx5 slot (1+view).
// ---------------------------------------------------------------------------
__global__ __launch_bounds__(256)
void edge_fused_k(const float* __restrict__ h0, const float* __restrict__ h1,
                  const int* __restrict__ grh, const bf16* __restrict__ vt,
                  bf16* __restrict__ ctx5)
{
  __shared__ short P[32 * 512];   // 32 KB
  const int tid = threadIdx.x;
  const int w = tid >> 6, ln = tid & 63;
  const int ln15 = ln & 15, quad = ln >> 4;
  const int bh = blockIdx.x, qt = blockIdx.y, view = blockIdx.z;
  const int bl = bh >> 4;
  bf16* ctx = ctx5 + (size_t)(1 + view) * 4194304;

  // ---- phase 1: rows w*8 .. w*8+7, one full wave per row ----
  const int kb = ln * 8;
  {
    const float* hjp = h1 + (size_t)view * 65536 + (size_t)bh * 512 + kb;
    float4 hA = *(const float4*)hjp;
    float4 hB = *(const float4*)(hjp + 4);
    float hjv[8] = {hA.x, hA.y, hA.z, hA.w, hB.x, hB.y, hB.z, hB.w};
    const float* h0b = h0 + (size_t)view * 65536 + (size_t)bh * 512 + qt * 32 + w * 8;
    const int* grow = grh + ((size_t)bl * 512 + qt * 32 + w * 8) * 512 + kb;

    int4 ga = *(const int4*)grow;
    int4 gb = *(const int4*)(grow + 4);
    #pragma unroll 2
    for (int rr = 0; rr < 8; rr++) {
      int rn = rr < 7 ? rr + 1 : rr;
      const int* gn = grow + (size_t)rn * 512;
      int4 gan = *(const int4*)gn;
      int4 gbn = *(const int4*)(gn + 4);
      int r = w * 8 + rr;              // local row in P, 0..31
      int qi = qt * 32 + r;            // global q index, 0..511
      float hi = h0b[rr];
      int g[8] = {ga.x, ga.y, ga.z, ga.w, gb.x, gb.y, gb.z, gb.w};
      float e[8];
      float m = -3.0e38f;
      #pragma unroll
      for (int j = 0; j < 8; j++) {
        float ej = hi + hjv[j];
        ej = ej >= 0.f ? ej : 0.01f * ej;
        int k = kb + j;
        bool adj;
        if (view == 0) adj = g[j] > 1;
        else if (view == 1) adj = g[j] == ((k == qi) ? 4 : 2);
        else if (view == 2) adj = g[j] == ((k == qi) ? 4 : 3);
        else adj = g[j] == 4;
        e[j] = adj ? ej : NEGV;
        m = fmaxf(m, e[j]);
      }
      #pragma unroll
      for (int off = 32; off; off >>= 1) m = fmaxf(m, __shfl_xor(m, off));
      float ssum = 0.f;
      #pragma unroll
      for (int j = 0; j < 8; j++) { e[j] = __expf(e[j] - m); ssum += e[j]; }
      #pragma unroll
      for (int off = 32; off; off >>= 1) ssum += __shfl_xor(ssum, off);
      float inv = 1.f / ssum;
      bf16x8 pv;
      #pragma unroll
      for (int j = 0; j < 8; j++) pv[j] = (short)f2us(e[j] * inv);
      *(bf16x8*)&P[r * 512 + ((ln ^ (r & 7)) * 8)] = pv;
      ga = gan; gb = gbn;
    }
  }
  __syncthreads();

  // ---- phase 2: ctx[rows, d] = P @ V^T, V straight from global ----
  const bf16* vb = vt + (size_t)bh * 64 * 512;
  const int m0 = (w >> 1) * 16, d0 = (w & 1) * 32;
  f32x4 acc[2];
  acc[0] = (f32x4)(0.0f); acc[1] = (f32x4)(0.0f);

  const int ra = m0 + ln15;
  const int rsw = ra & 7;
  #pragma unroll 4
  for (int k0 = 0; k0 < 512; k0 += 32) {
    int gsel = (k0 >> 3) + quad;
    bf16x8 a = *(bf16x8*)&P[ra * 512 + ((gsel ^ rsw) * 8)];
    #pragma unroll
    for (int nt = 0; nt < 2; nt++) {
      bf16x8 b = *(const bf16x8*)(vb + (size_t)(d0 + nt * 16 + ln15) * 512 + k0 + quad * 8);
      acc[nt] = mfma_bf16(a, b, acc[nt]);
    }
  }

  const int head = bh & 15;
  #pragma unroll
  for (int r = 0; r < 4; r++) {
    int s = qt * 32 + m0 + quad * 4 + r;
    #pragma unroll
    for (int nt = 0; nt < 2; nt++)
      ctx[((size_t)bl * 512 + s) * 1024 + head * 64 + d0 + nt * 16 + ln15] =
          __float2bfloat16(acc[nt][r]);
  }
}

// ---------------------------------------------------------------------------
extern "C" void kernel_launch(void* const* d_in, const int* in_sizes, int n_in,
                              void* d_out, int out_size, void* d_ws, size_t ws_size,
                              hipStream_t stream)
{
  const void* key   = d_in[0];
  const void* value = d_in[1];
  const void* query = d_in[2];
  const int*  grh   = (const int*)d_in[3];
  const void* Wq = d_in[5];
  const void* bq = d_in[6];
  const void* Wk = d_in[7];
  const void* bk = d_in[8];
  const void* Wv = d_in[9];
  const void* bv = d_in[10];
  const void* rel_emb = d_in[11];
  const void* att_w = d_in[12];
  const void* att_b = d_in[13];
  const void* gate_w = d_in[14];
  const void* gate_b = d_in[15];
  const void* sub_w = d_in[16];
  const void* sub_b = d_in[17];

  // workspace layout (floats) — total 36,765,712 fl = 147 MB
  int* dflag = (int*)d_ws;
  float* base = (float*)d_ws;
  bf16* qbf = (bf16*)(base + 16);
  bf16* kbf = (bf16*)(base + 16 + 2097152);
  bf16* vtb = (bf16*)(base + 16 + 2 * 2097152);
  bf16* Wt  = (bf16*)(base + 16 + 3 * 2097152);
  float* G  = base + 16 + 3 * 2097152 + 6815744;
  float* h0 = G + 2162688;
  float* h1 = h0 + 262144;
  bf16* ctx5   = (bf16*)(h1 + 262144);
  bf16* gated5 = ctx5 + 5ull * 4194304;

  detect_k<<<dim3(1), dim3(64), 0, stream>>>(Wq, dflag);

  // all 13 weight transposes in one launch
  wtrans_all_k<<<dim3(13 * 256), dim3(256), 0, stream>>>(
      Wq, Wk, Wv, gate_w, sub_w, Wt, dflag);

  // QKV projections batched (z: 0=q scaled, 1=k, 2=v transposed)
  qkv_gemm_k<<<dim3(32, 8, 3), dim3(256), 0, stream>>>(
      query, key, value, Wt, bq, bk, bv, qbf, kbf, vtb, dflag);

  qrel_k<<<dim3(16384), dim3(256), 0, stream>>>(qbf, rel_emb, G, dflag);

  // main view fully fused -> ctx5 slot 0 (+ top_attn to d_out)
  score_fused_k<<<dim3(128, 8), dim3(256), 0, stream>>>(
      qbf, kbf, G, vtb, rel_emb, ctx5, d_out, dflag);

  // edge views: h projections (4 views batched), then fused softmax+PV
  hv_k<<<dim3(128, 4), dim3(256), 0, stream>>>(vtb, att_w, att_b, h0, h1, dflag);
  edge_fused_k<<<dim3(128, 16, 4), dim3(256), 0, stream>>>(
      h0, h1, grh, vtb, ctx5);

  // 5 gate GEMMs batched, then one K=5120 sub GEMM straight to d_out
  gate_gemm_k<<<dim3(32, 8, 5), dim3(256), 0, stream>>>(
      ctx5, Wt, gate_b, gated5, dflag);
  sub_gemm_k<<<dim3(32, 8), dim3(256), 0, stream>>>(
      gated5, Wt, sub_b, d_out, dflag);
}

// Round 5
// 1009.714 us; speedup vs baseline: 1.0141x; 1.0141x over previous
//
#include <hip/hip_runtime.h>
#include <hip/hip_bf16.h>

typedef __hip_bfloat16 bf16;
typedef __attribute__((ext_vector_type(8))) short bf16x8;
typedef __attribute__((ext_vector_type(4))) float f32x4;

#define B_ 8
#define S_ 512
#define D_ 1024
#define H_ 16
#define NEGV -9.0e15f
#define WSL 1048576ull

__device__ __forceinline__ float bf2f(bf16 x) { return __bfloat162float(x); }
__device__ __forceinline__ float us2f(unsigned short u) {
  union { unsigned int i; float f; } c; c.i = ((unsigned int)u) << 16; return c.f;
}
__device__ __forceinline__ unsigned short f2us(float f) {
  bf16 h = __float2bfloat16(f);
  unsigned short u; __builtin_memcpy(&u, &h, 2); return u;
}
__device__ __forceinline__ float ldx(const void* p, size_t i, int isbf) {
  return isbf ? bf2f(((const bf16*)p)[i]) : ((const float*)p)[i];
}
struct F4 { float x, y, z, w; };
__device__ __forceinline__ F4 ld4(const void* p, size_t i, int isbf) {
  F4 r;
  if (isbf) {
    ushort4 u = *(const ushort4*)((const bf16*)p + i);
    r.x = us2f(u.x); r.y = us2f(u.y); r.z = us2f(u.z); r.w = us2f(u.w);
  } else {
    float4 d = *(const float4*)((const float*)p + i);
    r.x = d.x; r.y = d.y; r.z = d.z; r.w = d.w;
  }
  return r;
}
// 8 consecutive elements as bf16x8; converts if source is f32
__device__ __forceinline__ bf16x8 ld8bf(const void* p, size_t i, int isbf) {
  if (isbf) return *(const bf16x8*)((const bf16*)p + i);
  float4 a = *(const float4*)((const float*)p + i);
  float4 b = *(const float4*)((const float*)p + i + 4);
  bf16x8 r;
  r[0] = (short)f2us(a.x); r[1] = (short)f2us(a.y);
  r[2] = (short)f2us(a.z); r[3] = (short)f2us(a.w);
  r[4] = (short)f2us(b.x); r[5] = (short)f2us(b.y);
  r[6] = (short)f2us(b.z); r[7] = (short)f2us(b.w);
  return r;
}
__device__ __forceinline__ f32x4 mfma_bf16(bf16x8 a, bf16x8 b, f32x4 c) {
  return __builtin_amdgcn_mfma_f32_16x16x32_bf16(a, b, c, 0, 0, 0);
}

// Dtype detector (round-3 verified: picks f32 on this harness).
__global__ void detect_k(const void* __restrict__ w, int* __restrict__ flag)
{
  if (threadIdx.x == 0 && blockIdx.x == 0) {
    const unsigned short* u = (const unsigned short*)w;
    int sane = 0;
    for (int i = 0; i < 1024; i += 2) {
      float a = fabsf(us2f(u[i]));
      if (a == 0.f || (a > 9.5e-7f && a < 8.f)) sane++;
    }
    *flag = (sane > 256) ? 1 : 0;
  }
}

// ---------------------------------------------------------------------------
// ALL 13 weight transposes in one launch. slot = blockIdx.x>>8:
// 0..2 = Wq,Wk,Wv; 3..7 = gate_w srcs {0,5,1,2,3}; 8..12 = sub_w rows c.
// out[n][k] (bf16, 1024x1024) <- W[k][n] (per dflag dtype).
// ---------------------------------------------------------------------------
__global__ __launch_bounds__(256)
void wtrans_all_k(const void* __restrict__ Wq, const void* __restrict__ Wk,
                  const void* __restrict__ Wv, const void* __restrict__ gate_w,
                  const void* __restrict__ sub_w, bf16* __restrict__ Wt,
                  const int* __restrict__ dflag)
{
  const int isbf = *dflag;
  const int slot = blockIdx.x >> 8;
  const int blk = blockIdx.x & 255;
  const int gsrc[5] = {0, 5, 1, 2, 3};
  const void* W;
  size_t woff;
  if (slot < 3)      { W = slot == 0 ? Wq : (slot == 1 ? Wk : Wv); woff = 0; }
  else if (slot < 8) { W = gate_w; woff = (size_t)gsrc[slot - 3] * WSL; }
  else               { W = sub_w;  woff = (size_t)(slot - 8) * WSL; }
  bf16* out = Wt + (size_t)slot * WSL;

  __shared__ float t[64][68];
  const int tid = threadIdx.x;
  const int nt = blk & 15, kt = blk >> 4;
  {
    int r = tid >> 4, c4 = (tid & 15) * 4;
    #pragma unroll
    for (int i = 0; i < 4; i++) {
      int rr = r + i * 16;
      F4 v = ld4(W, woff + (size_t)(kt * 64 + rr) * 1024 + nt * 64 + c4, isbf);
      *(float4*)&t[rr][c4] = make_float4(v.x, v.y, v.z, v.w);
    }
  }
  __syncthreads();
  {
    int n = tid >> 4, k4 = (tid & 15) * 4;
    #pragma unroll
    for (int i = 0; i < 4; i++) {
      int nn = n + i * 16;
      ushort4 u;
      u.x = f2us(t[k4 + 0][nn]); u.y = f2us(t[k4 + 1][nn]);
      u.z = f2us(t[k4 + 2][nn]); u.w = f2us(t[k4 + 3][nn]);
      *(ushort4*)(out + (size_t)(nt * 64 + nn) * 1024 + kt * 64 + k4) = u;
    }
  }
}

// ---------------------------------------------------------------------------
// QKV projections, z-batched (z=0:q scaled, z=1:k, z=2:v transposed).
// 128x128 tile, BK=64, XOR-swizzled LDS (verified core).
// ---------------------------------------------------------------------------
__global__ __launch_bounds__(256)
void qkv_gemm_k(const void* __restrict__ Aq, const void* __restrict__ Ak,
                const void* __restrict__ Av, const bf16* __restrict__ Wt,
                const void* __restrict__ bqp, const void* __restrict__ bkp,
                const void* __restrict__ bvp, bf16* __restrict__ qbf,
                bf16* __restrict__ kbf, bf16* __restrict__ vtb,
                const int* __restrict__ dflag)
{
  const int isbf = *dflag;
  const int z = blockIdx.z;
  const void* A = z == 0 ? Aq : (z == 1 ? Ak : Av);
  const void* bias = z == 0 ? bqp : (z == 1 ? bkp : bvp);
  bf16* outB = z == 0 ? qbf : (z == 1 ? kbf : vtb);
  const bf16* Wz = Wt + (size_t)z * WSL;
  const float scale = z == 0 ? 0.125f : 1.0f;
  const int vtrans = (z == 2);

  __shared__ short As[128 * 64];
  __shared__ short Bs[128 * 64];
  const int tid = threadIdx.x;
  const int w = tid >> 6, ln = tid & 63;
  const int ln15 = ln & 15, quad = ln >> 4;
  const int wm = (w & 1) * 64, wn = (w >> 1) * 64;
  const int bm = blockIdx.x * 128, bn = blockIdx.y * 128;
  const int r0 = tid >> 3, g0 = tid & 7;
  f32x4 acc[4][4];
  #pragma unroll
  for (int mt = 0; mt < 4; mt++)
    #pragma unroll
    for (int nt = 0; nt < 4; nt++) acc[mt][nt] = (f32x4)(0.0f);

  for (int k0 = 0; k0 < 1024; k0 += 64) {
    #pragma unroll
    for (int i = 0; i < 4; i++) {
      int r = r0 + i * 32;
      int gsw = ((g0 ^ (r & 7)) * 8);
      bf16x8 av = ld8bf(A, (size_t)(bm + r) * 1024 + k0 + g0 * 8, isbf);
      *(bf16x8*)&As[r * 64 + gsw] = av;
      bf16x8 bv = *(const bf16x8*)(Wz + (size_t)(bn + r) * 1024 + k0 + g0 * 8);
      *(bf16x8*)&Bs[r * 64 + gsw] = bv;
    }
    __syncthreads();
    #pragma unroll
    for (int s = 0; s < 2; s++) {
      bf16x8 af[4], bfr[4];
      #pragma unroll
      for (int t = 0; t < 4; t++) {
        int ra = wm + t * 16 + ln15;
        af[t] = *(bf16x8*)&As[ra * 64 + (((s * 4 + quad) ^ (ra & 7)) * 8)];
        int rb = wn + t * 16 + ln15;
        bfr[t] = *(bf16x8*)&Bs[rb * 64 + (((s * 4 + quad) ^ (rb & 7)) * 8)];
      }
      #pragma unroll
      for (int mt = 0; mt < 4; mt++)
        #pragma unroll
        for (int nt = 0; nt < 4; nt++)
          acc[mt][nt] = mfma_bf16(af[mt], bfr[nt], acc[mt][nt]);
    }
    __syncthreads();
  }

  #pragma unroll
  for (int nt = 0; nt < 4; nt++) {
    int col = bn + wn + nt * 16 + ln15;
    float bv = ldx(bias, col, isbf);
    #pragma unroll
    for (int mt = 0; mt < 4; mt++) {
      #pragma unroll
      for (int r = 0; r < 4; r++) {
        int row = bm + wm + mt * 16 + quad * 4 + r;
        float v = (acc[mt][nt][r] + bv) * scale;
        int bb = row >> 9, s = row & 511;
        int h = col >> 6, d0 = col & 63;
        size_t o = vtrans ? (((size_t)(bb * 16 + h) * 64 + d0) * 512 + s)
                          : (((size_t)(bb * 16 + h) * 512 + s) * 64 + d0);
        outB[o] = __float2bfloat16(v);
      }
    }
  }
}

// ---------------------------------------------------------------------------
// Gate GEMMs, z-batched over 5 views (main + 4 edge).
// gated_z = sigmoid(ctx_z @ gate_w_z + gate_b_z) * ctx_z
// ---------------------------------------------------------------------------
__global__ __launch_bounds__(256)
void gate_gemm_k(const bf16* __restrict__ ctx5, const bf16* __restrict__ Wt,
                 const void* __restrict__ gate_b, bf16* __restrict__ gated5,
                 const int* __restrict__ dflag)
{
  const int isbf = *dflag;
  const int z = blockIdx.z;
  const int gsel[5] = {0, 5, 1, 2, 3};
  const bf16* A = ctx5 + (size_t)z * 4194304;
  bf16* outB = gated5 + (size_t)z * 4194304;
  const bf16* Wz = Wt + (size_t)(3 + z) * WSL;
  const size_t boff = (size_t)gsel[z] * 1024;

  __shared__ short As[128 * 64];
  __shared__ short Bs[128 * 64];
  const int tid = threadIdx.x;
  const int w = tid >> 6, ln = tid & 63;
  const int ln15 = ln & 15, quad = ln >> 4;
  const int wm = (w & 1) * 64, wn = (w >> 1) * 64;
  const int bm = blockIdx.x * 128, bn = blockIdx.y * 128;
  const int r0 = tid >> 3, g0 = tid & 7;
  f32x4 acc[4][4];
  #pragma unroll
  for (int mt = 0; mt < 4; mt++)
    #pragma unroll
    for (int nt = 0; nt < 4; nt++) acc[mt][nt] = (f32x4)(0.0f);

  for (int k0 = 0; k0 < 1024; k0 += 64) {
    #pragma unroll
    for (int i = 0; i < 4; i++) {
      int r = r0 + i * 32;
      int gsw = ((g0 ^ (r & 7)) * 8);
      bf16x8 av = *(const bf16x8*)(A + (size_t)(bm + r) * 1024 + k0 + g0 * 8);
      *(bf16x8*)&As[r * 64 + gsw] = av;
      bf16x8 bv = *(const bf16x8*)(Wz + (size_t)(bn + r) * 1024 + k0 + g0 * 8);
      *(bf16x8*)&Bs[r * 64 + gsw] = bv;
    }
    __syncthreads();
    #pragma unroll
    for (int s = 0; s < 2; s++) {
      bf16x8 af[4], bfr[4];
      #pragma unroll
      for (int t = 0; t < 4; t++) {
        int ra = wm + t * 16 + ln15;
        af[t] = *(bf16x8*)&As[ra * 64 + (((s * 4 + quad) ^ (ra & 7)) * 8)];
        int rb = wn + t * 16 + ln15;
        bfr[t] = *(bf16x8*)&Bs[rb * 64 + (((s * 4 + quad) ^ (rb & 7)) * 8)];
      }
      #pragma unroll
      for (int mt = 0; mt < 4; mt++)
        #pragma unroll
        for (int nt = 0; nt < 4; nt++)
          acc[mt][nt] = mfma_bf16(af[mt], bfr[nt], acc[mt][nt]);
    }
    __syncthreads();
  }

  #pragma unroll
  for (int nt = 0; nt < 4; nt++) {
    int col = bn + wn + nt * 16 + ln15;
    float bv = ldx(gate_b, boff + col, isbf);
    #pragma unroll
    for (int mt = 0; mt < 4; mt++) {
      #pragma unroll
      for (int r = 0; r < 4; r++) {
        int row = bm + wm + mt * 16 + quad * 4 + r;
        float v = acc[mt][nt][r] + bv;
        float x = bf2f(A[(size_t)row * 1024 + col]);
        outB[(size_t)row * 1024 + col] = __float2bfloat16(x / (1.f + __expf(-v)));
      }
    }
  }
}

// ---------------------------------------------------------------------------
// Final sub GEMM: out = [gated_0|...|gated_4](4096x5120) @ sub_w(5120x1024)
// + sub_b, written straight to d_out (dtype-aware).
// ---------------------------------------------------------------------------
__global__ __launch_bounds__(256)
void sub_gemm_k(const bf16* __restrict__ gated5, const bf16* __restrict__ Wt,
                const void* __restrict__ sub_b, void* __restrict__ dout,
                const int* __restrict__ dflag)
{
  const int isbf = *dflag;
  __shared__ short As[128 * 64];
  __shared__ short Bs[128 * 64];
  const int tid = threadIdx.x;
  const int w = tid >> 6, ln = tid & 63;
  const int ln15 = ln & 15, quad = ln >> 4;
  const int wm = (w & 1) * 64, wn = (w >> 1) * 64;
  const int bm = blockIdx.x * 128, bn = blockIdx.y * 128;
  const int r0 = tid >> 3, g0 = tid & 7;
  f32x4 acc[4][4];
  #pragma unroll
  for (int mt = 0; mt < 4; mt++)
    #pragma unroll
    for (int nt = 0; nt < 4; nt++) acc[mt][nt] = (f32x4)(0.0f);

  for (int k0 = 0; k0 < 5120; k0 += 64) {
    const int slot = k0 >> 10, kk = k0 & 1023;
    const bf16* Ab = gated5 + (size_t)slot * 4194304;
    const bf16* Wz = Wt + (size_t)(8 + slot) * WSL;
    #pragma unroll
    for (int i = 0; i < 4; i++) {
      int r = r0 + i * 32;
      int gsw = ((g0 ^ (r & 7)) * 8);
      bf16x8 av = *(const bf16x8*)(Ab + (size_t)(bm + r) * 1024 + kk + g0 * 8);
      *(bf16x8*)&As[r * 64 + gsw] = av;
      bf16x8 bv = *(const bf16x8*)(Wz + (size_t)(bn + r) * 1024 + kk + g0 * 8);
      *(bf16x8*)&Bs[r * 64 + gsw] = bv;
    }
    __syncthreads();
    #pragma unroll
    for (int s = 0; s < 2; s++) {
      bf16x8 af[4], bfr[4];
      #pragma unroll
      for (int t = 0; t < 4; t++) {
        int ra = wm + t * 16 + ln15;
        af[t] = *(bf16x8*)&As[ra * 64 + (((s * 4 + quad) ^ (ra & 7)) * 8)];
        int rb = wn + t * 16 + ln15;
        bfr[t] = *(bf16x8*)&Bs[rb * 64 + (((s * 4 + quad) ^ (rb & 7)) * 8)];
      }
      #pragma unroll
      for (int mt = 0; mt < 4; mt++)
        #pragma unroll
        for (int nt = 0; nt < 4; nt++)
          acc[mt][nt] = mfma_bf16(af[mt], bfr[nt], acc[mt][nt]);
    }
    __syncthreads();
  }

  #pragma unroll
  for (int nt = 0; nt < 4; nt++) {
    int col = bn + wn + nt * 16 + ln15;
    float bv = ldx(sub_b, col, isbf);
    #pragma unroll
    for (int mt = 0; mt < 4; mt++) {
      #pragma unroll
      for (int r = 0; r < 4; r++) {
        int row = bm + wm + mt * 16 + quad * 4 + r;
        float v = acc[mt][nt][r] + bv;
        size_t o = (size_t)row * 1024 + col;
        if (isbf) ((bf16*)dout)[o] = __float2bfloat16(v);
        else      ((float*)dout)[o] = v;
      }
    }
  }
}

// ---------------------------------------------------------------------------
// G[row][r] = q_row . rel_emb[r] (bf16 q). One wave per row.
// ---------------------------------------------------------------------------
__global__ __launch_bounds__(256)
void qrel_k(const bf16* __restrict__ qbf, const void* __restrict__ rel_emb,
            float* __restrict__ G, const int* __restrict__ dflag)
{
  const int isbf = *dflag;
  __shared__ float rel[33][65];
  __shared__ float qw[4][64];
  const int tid = threadIdx.x;
  for (int i = tid; i < 33 * 64; i += 256)
    rel[i >> 6][i & 63] = ldx(rel_emb, i, isbf);
  const int wv = tid >> 6, lane = tid & 63;
  const size_t row = (size_t)blockIdx.x * 4 + wv;
  qw[wv][lane] = bf2f(qbf[row * 64 + lane]);
  __syncthreads();
  if (lane < 33) {
    float s = 0.f;
    #pragma unroll
    for (int d = 0; d < 64; d++) s += qw[wv][d] * rel[lane][d];
    G[row * 33 + lane] = s;
  }
}

// ---------------------------------------------------------------------------
// Fully fused main view v3 = v2 + __launch_bounds__(256, 2).
// Round-4 post-mortem: without the min-waves hint the allocator capped VGPRs
// at 100 and SPILLED acc[32] (128 VGPRs) to scratch -> 540 MB of HBM writes
// per dispatch (matches WRITE_SIZE within 3%), 289 us. The (256,2) bound
// caps at 256 VGPRs (2 waves/SIMD), which holds acc + fragments (~200).
// QK unroll moderated 8 -> 4 to keep pipelining pressure under the cap.
// Numerics byte-identical to round-4 (harness-verified, absmax 0.00098).
// ---------------------------------------------------------------------------
__global__ __launch_bounds__(256, 2)
void score_fused_k(const bf16* __restrict__ qbf, const bf16* __restrict__ kbf,
                   const float* __restrict__ G, const bf16* __restrict__ vt,
                   const void* __restrict__ rel_emb, bf16* __restrict__ ctx,
                   void* __restrict__ dout, const int* __restrict__ dflag)
{
  __shared__ short Pw[4][16 * 256];   // 32 KB, per-wave private
  __shared__ float gbuf[64 * 33];     // 8448 B
  __shared__ float relbuf[33 * 64];   // 8448 B
  const int tid = threadIdx.x;
  const int w = tid >> 6, ln = tid & 63;
  const int ln15 = ln & 15, quad = ln >> 4;
  const int bh = blockIdx.x, qt = blockIdx.y;
  const size_t qrow0 = (size_t)bh * 512 + qt * 64;
  const int isbf = *dflag;

  // stage G (this block's 64 rows) + rel into LDS (one barrier, after QK)
  for (int i = tid; i < 64 * 33; i += 256) {
    int r = i / 33, c = i - r * 33;
    gbuf[i] = G[(qrow0 + r) * 33 + c];
  }
  for (int i = tid; i < 33 * 64; i += 256)
    relbuf[i] = ldx(rel_emb, i, isbf);

  // ---- QK^T: fragments straight from global, zero barriers ----
  const bf16* qrow = qbf + (qrow0 + w * 16 + ln15) * 64;
  bf16x8 af0 = *(const bf16x8*)(qrow + quad * 8);
  bf16x8 af1 = *(const bf16x8*)(qrow + 32 + quad * 8);
  const bf16* kb = kbf + (size_t)bh * 512 * 64;
  f32x4 acc[32];
  #pragma unroll
  for (int t = 0; t < 32; t++) acc[t] = (f32x4)(0.0f);
  #pragma unroll 4
  for (int t = 0; t < 32; t++) {
    const bf16* kr = kb + (size_t)(t * 16 + ln15) * 64 + quad * 8;
    bf16x8 b0 = *(const bf16x8*)kr;
    bf16x8 b1 = *(const bf16x8*)(kr + 32);
    acc[t] = mfma_bf16(af0, b0, acc[t]);
    acc[t] = mfma_bf16(af1, b1, acc[t]);
  }
  __syncthreads();   // gbuf/relbuf now valid

  // ---- rel bias + softmax (identical math to verified score_k) ----
  const int qg = qt * 64 + w * 16 + quad * 4;
  const int rowl0 = w * 16 + quad * 4;
  float mx[4], ssum[4], sle[4], sge[4];
  #pragma unroll
  for (int r = 0; r < 4; r++) mx[r] = -3.0e38f;
  for (int t = 0; t < 32; t++) {
    int k = t * 16 + ln15;
    #pragma unroll
    for (int r = 0; r < 4; r++) {
      int delta = k - (qg + r);
      int bkt = delta < -16 ? 0 : (delta > 16 ? 32 : delta + 16);
      float s = acc[t][r] + gbuf[(rowl0 + r) * 33 + bkt];
      acc[t][r] = s;
      mx[r] = fmaxf(mx[r], s);
    }
  }
  #pragma unroll
  for (int r = 0; r < 4; r++) {
    float m = mx[r];
    #pragma unroll
    for (int off = 1; off < 16; off <<= 1) m = fmaxf(m, __shfl_xor(m, off));
    mx[r] = m;
    ssum[r] = 0.f; sle[r] = 0.f; sge[r] = 0.f;
  }
  for (int t = 0; t < 32; t++) {
    int k = t * 16 + ln15;
    #pragma unroll
    for (int r = 0; r < 4; r++) {
      float p = __expf(acc[t][r] - mx[r]);
      acc[t][r] = p;
      ssum[r] += p;
      int delta = k - (qg + r);
      if (delta <= -16) sle[r] += p;
      if (delta >= 16) sge[r] += p;
    }
  }
  #pragma unroll
  for (int r = 0; r < 4; r++) {
    #pragma unroll
    for (int off = 1; off < 16; off <<= 1) {
      ssum[r] += __shfl_xor(ssum[r], off);
      sle[r] += __shfl_xor(sle[r], off);
      sge[r] += __shfl_xor(sge[r], off);
    }
  }
  float inv[4];
  #pragma unroll
  for (int r = 0; r < 4; r++) inv[r] = 1.f / ssum[r];

  // ---- per-wave P (16 rows), k in two 256-halves; PV + band + top_attn ----
  short* Pm = Pw[w];
  const bf16* vb = vt + (size_t)bh * 64 * 512;
  const int toph = ((bh & 15) == 0);
  const int bg = bh >> 4;
  f32x4 pacc[4];
  #pragma unroll
  for (int nt = 0; nt < 4; nt++) pacc[nt] = (f32x4)(0.0f);

  #pragma unroll
  for (int h = 0; h < 2; h++) {
    // store this half's P (normalized bf16), swizzled 16B groups
    #pragma unroll
    for (int t2 = 0; t2 < 16; t2++) {
      int gg = t2 * 2 + (ln15 >> 3);        // logical group = col>>3
      int slot = gg ^ (quad << 1);          // ((rowL>>2)&3)==quad for rowL=quad*4+r
      #pragma unroll
      for (int r = 0; r < 4; r++) {
        int rowL = quad * 4 + r;
        Pm[rowL * 256 + slot * 8 + (ln15 & 7)] =
            (short)f2us(acc[h * 16 + t2][r] * inv[r]);
      }
    }
    __syncthreads();

    // top_attn (head-0 blocks only): wave writes its own 16 rows, this half
    if (toph) {
      for (int i = ln; i < 16 * 32; i += 64) {
        int rowL = i >> 5, gg = i & 31;
        int slot = gg ^ (((rowL >> 2) & 3) << 1);
        bf16x8 u = *(bf16x8*)&Pm[rowL * 256 + slot * 8];
        size_t o = (size_t)4194304 + (size_t)bg * 262144 +
                   (size_t)(qt * 64 + w * 16 + rowL) * 512 + h * 256 + gg * 8;
        if (isbf) {
          *(bf16x8*)((bf16*)dout + o) = u;
        } else {
          float4 f0 = make_float4(us2f((unsigned short)u[0]), us2f((unsigned short)u[1]),
                                  us2f((unsigned short)u[2]), us2f((unsigned short)u[3]));
          float4 f1 = make_float4(us2f((unsigned short)u[4]), us2f((unsigned short)u[5]),
                                  us2f((unsigned short)u[6]), us2f((unsigned short)u[7]));
          *(float4*)((float*)dout + o) = f0;
          *(float4*)((float*)dout + o + 4) = f1;
        }
      }
    }

    // PV over this half: A from Pm (own rows), V fragments from global
    {
      const int rsw = ((ln15 >> 2) & 3) << 1;
      #pragma unroll
      for (int kk = 0; kk < 8; kk++) {
        int gg = kk * 4 + quad;
        bf16x8 a = *(bf16x8*)&Pm[ln15 * 256 + ((gg ^ rsw) * 8)];
        int k0 = h * 256 + kk * 32;
        #pragma unroll
        for (int nt = 0; nt < 4; nt++) {
          bf16x8 b = *(const bf16x8*)(vb + (size_t)(nt * 16 + ln15) * 512 + k0 + quad * 8);
          pacc[nt] = mfma_bf16(a, b, pacc[nt]);
        }
      }
    }

    // diagonal band of arel@rel for k in this half (rel from LDS)
    for (int rr = 1; rr < 32; rr++) {
      float av[4];
      #pragma unroll
      for (int r = 0; r < 4; r++) {
        int k = qg + r + rr - 16;
        av[r] = 0.f;
        if (k >= h * 256 && k < (h + 1) * 256) {
          int kl = k - h * 256;
          int rowL = quad * 4 + r;
          int slot = (kl >> 3) ^ (quad << 1);
          av[r] = us2f((unsigned short)Pm[rowL * 256 + slot * 8 + (kl & 7)]);
        }
      }
      #pragma unroll
      for (int nt = 0; nt < 4; nt++) {
        float relv = relbuf[rr * 64 + nt * 16 + ln15];
        #pragma unroll
        for (int r = 0; r < 4; r++) pacc[nt][r] += av[r] * relv;
      }
    }
    __syncthreads();   // before overwriting Pm with next half
  }

  // sle/sge terms (buckets 0 and 32)
  #pragma unroll
  for (int nt = 0; nt < 4; nt++) {
    float r0v = relbuf[nt * 16 + ln15];
    float r32v = relbuf[32 * 64 + nt * 16 + ln15];
    #pragma unroll
    for (int r = 0; r < 4; r++)
      pacc[nt][r] += sle[r] * inv[r] * r0v + sge[r] * inv[r] * r32v;
  }

  // ctx write (slot 0 layout [bl*512+s][1024])
  const int bl = bh >> 4, head = bh & 15;
  #pragma unroll
  for (int r = 0; r < 4; r++) {
    int s = qt * 64 + rowl0 + r;
    #pragma unroll
    for (int nt = 0; nt < 4; nt++)
      ctx[((size_t)bl * 512 + s) * 1024 + head * 64 + nt * 16 + ln15] =
          __float2bfloat16(pacc[nt][r]);
  }
}

// ---------------------------------------------------------------------------
// Edge h-projections, z-batched over 4 views (blockIdx.y).
// ---------------------------------------------------------------------------
__global__ __launch_bounds__(256)
void hv_k(const bf16* __restrict__ vt, const void* __restrict__ att_w,
          const void* __restrict__ att_b, float* __restrict__ h0,
          float* __restrict__ h1, const int* __restrict__ dflag)
{
  const int i0s[4] = {6, 0, 2, 4};
  const int i1s[4] = {7, 1, 3, 5};
  const int z = blockIdx.y;
  const int i0 = i0s[z], i1 = i1s[z];
  __shared__ float w0[64], w1[64];
  const int tid = threadIdx.x;
  const int bh = blockIdx.x;
  const int isbf = *dflag;
  if (tid < 64) {
    w0[tid] = ldx(att_w, i0 * 64 + tid, isbf);
    w1[tid] = ldx(att_w, i1 * 64 + tid, isbf);
  }
  __syncthreads();
  const bf16* vb = vt + (size_t)bh * 64 * 512 + tid * 2;
  float a00 = 0, a01 = 0, a10 = 0, a11 = 0;
  for (int d = 0; d < 64; d++) {
    ushort2 u = *(const ushort2*)(vb + (size_t)d * 512);
    float f0 = us2f(u.x), f1 = us2f(u.y);
    a00 += f0 * w0[d]; a10 += f1 * w0[d];
    a01 += f0 * w1[d]; a11 += f1 * w1[d];
  }
  float b0 = ldx(att_b, i0, isbf), b1 = ldx(att_b, i1, isbf);
  float* p0 = h0 + (size_t)z * 65536 + (size_t)bh * 512 + tid * 2;
  float* p1 = h1 + (size_t)z * 65536 + (size_t)bh * 512 + tid * 2;
  p0[0] = a00 + b0; p0[1] = a10 + b0;
  p1[0] = a01 + b1; p1[1] = a11 + b1;
}

// ---------------------------------------------------------------------------
// Fused edge view, z-batched over the 4 views (blockIdx.z). Verified round-2
// structure: 32 q-rows/block, 32KB LDS P, softmax per wave-row, PV with V
// fragments from global. Writes ctx5 slot (1+view).
// ---------------------------------------------------------------------------
__global__ __launch_bounds__(256)
void edge_fused_k(const float* __restrict__ h0, const float* __restrict__ h1,
                  const int* __restrict__ grh, const bf16* __restrict__ vt,
                  bf16* __restrict__ ctx5)
{
  __shared__ short P[32 * 512];   // 32 KB
  const int tid = threadIdx.x;
  const int w = tid >> 6, ln = tid & 63;
  const int ln15 = ln & 15, quad = ln >> 4;
  const int bh = blockIdx.x, qt = blockIdx.y, view = blockIdx.z;
  const int bl = bh >> 4;
  bf16* ctx = ctx5 + (size_t)(1 + view) * 4194304;

  // ---- phase 1: rows w*8 .. w*8+7, one full wave per row ----
  const int kb = ln * 8;
  {
    const float* hjp = h1 + (size_t)view * 65536 + (size_t)bh * 512 + kb;
    float4 hA = *(const float4*)hjp;
    float4 hB = *(const float4*)(hjp + 4);
    float hjv[8] = {hA.x, hA.y, hA.z, hA.w, hB.x, hB.y, hB.z, hB.w};
    const float* h0b = h0 + (size_t)view * 65536 + (size_t)bh * 512 + qt * 32 + w * 8;
    const int* grow = grh + ((size_t)bl * 512 + qt * 32 + w * 8) * 512 + kb;

    int4 ga = *(const int4*)grow;
    int4 gb = *(const int4*)(grow + 4);
    #pragma unroll 2
    for (int rr = 0; rr < 8; rr++) {
      int rn = rr < 7 ? rr + 1 : rr;
      const int* gn = grow + (size_t)rn * 512;
      int4 gan = *(const int4*)gn;
      int4 gbn = *(const int4*)(gn + 4);
      int r = w * 8 + rr;              // local row in P, 0..31
      int qi = qt * 32 + r;            // global q index, 0..511
      float hi = h0b[rr];
      int g[8] = {ga.x, ga.y, ga.z, ga.w, gb.x, gb.y, gb.z, gb.w};
      float e[8];
      float m = -3.0e38f;
      #pragma unroll
      for (int j = 0; j < 8; j++) {
        float ej = hi + hjv[j];
        ej = ej >= 0.f ? ej : 0.01f * ej;
        int k = kb + j;
        bool adj;
        if (view == 0) adj = g[j] > 1;
        else if (view == 1) adj = g[j] == ((k == qi) ? 4 : 2);
        else if (view == 2) adj = g[j] == ((k == qi) ? 4 : 3);
        else adj = g[j] == 4;
        e[j] = adj ? ej : NEGV;
        m = fmaxf(m, e[j]);
      }
      #pragma unroll
      for (int off = 32; off; off >>= 1) m = fmaxf(m, __shfl_xor(m, off));
      float ssum = 0.f;
      #pragma unroll
      for (int j = 0; j < 8; j++) { e[j] = __expf(e[j] - m); ssum += e[j]; }
      #pragma unroll
      for (int off = 32; off; off >>= 1) ssum += __shfl_xor(ssum, off);
      float inv = 1.f / ssum;
      bf16x8 pv;
      #pragma unroll
      for (int j = 0; j < 8; j++) pv[j] = (short)f2us(e[j] * inv);
      *(bf16x8*)&P[r * 512 + ((ln ^ (r & 7)) * 8)] = pv;
      ga = gan; gb = gbn;
    }
  }
  __syncthreads();

  // ---- phase 2: ctx[rows, d] = P @ V^T, V straight from global ----
  const bf16* vb = vt + (size_t)bh * 64 * 512;
  const int m0 = (w >> 1) * 16, d0 = (w & 1) * 32;
  f32x4 acc[2];
  acc[0] = (f32x4)(0.0f); acc[1] = (f32x4)(0.0f);

  const int ra = m0 + ln15;
  const int rsw = ra & 7;
  #pragma unroll 4
  for (int k0 = 0; k0 < 512; k0 += 32) {
    int gsel = (k0 >> 3) + quad;
    bf16x8 a = *(bf16x8*)&P[ra * 512 + ((gsel ^ rsw) * 8)];
    #pragma unroll
    for (int nt = 0; nt < 2; nt++) {
      bf16x8 b = *(const bf16x8*)(vb + (size_t)(d0 + nt * 16 + ln15) * 512 + k0 + quad * 8);
      acc[nt] = mfma_bf16(a, b, acc[nt]);
    }
  }

  const int head = bh & 15;
  #pragma unroll
  for (int r = 0; r < 4; r++) {
    int s = qt * 32 + m0 + quad * 4 + r;
    #pragma unroll
    for (int nt = 0; nt < 2; nt++)
      ctx[((size_t)bl * 512 + s) * 1024 + head * 64 + d0 + nt * 16 + ln15] =
          __float2bfloat16(acc[nt][r]);
  }
}

// ---------------------------------------------------------------------------
extern "C" void kernel_launch(void* const* d_in, const int* in_sizes, int n_in,
                              void* d_out, int out_size, void* d_ws, size_t ws_size,
                              hipStream_t stream)
{
  const void* key   = d_in[0];
  const void* value = d_in[1];
  const void* query = d_in[2];
  const int*  grh   = (const int*)d_in[3];
  const void* Wq = d_in[5];
  const void* bq = d_in[6];
  const void* Wk = d_in[7];
  const void* bk = d_in[8];
  const void* Wv = d_in[9];
  const void* bv = d_in[10];
  const void* rel_emb = d_in[11];
  const void* att_w = d_in[12];
  const void* att_b = d_in[13];
  const void* gate_w = d_in[14];
  const void* gate_b = d_in[15];
  const void* sub_w = d_in[16];
  const void* sub_b = d_in[17];

  // workspace layout (floats) — total 36,765,712 fl = 147 MB
  int* dflag = (int*)d_ws;
  float* base = (float*)d_ws;
  bf16* qbf = (bf16*)(base + 16);
  bf16* kbf = (bf16*)(base + 16 + 2097152);
  bf16* vtb = (bf16*)(base + 16 + 2 * 2097152);
  bf16* Wt  = (bf16*)(base + 16 + 3 * 2097152);
  float* G  = base + 16 + 3 * 2097152 + 6815744;
  float* h0 = G + 2162688;
  float* h1 = h0 + 262144;
  bf16* ctx5   = (bf16*)(h1 + 262144);
  bf16* gated5 = ctx5 + 5ull * 4194304;

  detect_k<<<dim3(1), dim3(64), 0, stream>>>(Wq, dflag);

  // all 13 weight transposes in one launch
  wtrans_all_k<<<dim3(13 * 256), dim3(256), 0, stream>>>(
      Wq, Wk, Wv, gate_w, sub_w, Wt, dflag);

  // QKV projections batched (z: 0=q scaled, 1=k, 2=v transposed)
  qkv_gemm_k<<<dim3(32, 8, 3), dim3(256), 0, stream>>>(
      query, key, value, Wt, bq, bk, bv, qbf, kbf, vtb, dflag);

  qrel_k<<<dim3(16384), dim3(256), 0, stream>>>(qbf, rel_emb, G, dflag);

  // main view fully fused -> ctx5 slot 0 (+ top_attn to d_out)
  score_fused_k<<<dim3(128, 8), dim3(256), 0, stream>>>(
      qbf, kbf, G, vtb, rel_emb, ctx5, d_out, dflag);

  // edge views: h projections (4 views batched), then fused softmax+PV
  hv_k<<<dim3(128, 4), dim3(256), 0, stream>>>(vtb, att_w, att_b, h0, h1, dflag);
  edge_fused_k<<<dim3(128, 16, 4), dim3(256), 0, stream>>>(
      h0, h1, grh, vtb, ctx5);

  // 5 gate GEMMs batched, then one K=5120 sub GEMM straight to d_out
  gate_gemm_k<<<dim3(32, 8, 5), dim3(256), 0, stream>>>(
      ctx5, Wt, gate_b, gated5, dflag);
  sub_gemm_k<<<dim3(32, 8), dim3(256), 0, stream>>>(
      gated5, Wt, sub_b, d_out, dflag);
}

// Round 6
// 891.782 us; speedup vs baseline: 1.1482x; 1.1322x over previous
//
#include <hip/hip_runtime.h>
#include <hip/hip_bf16.h>

typedef __hip_bfloat16 bf16;
typedef __attribute__((ext_vector_type(8))) short bf16x8;
typedef __attribute__((ext_vector_type(4))) float f32x4;

#define B_ 8
#define S_ 512
#define D_ 1024
#define H_ 16
#define NEGV -9.0e15f
#define WSL 1048576ull

__device__ __forceinline__ float bf2f(bf16 x) { return __bfloat162float(x); }
__device__ __forceinline__ float us2f(unsigned short u) {
  union { unsigned int i; float f; } c; c.i = ((unsigned int)u) << 16; return c.f;
}
__device__ __forceinline__ unsigned short f2us(float f) {
  bf16 h = __float2bfloat16(f);
  unsigned short u; __builtin_memcpy(&u, &h, 2); return u;
}
__device__ __forceinline__ float ldx(const void* p, size_t i, int isbf) {
  return isbf ? bf2f(((const bf16*)p)[i]) : ((const float*)p)[i];
}
struct F4 { float x, y, z, w; };
__device__ __forceinline__ F4 ld4(const void* p, size_t i, int isbf) {
  F4 r;
  if (isbf) {
    ushort4 u = *(const ushort4*)((const bf16*)p + i);
    r.x = us2f(u.x); r.y = us2f(u.y); r.z = us2f(u.z); r.w = us2f(u.w);
  } else {
    float4 d = *(const float4*)((const float*)p + i);
    r.x = d.x; r.y = d.y; r.z = d.z; r.w = d.w;
  }
  return r;
}
// 8 consecutive elements as bf16x8; converts if source is f32
__device__ __forceinline__ bf16x8 ld8bf(const void* p, size_t i, int isbf) {
  if (isbf) return *(const bf16x8*)((const bf16*)p + i);
  float4 a = *(const float4*)((const float*)p + i);
  float4 b = *(const float4*)((const float*)p + i + 4);
  bf16x8 r;
  r[0] = (short)f2us(a.x); r[1] = (short)f2us(a.y);
  r[2] = (short)f2us(a.z); r[3] = (short)f2us(a.w);
  r[4] = (short)f2us(b.x); r[5] = (short)f2us(b.y);
  r[6] = (short)f2us(b.z); r[7] = (short)f2us(b.w);
  return r;
}
__device__ __forceinline__ f32x4 mfma_bf16(bf16x8 a, bf16x8 b, f32x4 c) {
  return __builtin_amdgcn_mfma_f32_16x16x32_bf16(a, b, c, 0, 0, 0);
}

// Dtype detector (round-3 verified: picks f32 on this harness).
__global__ void detect_k(const void* __restrict__ w, int* __restrict__ flag)
{
  if (threadIdx.x == 0 && blockIdx.x == 0) {
    const unsigned short* u = (const unsigned short*)w;
    int sane = 0;
    for (int i = 0; i < 1024; i += 2) {
      float a = fabsf(us2f(u[i]));
      if (a == 0.f || (a > 9.5e-7f && a < 8.f)) sane++;
    }
    *flag = (sane > 256) ? 1 : 0;
  }
}

// ---------------------------------------------------------------------------
// ALL 13 weight transposes in one launch. slot = blockIdx.x>>8:
// 0..2 = Wq,Wk,Wv; 3..7 = gate_w srcs {0,5,1,2,3}; 8..12 = sub_w rows c.
// out[n][k] (bf16, 1024x1024) <- W[k][n] (per dflag dtype).
// ---------------------------------------------------------------------------
__global__ __launch_bounds__(256)
void wtrans_all_k(const void* __restrict__ Wq, const void* __restrict__ Wk,
                  const void* __restrict__ Wv, const void* __restrict__ gate_w,
                  const void* __restrict__ sub_w, bf16* __restrict__ Wt,
                  const int* __restrict__ dflag)
{
  const int isbf = *dflag;
  const int slot = blockIdx.x >> 8;
  const int blk = blockIdx.x & 255;
  const int gsrc[5] = {0, 5, 1, 2, 3};
  const void* W;
  size_t woff;
  if (slot < 3)      { W = slot == 0 ? Wq : (slot == 1 ? Wk : Wv); woff = 0; }
  else if (slot < 8) { W = gate_w; woff = (size_t)gsrc[slot - 3] * WSL; }
  else               { W = sub_w;  woff = (size_t)(slot - 8) * WSL; }
  bf16* out = Wt + (size_t)slot * WSL;

  __shared__ float t[64][68];
  const int tid = threadIdx.x;
  const int nt = blk & 15, kt = blk >> 4;
  {
    int r = tid >> 4, c4 = (tid & 15) * 4;
    #pragma unroll
    for (int i = 0; i < 4; i++) {
      int rr = r + i * 16;
      F4 v = ld4(W, woff + (size_t)(kt * 64 + rr) * 1024 + nt * 64 + c4, isbf);
      *(float4*)&t[rr][c4] = make_float4(v.x, v.y, v.z, v.w);
    }
  }
  __syncthreads();
  {
    int n = tid >> 4, k4 = (tid & 15) * 4;
    #pragma unroll
    for (int i = 0; i < 4; i++) {
      int nn = n + i * 16;
      ushort4 u;
      u.x = f2us(t[k4 + 0][nn]); u.y = f2us(t[k4 + 1][nn]);
      u.z = f2us(t[k4 + 2][nn]); u.w = f2us(t[k4 + 3][nn]);
      *(ushort4*)(out + (size_t)(nt * 64 + nn) * 1024 + kt * 64 + k4) = u;
    }
  }
}

// ---------------------------------------------------------------------------
// QKV projections, z-batched (z=0:q scaled, z=1:k, z=2:v transposed).
// 128x128 tile, BK=64, XOR-swizzled LDS (verified core).
// ---------------------------------------------------------------------------
__global__ __launch_bounds__(256)
void qkv_gemm_k(const void* __restrict__ Aq, const void* __restrict__ Ak,
                const void* __restrict__ Av, const bf16* __restrict__ Wt,
                const void* __restrict__ bqp, const void* __restrict__ bkp,
                const void* __restrict__ bvp, bf16* __restrict__ qbf,
                bf16* __restrict__ kbf, bf16* __restrict__ vtb,
                const int* __restrict__ dflag)
{
  const int isbf = *dflag;
  const int z = blockIdx.z;
  const void* A = z == 0 ? Aq : (z == 1 ? Ak : Av);
  const void* bias = z == 0 ? bqp : (z == 1 ? bkp : bvp);
  bf16* outB = z == 0 ? qbf : (z == 1 ? kbf : vtb);
  const bf16* Wz = Wt + (size_t)z * WSL;
  const float scale = z == 0 ? 0.125f : 1.0f;
  const int vtrans = (z == 2);

  __shared__ short As[128 * 64];
  __shared__ short Bs[128 * 64];
  const int tid = threadIdx.x;
  const int w = tid >> 6, ln = tid & 63;
  const int ln15 = ln & 15, quad = ln >> 4;
  const int wm = (w & 1) * 64, wn = (w >> 1) * 64;
  const int bm = blockIdx.x * 128, bn = blockIdx.y * 128;
  const int r0 = tid >> 3, g0 = tid & 7;
  f32x4 acc[4][4];
  #pragma unroll
  for (int mt = 0; mt < 4; mt++)
    #pragma unroll
    for (int nt = 0; nt < 4; nt++) acc[mt][nt] = (f32x4)(0.0f);

  for (int k0 = 0; k0 < 1024; k0 += 64) {
    #pragma unroll
    for (int i = 0; i < 4; i++) {
      int r = r0 + i * 32;
      int gsw = ((g0 ^ (r & 7)) * 8);
      bf16x8 av = ld8bf(A, (size_t)(bm + r) * 1024 + k0 + g0 * 8, isbf);
      *(bf16x8*)&As[r * 64 + gsw] = av;
      bf16x8 bv = *(const bf16x8*)(Wz + (size_t)(bn + r) * 1024 + k0 + g0 * 8);
      *(bf16x8*)&Bs[r * 64 + gsw] = bv;
    }
    __syncthreads();
    #pragma unroll
    for (int s = 0; s < 2; s++) {
      bf16x8 af[4], bfr[4];
      #pragma unroll
      for (int t = 0; t < 4; t++) {
        int ra = wm + t * 16 + ln15;
        af[t] = *(bf16x8*)&As[ra * 64 + (((s * 4 + quad) ^ (ra & 7)) * 8)];
        int rb = wn + t * 16 + ln15;
        bfr[t] = *(bf16x8*)&Bs[rb * 64 + (((s * 4 + quad) ^ (rb & 7)) * 8)];
      }
      #pragma unroll
      for (int mt = 0; mt < 4; mt++)
        #pragma unroll
        for (int nt = 0; nt < 4; nt++)
          acc[mt][nt] = mfma_bf16(af[mt], bfr[nt], acc[mt][nt]);
    }
    __syncthreads();
  }

  #pragma unroll
  for (int nt = 0; nt < 4; nt++) {
    int col = bn + wn + nt * 16 + ln15;
    float bv = ldx(bias, col, isbf);
    #pragma unroll
    for (int mt = 0; mt < 4; mt++) {
      #pragma unroll
      for (int r = 0; r < 4; r++) {
        int row = bm + wm + mt * 16 + quad * 4 + r;
        float v = (acc[mt][nt][r] + bv) * scale;
        int bb = row >> 9, s = row & 511;
        int h = col >> 6, d0 = col & 63;
        size_t o = vtrans ? (((size_t)(bb * 16 + h) * 64 + d0) * 512 + s)
                          : (((size_t)(bb * 16 + h) * 512 + s) * 64 + d0);
        outB[o] = __float2bfloat16(v);
      }
    }
  }
}

// ---------------------------------------------------------------------------
// Gate GEMMs, z-batched over 5 views (main + 4 edge).
// gated_z = sigmoid(ctx_z @ gate_w_z + gate_b_z) * ctx_z
// ---------------------------------------------------------------------------
__global__ __launch_bounds__(256)
void gate_gemm_k(const bf16* __restrict__ ctx5, const bf16* __restrict__ Wt,
                 const void* __restrict__ gate_b, bf16* __restrict__ gated5,
                 const int* __restrict__ dflag)
{
  const int isbf = *dflag;
  const int z = blockIdx.z;
  const int gsel[5] = {0, 5, 1, 2, 3};
  const bf16* A = ctx5 + (size_t)z * 4194304;
  bf16* outB = gated5 + (size_t)z * 4194304;
  const bf16* Wz = Wt + (size_t)(3 + z) * WSL;
  const size_t boff = (size_t)gsel[z] * 1024;

  __shared__ short As[128 * 64];
  __shared__ short Bs[128 * 64];
  const int tid = threadIdx.x;
  const int w = tid >> 6, ln = tid & 63;
  const int ln15 = ln & 15, quad = ln >> 4;
  const int wm = (w & 1) * 64, wn = (w >> 1) * 64;
  const int bm = blockIdx.x * 128, bn = blockIdx.y * 128;
  const int r0 = tid >> 3, g0 = tid & 7;
  f32x4 acc[4][4];
  #pragma unroll
  for (int mt = 0; mt < 4; mt++)
    #pragma unroll
    for (int nt = 0; nt < 4; nt++) acc[mt][nt] = (f32x4)(0.0f);

  for (int k0 = 0; k0 < 1024; k0 += 64) {
    #pragma unroll
    for (int i = 0; i < 4; i++) {
      int r = r0 + i * 32;
      int gsw = ((g0 ^ (r & 7)) * 8);
      bf16x8 av = *(const bf16x8*)(A + (size_t)(bm + r) * 1024 + k0 + g0 * 8);
      *(bf16x8*)&As[r * 64 + gsw] = av;
      bf16x8 bv = *(const bf16x8*)(Wz + (size_t)(bn + r) * 1024 + k0 + g0 * 8);
      *(bf16x8*)&Bs[r * 64 + gsw] = bv;
    }
    __syncthreads();
    #pragma unroll
    for (int s = 0; s < 2; s++) {
      bf16x8 af[4], bfr[4];
      #pragma unroll
      for (int t = 0; t < 4; t++) {
        int ra = wm + t * 16 + ln15;
        af[t] = *(bf16x8*)&As[ra * 64 + (((s * 4 + quad) ^ (ra & 7)) * 8)];
        int rb = wn + t * 16 + ln15;
        bfr[t] = *(bf16x8*)&Bs[rb * 64 + (((s * 4 + quad) ^ (rb & 7)) * 8)];
      }
      #pragma unroll
      for (int mt = 0; mt < 4; mt++)
        #pragma unroll
        for (int nt = 0; nt < 4; nt++)
          acc[mt][nt] = mfma_bf16(af[mt], bfr[nt], acc[mt][nt]);
    }
    __syncthreads();
  }

  #pragma unroll
  for (int nt = 0; nt < 4; nt++) {
    int col = bn + wn + nt * 16 + ln15;
    float bv = ldx(gate_b, boff + col, isbf);
    #pragma unroll
    for (int mt = 0; mt < 4; mt++) {
      #pragma unroll
      for (int r = 0; r < 4; r++) {
        int row = bm + wm + mt * 16 + quad * 4 + r;
        float v = acc[mt][nt][r] + bv;
        float x = bf2f(A[(size_t)row * 1024 + col]);
        outB[(size_t)row * 1024 + col] = __float2bfloat16(x / (1.f + __expf(-v)));
      }
    }
  }
}

// ---------------------------------------------------------------------------
// Final sub GEMM: out = [gated_0|...|gated_4](4096x5120) @ sub_w(5120x1024)
// + sub_b, written straight to d_out (dtype-aware).
// ---------------------------------------------------------------------------
__global__ __launch_bounds__(256)
void sub_gemm_k(const bf16* __restrict__ gated5, const bf16* __restrict__ Wt,
                const void* __restrict__ sub_b, void* __restrict__ dout,
                const int* __restrict__ dflag)
{
  const int isbf = *dflag;
  __shared__ short As[128 * 64];
  __shared__ short Bs[128 * 64];
  const int tid = threadIdx.x;
  const int w = tid >> 6, ln = tid & 63;
  const int ln15 = ln & 15, quad = ln >> 4;
  const int wm = (w & 1) * 64, wn = (w >> 1) * 64;
  const int bm = blockIdx.x * 128, bn = blockIdx.y * 128;
  const int r0 = tid >> 3, g0 = tid & 7;
  f32x4 acc[4][4];
  #pragma unroll
  for (int mt = 0; mt < 4; mt++)
    #pragma unroll
    for (int nt = 0; nt < 4; nt++) acc[mt][nt] = (f32x4)(0.0f);

  for (int k0 = 0; k0 < 5120; k0 += 64) {
    const int slot = k0 >> 10, kk = k0 & 1023;
    const bf16* Ab = gated5 + (size_t)slot * 4194304;
    const bf16* Wz = Wt + (size_t)(8 + slot) * WSL;
    #pragma unroll
    for (int i = 0; i < 4; i++) {
      int r = r0 + i * 32;
      int gsw = ((g0 ^ (r & 7)) * 8);
      bf16x8 av = *(const bf16x8*)(Ab + (size_t)(bm + r) * 1024 + kk + g0 * 8);
      *(bf16x8*)&As[r * 64 + gsw] = av;
      bf16x8 bv = *(const bf16x8*)(Wz + (size_t)(bn + r) * 1024 + kk + g0 * 8);
      *(bf16x8*)&Bs[r * 64 + gsw] = bv;
    }
    __syncthreads();
    #pragma unroll
    for (int s = 0; s < 2; s++) {
      bf16x8 af[4], bfr[4];
      #pragma unroll
      for (int t = 0; t < 4; t++) {
        int ra = wm + t * 16 + ln15;
        af[t] = *(bf16x8*)&As[ra * 64 + (((s * 4 + quad) ^ (ra & 7)) * 8)];
        int rb = wn + t * 16 + ln15;
        bfr[t] = *(bf16x8*)&Bs[rb * 64 + (((s * 4 + quad) ^ (rb & 7)) * 8)];
      }
      #pragma unroll
      for (int mt = 0; mt < 4; mt++)
        #pragma unroll
        for (int nt = 0; nt < 4; nt++)
          acc[mt][nt] = mfma_bf16(af[mt], bfr[nt], acc[mt][nt]);
    }
    __syncthreads();
  }

  #pragma unroll
  for (int nt = 0; nt < 4; nt++) {
    int col = bn + wn + nt * 16 + ln15;
    float bv = ldx(sub_b, col, isbf);
    #pragma unroll
    for (int mt = 0; mt < 4; mt++) {
      #pragma unroll
      for (int r = 0; r < 4; r++) {
        int row = bm + wm + mt * 16 + quad * 4 + r;
        float v = acc[mt][nt][r] + bv;
        size_t o = (size_t)row * 1024 + col;
        if (isbf) ((bf16*)dout)[o] = __float2bfloat16(v);
        else      ((float*)dout)[o] = v;
      }
    }
  }
}

// ---------------------------------------------------------------------------
// G[row][r] = q_row . rel_emb[r] (bf16 q). One wave per row.
// ---------------------------------------------------------------------------
__global__ __launch_bounds__(256)
void qrel_k(const bf16* __restrict__ qbf, const void* __restrict__ rel_emb,
            float* __restrict__ G, const int* __restrict__ dflag)
{
  const int isbf = *dflag;
  __shared__ float rel[33][65];
  __shared__ float qw[4][64];
  const int tid = threadIdx.x;
  for (int i = tid; i < 33 * 64; i += 256)
    rel[i >> 6][i & 63] = ldx(rel_emb, i, isbf);
  const int wv = tid >> 6, lane = tid & 63;
  const size_t row = (size_t)blockIdx.x * 4 + wv;
  qw[wv][lane] = bf2f(qbf[row * 64 + lane]);
  __syncthreads();
  if (lane < 33) {
    float s = 0.f;
    #pragma unroll
    for (int d = 0; d < 64; d++) s += qw[wv][d] * rel[lane][d];
    G[row * 33 + lane] = s;
  }
}

// ---------------------------------------------------------------------------
// Fully fused main view v4 = v3 with ALL acc-indexing loops FULLY unrolled.
// Round-5 post-mortem (rule #20): '#pragma unroll 4/8' on the QK loop is a
// PARTIAL unroll -> loop var t stays runtime -> acc[t] runtime-indexed ->
// whole acc[32] array allocated in scratch (VGPR 84, 537 MB spill writes,
// matches WRITE_SIZE). Round 3 worked (VGPR 192, 16 MB) because its loops
// auto-FULLY-unrolled. Fix: '#pragma unroll' (no count) on the QK loop and
// all softmax loops so every acc index is a compile-time constant.
// __launch_bounds__(256,2) kept: 256-VGPR budget holds acc(128)+frags.
// ---------------------------------------------------------------------------
__global__ __launch_bounds__(256, 2)
void score_fused_k(const bf16* __restrict__ qbf, const bf16* __restrict__ kbf,
                   const float* __restrict__ G, const bf16* __restrict__ vt,
                   const void* __restrict__ rel_emb, bf16* __restrict__ ctx,
                   void* __restrict__ dout, const int* __restrict__ dflag)
{
  __shared__ short Pw[4][16 * 256];   // 32 KB, per-wave private
  __shared__ float gbuf[64 * 33];     // 8448 B
  __shared__ float relbuf[33 * 64];   // 8448 B
  const int tid = threadIdx.x;
  const int w = tid >> 6, ln = tid & 63;
  const int ln15 = ln & 15, quad = ln >> 4;
  const int bh = blockIdx.x, qt = blockIdx.y;
  const size_t qrow0 = (size_t)bh * 512 + qt * 64;
  const int isbf = *dflag;

  // stage G (this block's 64 rows) + rel into LDS (one barrier, after QK)
  for (int i = tid; i < 64 * 33; i += 256) {
    int r = i / 33, c = i - r * 33;
    gbuf[i] = G[(qrow0 + r) * 33 + c];
  }
  for (int i = tid; i < 33 * 64; i += 256)
    relbuf[i] = ldx(rel_emb, i, isbf);

  // ---- QK^T: fragments straight from global, zero barriers ----
  // FULL unroll: acc[t] must be compile-time indexed (rule #20).
  const bf16* qrow = qbf + (qrow0 + w * 16 + ln15) * 64;
  bf16x8 af0 = *(const bf16x8*)(qrow + quad * 8);
  bf16x8 af1 = *(const bf16x8*)(qrow + 32 + quad * 8);
  const bf16* kb = kbf + (size_t)bh * 512 * 64;
  f32x4 acc[32];
  #pragma unroll
  for (int t = 0; t < 32; t++) acc[t] = (f32x4)(0.0f);
  #pragma unroll
  for (int t = 0; t < 32; t++) {
    const bf16* kr = kb + (size_t)(t * 16 + ln15) * 64 + quad * 8;
    bf16x8 b0 = *(const bf16x8*)kr;
    bf16x8 b1 = *(const bf16x8*)(kr + 32);
    acc[t] = mfma_bf16(af0, b0, acc[t]);
    acc[t] = mfma_bf16(af1, b1, acc[t]);
  }
  __syncthreads();   // gbuf/relbuf now valid

  // ---- rel bias + softmax (identical math to verified score_k) ----
  const int qg = qt * 64 + w * 16 + quad * 4;
  const int rowl0 = w * 16 + quad * 4;
  float mx[4], ssum[4], sle[4], sge[4];
  #pragma unroll
  for (int r = 0; r < 4; r++) mx[r] = -3.0e38f;
  #pragma unroll
  for (int t = 0; t < 32; t++) {
    int k = t * 16 + ln15;
    #pragma unroll
    for (int r = 0; r < 4; r++) {
      int delta = k - (qg + r);
      int bkt = delta < -16 ? 0 : (delta > 16 ? 32 : delta + 16);
      float s = acc[t][r] + gbuf[(rowl0 + r) * 33 + bkt];
      acc[t][r] = s;
      mx[r] = fmaxf(mx[r], s);
    }
  }
  #pragma unroll
  for (int r = 0; r < 4; r++) {
    float m = mx[r];
    #pragma unroll
    for (int off = 1; off < 16; off <<= 1) m = fmaxf(m, __shfl_xor(m, off));
    mx[r] = m;
    ssum[r] = 0.f; sle[r] = 0.f; sge[r] = 0.f;
  }
  #pragma unroll
  for (int t = 0; t < 32; t++) {
    int k = t * 16 + ln15;
    #pragma unroll
    for (int r = 0; r < 4; r++) {
      float p = __expf(acc[t][r] - mx[r]);
      acc[t][r] = p;
      ssum[r] += p;
      int delta = k - (qg + r);
      if (delta <= -16) sle[r] += p;
      if (delta >= 16) sge[r] += p;
    }
  }
  #pragma unroll
  for (int r = 0; r < 4; r++) {
    #pragma unroll
    for (int off = 1; off < 16; off <<= 1) {
      ssum[r] += __shfl_xor(ssum[r], off);
      sle[r] += __shfl_xor(sle[r], off);
      sge[r] += __shfl_xor(sge[r], off);
    }
  }
  float inv[4];
  #pragma unroll
  for (int r = 0; r < 4; r++) inv[r] = 1.f / ssum[r];

  // ---- per-wave P (16 rows), k in two 256-halves; PV + band + top_attn ----
  short* Pm = Pw[w];
  const bf16* vb = vt + (size_t)bh * 64 * 512;
  const int toph = ((bh & 15) == 0);
  const int bg = bh >> 4;
  f32x4 pacc[4];
  #pragma unroll
  for (int nt = 0; nt < 4; nt++) pacc[nt] = (f32x4)(0.0f);

  #pragma unroll
  for (int h = 0; h < 2; h++) {
    // store this half's P (normalized bf16), swizzled 16B groups
    #pragma unroll
    for (int t2 = 0; t2 < 16; t2++) {
      int gg = t2 * 2 + (ln15 >> 3);        // logical group = col>>3
      int slot = gg ^ (quad << 1);          // ((rowL>>2)&3)==quad for rowL=quad*4+r
      #pragma unroll
      for (int r = 0; r < 4; r++) {
        int rowL = quad * 4 + r;
        Pm[rowL * 256 + slot * 8 + (ln15 & 7)] =
            (short)f2us(acc[h * 16 + t2][r] * inv[r]);
      }
    }
    __syncthreads();

    // top_attn (head-0 blocks only): wave writes its own 16 rows, this half
    if (toph) {
      for (int i = ln; i < 16 * 32; i += 64) {
        int rowL = i >> 5, gg = i & 31;
        int slot = gg ^ (((rowL >> 2) & 3) << 1);
        bf16x8 u = *(bf16x8*)&Pm[rowL * 256 + slot * 8];
        size_t o = (size_t)4194304 + (size_t)bg * 262144 +
                   (size_t)(qt * 64 + w * 16 + rowL) * 512 + h * 256 + gg * 8;
        if (isbf) {
          *(bf16x8*)((bf16*)dout + o) = u;
        } else {
          float4 f0 = make_float4(us2f((unsigned short)u[0]), us2f((unsigned short)u[1]),
                                  us2f((unsigned short)u[2]), us2f((unsigned short)u[3]));
          float4 f1 = make_float4(us2f((unsigned short)u[4]), us2f((unsigned short)u[5]),
                                  us2f((unsigned short)u[6]), us2f((unsigned short)u[7]));
          *(float4*)((float*)dout + o) = f0;
          *(float4*)((float*)dout + o + 4) = f1;
        }
      }
    }

    // PV over this half: A from Pm (own rows), V fragments from global
    {
      const int rsw = ((ln15 >> 2) & 3) << 1;
      #pragma unroll
      for (int kk = 0; kk < 8; kk++) {
        int gg = kk * 4 + quad;
        bf16x8 a = *(bf16x8*)&Pm[ln15 * 256 + ((gg ^ rsw) * 8)];
        int k0 = h * 256 + kk * 32;
        #pragma unroll
        for (int nt = 0; nt < 4; nt++) {
          bf16x8 b = *(const bf16x8*)(vb + (size_t)(nt * 16 + ln15) * 512 + k0 + quad * 8);
          pacc[nt] = mfma_bf16(a, b, pacc[nt]);
        }
      }
    }

    // diagonal band of arel@rel for k in this half (rel from LDS)
    for (int rr = 1; rr < 32; rr++) {
      float av[4];
      #pragma unroll
      for (int r = 0; r < 4; r++) {
        int k = qg + r + rr - 16;
        av[r] = 0.f;
        if (k >= h * 256 && k < (h + 1) * 256) {
          int kl = k - h * 256;
          int rowL = quad * 4 + r;
          int slot = (kl >> 3) ^ (quad << 1);
          av[r] = us2f((unsigned short)Pm[rowL * 256 + slot * 8 + (kl & 7)]);
        }
      }
      #pragma unroll
      for (int nt = 0; nt < 4; nt++) {
        float relv = relbuf[rr * 64 + nt * 16 + ln15];
        #pragma unroll
        for (int r = 0; r < 4; r++) pacc[nt][r] += av[r] * relv;
      }
    }
    __syncthreads();   // before overwriting Pm with next half
  }

  // sle/sge terms (buckets 0 and 32)
  #pragma unroll
  for (int nt = 0; nt < 4; nt++) {
    float r0v = relbuf[nt * 16 + ln15];
    float r32v = relbuf[32 * 64 + nt * 16 + ln15];
    #pragma unroll
    for (int r = 0; r < 4; r++)
      pacc[nt][r] += sle[r] * inv[r] * r0v + sge[r] * inv[r] * r32v;
  }

  // ctx write (slot 0 layout [bl*512+s][1024])
  const int bl = bh >> 4, head = bh & 15;
  #pragma unroll
  for (int r = 0; r < 4; r++) {
    int s = qt * 64 + rowl0 + r;
    #pragma unroll
    for (int nt = 0; nt < 4; nt++)
      ctx[((size_t)bl * 512 + s) * 1024 + head * 64 + nt * 16 + ln15] =
          __float2bfloat16(pacc[nt][r]);
  }
}

// ---------------------------------------------------------------------------
// Edge h-projections, z-batched over 4 views (blockIdx.y).
// ---------------------------------------------------------------------------
__global__ __launch_bounds__(256)
void hv_k(const bf16* __restrict__ vt, const void* __restrict__ att_w,
          const void* __restrict__ att_b, float* __restrict__ h0,
          float* __restrict__ h1, const int* __restrict__ dflag)
{
  const int i0s[4] = {6, 0, 2, 4};
  const int i1s[4] = {7, 1, 3, 5};
  const int z = blockIdx.y;
  const int i0 = i0s[z], i1 = i1s[z];
  __shared__ float w0[64], w1[64];
  const int tid = threadIdx.x;
  const int bh = blockIdx.x;
  const int isbf = *dflag;
  if (tid < 64) {
    w0[tid] = ldx(att_w, i0 * 64 + tid, isbf);
    w1[tid] = ldx(att_w, i1 * 64 + tid, isbf);
  }
  __syncthreads();
  const bf16* vb = vt + (size_t)bh * 64 * 512 + tid * 2;
  float a00 = 0, a01 = 0, a10 = 0, a11 = 0;
  for (int d = 0; d < 64; d++) {
    ushort2 u = *(const ushort2*)(vb + (size_t)d * 512);
    float f0 = us2f(u.x), f1 = us2f(u.y);
    a00 += f0 * w0[d]; a10 += f1 * w0[d];
    a01 += f0 * w1[d]; a11 += f1 * w1[d];
  }
  float b0 = ldx(att_b, i0, isbf), b1 = ldx(att_b, i1, isbf);
  float* p0 = h0 + (size_t)z * 65536 + (size_t)bh * 512 + tid * 2;
  float* p1 = h1 + (size_t)z * 65536 + (size_t)bh * 512 + tid * 2;
  p0[0] = a00 + b0; p0[1] = a10 + b0;
  p1[0] = a01 + b1; p1[1] = a11 + b1;
}

// ---------------------------------------------------------------------------
// Fused edge view, z-batched over the 4 views (blockIdx.z). Verified round-2
// structure: 32 q-rows/block, 32KB LDS P, softmax per wave-row, PV with V
// fragments from global. Writes ctx5 slot (1+view).
// ---------------------------------------------------------------------------
__global__ __launch_bounds__(256)
void edge_fused_k(const float* __restrict__ h0, const float* __restrict__ h1,
                  const int* __restrict__ grh, const bf16* __restrict__ vt,
                  bf16* __restrict__ ctx5)
{
  __shared__ short P[32 * 512];   // 32 KB
  const int tid = threadIdx.x;
  const int w = tid >> 6, ln = tid & 63;
  const int ln15 = ln & 15, quad = ln >> 4;
  const int bh = blockIdx.x, qt = blockIdx.y, view = blockIdx.z;
  const int bl = bh >> 4;
  bf16* ctx = ctx5 + (size_t)(1 + view) * 4194304;

  // ---- phase 1: rows w*8 .. w*8+7, one full wave per row ----
  const int kb = ln * 8;
  {
    const float* hjp = h1 + (size_t)view * 65536 + (size_t)bh * 512 + kb;
    float4 hA = *(const float4*)hjp;
    float4 hB = *(const float4*)(hjp + 4);
    float hjv[8] = {hA.x, hA.y, hA.z, hA.w, hB.x, hB.y, hB.z, hB.w};
    const float* h0b = h0 + (size_t)view * 65536 + (size_t)bh * 512 + qt * 32 + w * 8;
    const int* grow = grh + ((size_t)bl * 512 + qt * 32 + w * 8) * 512 + kb;

    int4 ga = *(const int4*)grow;
    int4 gb = *(const int4*)(grow + 4);
    #pragma unroll 2
    for (int rr = 0; rr < 8; rr++) {
      int rn = rr < 7 ? rr + 1 : rr;
      const int* gn = grow + (size_t)rn * 512;
      int4 gan = *(const int4*)gn;
      int4 gbn = *(const int4*)(gn + 4);
      int r = w * 8 + rr;              // local row in P, 0..31
      int qi = qt * 32 + r;            // global q index, 0..511
      float hi = h0b[rr];
      int g[8] = {ga.x, ga.y, ga.z, ga.w, gb.x, gb.y, gb.z, gb.w};
      float e[8];
      float m = -3.0e38f;
      #pragma unroll
      for (int j = 0; j < 8; j++) {
        float ej = hi + hjv[j];
        ej = ej >= 0.f ? ej : 0.01f * ej;
        int k = kb + j;
        bool adj;
        if (view == 0) adj = g[j] > 1;
        else if (view == 1) adj = g[j] == ((k == qi) ? 4 : 2);
        else if (view == 2) adj = g[j] == ((k == qi) ? 4 : 3);
        else adj = g[j] == 4;
        e[j] = adj ? ej : NEGV;
        m = fmaxf(m, e[j]);
      }
      #pragma unroll
      for (int off = 32; off; off >>= 1) m = fmaxf(m, __shfl_xor(m, off));
      float ssum = 0.f;
      #pragma unroll
      for (int j = 0; j < 8; j++) { e[j] = __expf(e[j] - m); ssum += e[j]; }
      #pragma unroll
      for (int off = 32; off; off >>= 1) ssum += __shfl_xor(ssum, off);
      float inv = 1.f / ssum;
      bf16x8 pv;
      #pragma unroll
      for (int j = 0; j < 8; j++) pv[j] = (short)f2us(e[j] * inv);
      *(bf16x8*)&P[r * 512 + ((ln ^ (r & 7)) * 8)] = pv;
      ga = gan; gb = gbn;
    }
  }
  __syncthreads();

  // ---- phase 2: ctx[rows, d] = P @ V^T, V straight from global ----
  const bf16* vb = vt + (size_t)bh * 64 * 512;
  const int m0 = (w >> 1) * 16, d0 = (w & 1) * 32;
  f32x4 acc[2];
  acc[0] = (f32x4)(0.0f); acc[1] = (f32x4)(0.0f);

  const int ra = m0 + ln15;
  const int rsw = ra & 7;
  #pragma unroll 4
  for (int k0 = 0; k0 < 512; k0 += 32) {
    int gsel = (k0 >> 3) + quad;
    bf16x8 a = *(bf16x8*)&P[ra * 512 + ((gsel ^ rsw) * 8)];
    #pragma unroll
    for (int nt = 0; nt < 2; nt++) {
      bf16x8 b = *(const bf16x8*)(vb + (size_t)(d0 + nt * 16 + ln15) * 512 + k0 + quad * 8);
      acc[nt] = mfma_bf16(a, b, acc[nt]);
    }
  }

  const int head = bh & 15;
  #pragma unroll
  for (int r = 0; r < 4; r++) {
    int s = qt * 32 + m0 + quad * 4 + r;
    #pragma unroll
    for (int nt = 0; nt < 2; nt++)
      ctx[((size_t)bl * 512 + s) * 1024 + head * 64 + d0 + nt * 16 + ln15] =
          __float2bfloat16(acc[nt][r]);
  }
}

// ---------------------------------------------------------------------------
extern "C" void kernel_launch(void* const* d_in, const int* in_sizes, int n_in,
                              void* d_out, int out_size, void* d_ws, size_t ws_size,
                              hipStream_t stream)
{
  const void* key   = d_in[0];
  const void* value = d_in[1];
  const void* query = d_in[2];
  const int*  grh   = (const int*)d_in[3];
  const void* Wq = d_in[5];
  const void* bq = d_in[6];
  const void* Wk = d_in[7];
  const void* bk = d_in[8];
  const void* Wv = d_in[9];
  const void* bv = d_in[10];
  const void* rel_emb = d_in[11];
  const void* att_w = d_in[12];
  const void* att_b = d_in[13];
  const void* gate_w = d_in[14];
  const void* gate_b = d_in[15];
  const void* sub_w = d_in[16];
  const void* sub_b = d_in[17];

  // workspace layout (floats) — total 36,765,712 fl = 147 MB
  int* dflag = (int*)d_ws;
  float* base = (float*)d_ws;
  bf16* qbf = (bf16*)(base + 16);
  bf16* kbf = (bf16*)(base + 16 + 2097152);
  bf16* vtb = (bf16*)(base + 16 + 2 * 2097152);
  bf16* Wt  = (bf16*)(base + 16 + 3 * 2097152);
  float* G  = base + 16 + 3 * 2097152 + 6815744;
  float* h0 = G + 2162688;
  float* h1 = h0 + 262144;
  bf16* ctx5   = (bf16*)(h1 + 262144);
  bf16* gated5 = ctx5 + 5ull * 4194304;

  detect_k<<<dim3(1), dim3(64), 0, stream>>>(Wq, dflag);

  // all 13 weight transposes in one launch
  wtrans_all_k<<<dim3(13 * 256), dim3(256), 0, stream>>>(
      Wq, Wk, Wv, gate_w, sub_w, Wt, dflag);

  // QKV projections batched (z: 0=q scaled, 1=k, 2=v transposed)
  qkv_gemm_k<<<dim3(32, 8, 3), dim3(256), 0, stream>>>(
      query, key, value, Wt, bq, bk, bv, qbf, kbf, vtb, dflag);

  qrel_k<<<dim3(16384), dim3(256), 0, stream>>>(qbf, rel_emb, G, dflag);

  // main view fully fused -> ctx5 slot 0 (+ top_attn to d_out)
  score_fused_k<<<dim3(128, 8), dim3(256), 0, stream>>>(
      qbf, kbf, G, vtb, rel_emb, ctx5, d_out, dflag);

  // edge views: h projections (4 views batched), then fused softmax+PV
  hv_k<<<dim3(128, 4), dim3(256), 0, stream>>>(vtb, att_w, att_b, h0, h1, dflag);
  edge_fused_k<<<dim3(128, 16, 4), dim3(256), 0, stream>>>(
      h0, h1, grh, vtb, ctx5);

  // 5 gate GEMMs batched, then one K=5120 sub GEMM straight to d_out
  gate_gemm_k<<<dim3(32, 8, 5), dim3(256), 0, stream>>>(
      ctx5, Wt, gate_b, gated5, dflag);
  sub_gemm_k<<<dim3(32, 8), dim3(256), 0, stream>>>(
      gated5, Wt, sub_b, d_out, dflag);
}

// Round 7
// 854.490 us; speedup vs baseline: 1.1983x; 1.0436x over previous
//
#include <hip/hip_runtime.h>
#include <hip/hip_bf16.h>

typedef __hip_bfloat16 bf16;
typedef __attribute__((ext_vector_type(8))) short bf16x8;
typedef __attribute__((ext_vector_type(4))) float f32x4;

#define B_ 8
#define S_ 512
#define D_ 1024
#define H_ 16
#define NEGV -9.0e15f
#define WSL 1048576ull

__device__ __forceinline__ float bf2f(bf16 x) { return __bfloat162float(x); }
__device__ __forceinline__ float us2f(unsigned short u) {
  union { unsigned int i; float f; } c; c.i = ((unsigned int)u) << 16; return c.f;
}
__device__ __forceinline__ unsigned short f2us(float f) {
  bf16 h = __float2bfloat16(f);
  unsigned short u; __builtin_memcpy(&u, &h, 2); return u;
}
__device__ __forceinline__ float ldx(const void* p, size_t i, int isbf) {
  return isbf ? bf2f(((const bf16*)p)[i]) : ((const float*)p)[i];
}
struct F4 { float x, y, z, w; };
__device__ __forceinline__ F4 ld4(const void* p, size_t i, int isbf) {
  F4 r;
  if (isbf) {
    ushort4 u = *(const ushort4*)((const bf16*)p + i);
    r.x = us2f(u.x); r.y = us2f(u.y); r.z = us2f(u.z); r.w = us2f(u.w);
  } else {
    float4 d = *(const float4*)((const float*)p + i);
    r.x = d.x; r.y = d.y; r.z = d.z; r.w = d.w;
  }
  return r;
}
// 8 consecutive elements as bf16x8; converts if source is f32
__device__ __forceinline__ bf16x8 ld8bf(const void* p, size_t i, int isbf) {
  if (isbf) return *(const bf16x8*)((const bf16*)p + i);
  float4 a = *(const float4*)((const float*)p + i);
  float4 b = *(const float4*)((const float*)p + i + 4);
  bf16x8 r;
  r[0] = (short)f2us(a.x); r[1] = (short)f2us(a.y);
  r[2] = (short)f2us(a.z); r[3] = (short)f2us(a.w);
  r[4] = (short)f2us(b.x); r[5] = (short)f2us(b.y);
  r[6] = (short)f2us(b.z); r[7] = (short)f2us(b.w);
  return r;
}
__device__ __forceinline__ f32x4 mfma_bf16(bf16x8 a, bf16x8 b, f32x4 c) {
  return __builtin_amdgcn_mfma_f32_16x16x32_bf16(a, b, c, 0, 0, 0);
}

// Dtype detector (round-3 verified: picks f32 on this harness).
__global__ void detect_k(const void* __restrict__ w, int* __restrict__ flag)
{
  if (threadIdx.x == 0 && blockIdx.x == 0) {
    const unsigned short* u = (const unsigned short*)w;
    int sane = 0;
    for (int i = 0; i < 1024; i += 2) {
      float a = fabsf(us2f(u[i]));
      if (a == 0.f || (a > 9.5e-7f && a < 8.f)) sane++;
    }
    *flag = (sane > 256) ? 1 : 0;
  }
}

// ---------------------------------------------------------------------------
// Mask bit-planes: grh (8.4 MB int32, logically read 64x by edge views) ->
// 4 views x 8 batches x 512 q x 64 bytes = 1 MB of packed adjacency bits
// (diagonal/eye rule folded in). Read once, L2-resident thereafter.
// maskp[view*262144 + bl*32768 + qi*64 + byte], bit j = k = byte*8 + j.
// ---------------------------------------------------------------------------
__global__ __launch_bounds__(256)
void mask_pack_k(const int* __restrict__ grh, unsigned char* __restrict__ maskp)
{
  int t = blockIdx.x * 256 + threadIdx.x;     // [0, 8*512*64)
  int byte = t & 63, qi = (t >> 6) & 511, bl = t >> 15;
  const int* g = grh + ((size_t)bl * 512 + qi) * 512 + byte * 8;
  int4 a = *(const int4*)g;
  int4 b = *(const int4*)(g + 4);
  int gs[8] = {a.x, a.y, a.z, a.w, b.x, b.y, b.z, b.w};
  unsigned int m0 = 0, m1 = 0, m2 = 0, m3 = 0;
  #pragma unroll
  for (int j = 0; j < 8; j++) {
    int k = byte * 8 + j;
    int diag = (k == qi);
    m0 |= (unsigned int)(gs[j] > 1) << j;
    m1 |= (unsigned int)(gs[j] == (diag ? 4 : 2)) << j;
    m2 |= (unsigned int)(gs[j] == (diag ? 4 : 3)) << j;
    m3 |= (unsigned int)(gs[j] == 4) << j;
  }
  size_t o = (size_t)bl * 32768 + (size_t)qi * 64 + byte;
  maskp[o]          = (unsigned char)m0;
  maskp[o + 262144] = (unsigned char)m1;
  maskp[o + 524288] = (unsigned char)m2;
  maskp[o + 786432] = (unsigned char)m3;
}

// ---------------------------------------------------------------------------
// ALL 13 weight transposes in one launch. slot = blockIdx.x>>8:
// 0..2 = Wq,Wk,Wv; 3..7 = gate_w srcs {0,5,1,2,3}; 8..12 = sub_w rows c.
// out[n][k] (bf16, 1024x1024) <- W[k][n] (per dflag dtype).
// ---------------------------------------------------------------------------
__global__ __launch_bounds__(256)
void wtrans_all_k(const void* __restrict__ Wq, const void* __restrict__ Wk,
                  const void* __restrict__ Wv, const void* __restrict__ gate_w,
                  const void* __restrict__ sub_w, bf16* __restrict__ Wt,
                  const int* __restrict__ dflag)
{
  const int isbf = *dflag;
  const int slot = blockIdx.x >> 8;
  const int blk = blockIdx.x & 255;
  const int gsrc[5] = {0, 5, 1, 2, 3};
  const void* W;
  size_t woff;
  if (slot < 3)      { W = slot == 0 ? Wq : (slot == 1 ? Wk : Wv); woff = 0; }
  else if (slot < 8) { W = gate_w; woff = (size_t)gsrc[slot - 3] * WSL; }
  else               { W = sub_w;  woff = (size_t)(slot - 8) * WSL; }
  bf16* out = Wt + (size_t)slot * WSL;

  __shared__ float t[64][68];
  const int tid = threadIdx.x;
  const int nt = blk & 15, kt = blk >> 4;
  {
    int r = tid >> 4, c4 = (tid & 15) * 4;
    #pragma unroll
    for (int i = 0; i < 4; i++) {
      int rr = r + i * 16;
      F4 v = ld4(W, woff + (size_t)(kt * 64 + rr) * 1024 + nt * 64 + c4, isbf);
      *(float4*)&t[rr][c4] = make_float4(v.x, v.y, v.z, v.w);
    }
  }
  __syncthreads();
  {
    int n = tid >> 4, k4 = (tid & 15) * 4;
    #pragma unroll
    for (int i = 0; i < 4; i++) {
      int nn = n + i * 16;
      ushort4 u;
      u.x = f2us(t[k4 + 0][nn]); u.y = f2us(t[k4 + 1][nn]);
      u.z = f2us(t[k4 + 2][nn]); u.w = f2us(t[k4 + 3][nn]);
      *(ushort4*)(out + (size_t)(nt * 64 + nn) * 1024 + kt * 64 + k4) = u;
    }
  }
}

// ---------------------------------------------------------------------------
// QKV projections, z-batched (z=0:q scaled, z=1:k, z=2:v transposed).
// 128x128 tile, BK=64, XOR-swizzled LDS (verified core).
// ---------------------------------------------------------------------------
__global__ __launch_bounds__(256)
void qkv_gemm_k(const void* __restrict__ Aq, const void* __restrict__ Ak,
                const void* __restrict__ Av, const bf16* __restrict__ Wt,
                const void* __restrict__ bqp, const void* __restrict__ bkp,
                const void* __restrict__ bvp, bf16* __restrict__ qbf,
                bf16* __restrict__ kbf, bf16* __restrict__ vtb,
                const int* __restrict__ dflag)
{
  const int isbf = *dflag;
  const int z = blockIdx.z;
  const void* A = z == 0 ? Aq : (z == 1 ? Ak : Av);
  const void* bias = z == 0 ? bqp : (z == 1 ? bkp : bvp);
  bf16* outB = z == 0 ? qbf : (z == 1 ? kbf : vtb);
  const bf16* Wz = Wt + (size_t)z * WSL;
  const float scale = z == 0 ? 0.125f : 1.0f;
  const int vtrans = (z == 2);

  __shared__ short As[128 * 64];
  __shared__ short Bs[128 * 64];
  const int tid = threadIdx.x;
  const int w = tid >> 6, ln = tid & 63;
  const int ln15 = ln & 15, quad = ln >> 4;
  const int wm = (w & 1) * 64, wn = (w >> 1) * 64;
  const int bm = blockIdx.x * 128, bn = blockIdx.y * 128;
  const int r0 = tid >> 3, g0 = tid & 7;
  f32x4 acc[4][4];
  #pragma unroll
  for (int mt = 0; mt < 4; mt++)
    #pragma unroll
    for (int nt = 0; nt < 4; nt++) acc[mt][nt] = (f32x4)(0.0f);

  for (int k0 = 0; k0 < 1024; k0 += 64) {
    #pragma unroll
    for (int i = 0; i < 4; i++) {
      int r = r0 + i * 32;
      int gsw = ((g0 ^ (r & 7)) * 8);
      bf16x8 av = ld8bf(A, (size_t)(bm + r) * 1024 + k0 + g0 * 8, isbf);
      *(bf16x8*)&As[r * 64 + gsw] = av;
      bf16x8 bv = *(const bf16x8*)(Wz + (size_t)(bn + r) * 1024 + k0 + g0 * 8);
      *(bf16x8*)&Bs[r * 64 + gsw] = bv;
    }
    __syncthreads();
    #pragma unroll
    for (int s = 0; s < 2; s++) {
      bf16x8 af[4], bfr[4];
      #pragma unroll
      for (int t = 0; t < 4; t++) {
        int ra = wm + t * 16 + ln15;
        af[t] = *(bf16x8*)&As[ra * 64 + (((s * 4 + quad) ^ (ra & 7)) * 8)];
        int rb = wn + t * 16 + ln15;
        bfr[t] = *(bf16x8*)&Bs[rb * 64 + (((s * 4 + quad) ^ (rb & 7)) * 8)];
      }
      #pragma unroll
      for (int mt = 0; mt < 4; mt++)
        #pragma unroll
        for (int nt = 0; nt < 4; nt++)
          acc[mt][nt] = mfma_bf16(af[mt], bfr[nt], acc[mt][nt]);
    }
    __syncthreads();
  }

  #pragma unroll
  for (int nt = 0; nt < 4; nt++) {
    int col = bn + wn + nt * 16 + ln15;
    float bv = ldx(bias, col, isbf);
    #pragma unroll
    for (int mt = 0; mt < 4; mt++) {
      #pragma unroll
      for (int r = 0; r < 4; r++) {
        int row = bm + wm + mt * 16 + quad * 4 + r;
        float v = (acc[mt][nt][r] + bv) * scale;
        int bb = row >> 9, s = row & 511;
        int h = col >> 6, d0 = col & 63;
        size_t o = vtrans ? (((size_t)(bb * 16 + h) * 64 + d0) * 512 + s)
                          : (((size_t)(bb * 16 + h) * 512 + s) * 64 + d0);
        outB[o] = __float2bfloat16(v);
      }
    }
  }
}

// ---------------------------------------------------------------------------
// Gate GEMMs, z-batched over 5 views (main + 4 edge).
// gated_z = sigmoid(ctx_z @ gate_w_z + gate_b_z) * ctx_z
// ---------------------------------------------------------------------------
__global__ __launch_bounds__(256)
void gate_gemm_k(const bf16* __restrict__ ctx5, const bf16* __restrict__ Wt,
                 const void* __restrict__ gate_b, bf16* __restrict__ gated5,
                 const int* __restrict__ dflag)
{
  const int isbf = *dflag;
  const int z = blockIdx.z;
  const int gsel[5] = {0, 5, 1, 2, 3};
  const bf16* A = ctx5 + (size_t)z * 4194304;
  bf16* outB = gated5 + (size_t)z * 4194304;
  const bf16* Wz = Wt + (size_t)(3 + z) * WSL;
  const size_t boff = (size_t)gsel[z] * 1024;

  __shared__ short As[128 * 64];
  __shared__ short Bs[128 * 64];
  const int tid = threadIdx.x;
  const int w = tid >> 6, ln = tid & 63;
  const int ln15 = ln & 15, quad = ln >> 4;
  const int wm = (w & 1) * 64, wn = (w >> 1) * 64;
  const int bm = blockIdx.x * 128, bn = blockIdx.y * 128;
  const int r0 = tid >> 3, g0 = tid & 7;
  f32x4 acc[4][4];
  #pragma unroll
  for (int mt = 0; mt < 4; mt++)
    #pragma unroll
    for (int nt = 0; nt < 4; nt++) acc[mt][nt] = (f32x4)(0.0f);

  for (int k0 = 0; k0 < 1024; k0 += 64) {
    #pragma unroll
    for (int i = 0; i < 4; i++) {
      int r = r0 + i * 32;
      int gsw = ((g0 ^ (r & 7)) * 8);
      bf16x8 av = *(const bf16x8*)(A + (size_t)(bm + r) * 1024 + k0 + g0 * 8);
      *(bf16x8*)&As[r * 64 + gsw] = av;
      bf16x8 bv = *(const bf16x8*)(Wz + (size_t)(bn + r) * 1024 + k0 + g0 * 8);
      *(bf16x8*)&Bs[r * 64 + gsw] = bv;
    }
    __syncthreads();
    #pragma unroll
    for (int s = 0; s < 2; s++) {
      bf16x8 af[4], bfr[4];
      #pragma unroll
      for (int t = 0; t < 4; t++) {
        int ra = wm + t * 16 + ln15;
        af[t] = *(bf16x8*)&As[ra * 64 + (((s * 4 + quad) ^ (ra & 7)) * 8)];
        int rb = wn + t * 16 + ln15;
        bfr[t] = *(bf16x8*)&Bs[rb * 64 + (((s * 4 + quad) ^ (rb & 7)) * 8)];
      }
      #pragma unroll
      for (int mt = 0; mt < 4; mt++)
        #pragma unroll
        for (int nt = 0; nt < 4; nt++)
          acc[mt][nt] = mfma_bf16(af[mt], bfr[nt], acc[mt][nt]);
    }
    __syncthreads();
  }

  #pragma unroll
  for (int nt = 0; nt < 4; nt++) {
    int col = bn + wn + nt * 16 + ln15;
    float bv = ldx(gate_b, boff + col, isbf);
    #pragma unroll
    for (int mt = 0; mt < 4; mt++) {
      #pragma unroll
      for (int r = 0; r < 4; r++) {
        int row = bm + wm + mt * 16 + quad * 4 + r;
        float v = acc[mt][nt][r] + bv;
        float x = bf2f(A[(size_t)row * 1024 + col]);
        outB[(size_t)row * 1024 + col] = __float2bfloat16(x / (1.f + __expf(-v)));
      }
    }
  }
}

// ---------------------------------------------------------------------------
// Final sub GEMM: out = [gated_0|...|gated_4](4096x5120) @ sub_w(5120x1024)
// + sub_b, written straight to d_out (dtype-aware).
// ---------------------------------------------------------------------------
__global__ __launch_bounds__(256)
void sub_gemm_k(const bf16* __restrict__ gated5, const bf16* __restrict__ Wt,
                const void* __restrict__ sub_b, void* __restrict__ dout,
                const int* __restrict__ dflag)
{
  const int isbf = *dflag;
  __shared__ short As[128 * 64];
  __shared__ short Bs[128 * 64];
  const int tid = threadIdx.x;
  const int w = tid >> 6, ln = tid & 63;
  const int ln15 = ln & 15, quad = ln >> 4;
  const int wm = (w & 1) * 64, wn = (w >> 1) * 64;
  const int bm = blockIdx.x * 128, bn = blockIdx.y * 128;
  const int r0 = tid >> 3, g0 = tid & 7;
  f32x4 acc[4][4];
  #pragma unroll
  for (int mt = 0; mt < 4; mt++)
    #pragma unroll
    for (int nt = 0; nt < 4; nt++) acc[mt][nt] = (f32x4)(0.0f);

  for (int k0 = 0; k0 < 5120; k0 += 64) {
    const int slot = k0 >> 10, kk = k0 & 1023;
    const bf16* Ab = gated5 + (size_t)slot * 4194304;
    const bf16* Wz = Wt + (size_t)(8 + slot) * WSL;
    #pragma unroll
    for (int i = 0; i < 4; i++) {
      int r = r0 + i * 32;
      int gsw = ((g0 ^ (r & 7)) * 8);
      bf16x8 av = *(const bf16x8*)(Ab + (size_t)(bm + r) * 1024 + kk + g0 * 8);
      *(bf16x8*)&As[r * 64 + gsw] = av;
      bf16x8 bv = *(const bf16x8*)(Wz + (size_t)(bn + r) * 1024 + kk + g0 * 8);
      *(bf16x8*)&Bs[r * 64 + gsw] = bv;
    }
    __syncthreads();
    #pragma unroll
    for (int s = 0; s < 2; s++) {
      bf16x8 af[4], bfr[4];
      #pragma unroll
      for (int t = 0; t < 4; t++) {
        int ra = wm + t * 16 + ln15;
        af[t] = *(bf16x8*)&As[ra * 64 + (((s * 4 + quad) ^ (ra & 7)) * 8)];
        int rb = wn + t * 16 + ln15;
        bfr[t] = *(bf16x8*)&Bs[rb * 64 + (((s * 4 + quad) ^ (rb & 7)) * 8)];
      }
      #pragma unroll
      for (int mt = 0; mt < 4; mt++)
        #pragma unroll
        for (int nt = 0; nt < 4; nt++)
          acc[mt][nt] = mfma_bf16(af[mt], bfr[nt], acc[mt][nt]);
    }
    __syncthreads();
  }

  #pragma unroll
  for (int nt = 0; nt < 4; nt++) {
    int col = bn + wn + nt * 16 + ln15;
    float bv = ldx(sub_b, col, isbf);
    #pragma unroll
    for (int mt = 0; mt < 4; mt++) {
      #pragma unroll
      for (int r = 0; r < 4; r++) {
        int row = bm + wm + mt * 16 + quad * 4 + r;
        float v = acc[mt][nt][r] + bv;
        size_t o = (size_t)row * 1024 + col;
        if (isbf) ((bf16*)dout)[o] = __float2bfloat16(v);
        else      ((float*)dout)[o] = v;
      }
    }
  }
}

// ---------------------------------------------------------------------------
// G[row][r] = q_row . rel_emb[r] (bf16 q). One wave per row.
// ---------------------------------------------------------------------------
__global__ __launch_bounds__(256)
void qrel_k(const bf16* __restrict__ qbf, const void* __restrict__ rel_emb,
            float* __restrict__ G, const int* __restrict__ dflag)
{
  const int isbf = *dflag;
  __shared__ float rel[33][65];
  __shared__ float qw[4][64];
  const int tid = threadIdx.x;
  for (int i = tid; i < 33 * 64; i += 256)
    rel[i >> 6][i & 63] = ldx(rel_emb, i, isbf);
  const int wv = tid >> 6, lane = tid & 63;
  const size_t row = (size_t)blockIdx.x * 4 + wv;
  qw[wv][lane] = bf2f(qbf[row * 64 + lane]);
  __syncthreads();
  if (lane < 33) {
    float s = 0.f;
    #pragma unroll
    for (int d = 0; d < 64; d++) s += qw[wv][d] * rel[lane][d];
    G[row * 33 + lane] = s;
  }
}

// ---------------------------------------------------------------------------
// Fully fused main view v4 (round-6 verified: full unroll keeps acc in regs).
// ---------------------------------------------------------------------------
__global__ __launch_bounds__(256, 2)
void score_fused_k(const bf16* __restrict__ qbf, const bf16* __restrict__ kbf,
                   const float* __restrict__ G, const bf16* __restrict__ vt,
                   const void* __restrict__ rel_emb, bf16* __restrict__ ctx,
                   void* __restrict__ dout, const int* __restrict__ dflag)
{
  __shared__ short Pw[4][16 * 256];   // 32 KB, per-wave private
  __shared__ float gbuf[64 * 33];     // 8448 B
  __shared__ float relbuf[33 * 64];   // 8448 B
  const int tid = threadIdx.x;
  const int w = tid >> 6, ln = tid & 63;
  const int ln15 = ln & 15, quad = ln >> 4;
  const int bh = blockIdx.x, qt = blockIdx.y;
  const size_t qrow0 = (size_t)bh * 512 + qt * 64;
  const int isbf = *dflag;

  // stage G (this block's 64 rows) + rel into LDS (one barrier, after QK)
  for (int i = tid; i < 64 * 33; i += 256) {
    int r = i / 33, c = i - r * 33;
    gbuf[i] = G[(qrow0 + r) * 33 + c];
  }
  for (int i = tid; i < 33 * 64; i += 256)
    relbuf[i] = ldx(rel_emb, i, isbf);

  // ---- QK^T: fragments straight from global, zero barriers ----
  // FULL unroll: acc[t] must be compile-time indexed (rule #20).
  const bf16* qrow = qbf + (qrow0 + w * 16 + ln15) * 64;
  bf16x8 af0 = *(const bf16x8*)(qrow + quad * 8);
  bf16x8 af1 = *(const bf16x8*)(qrow + 32 + quad * 8);
  const bf16* kb = kbf + (size_t)bh * 512 * 64;
  f32x4 acc[32];
  #pragma unroll
  for (int t = 0; t < 32; t++) acc[t] = (f32x4)(0.0f);
  #pragma unroll
  for (int t = 0; t < 32; t++) {
    const bf16* kr = kb + (size_t)(t * 16 + ln15) * 64 + quad * 8;
    bf16x8 b0 = *(const bf16x8*)kr;
    bf16x8 b1 = *(const bf16x8*)(kr + 32);
    acc[t] = mfma_bf16(af0, b0, acc[t]);
    acc[t] = mfma_bf16(af1, b1, acc[t]);
  }
  __syncthreads();   // gbuf/relbuf now valid

  // ---- rel bias + softmax (identical math to verified score_k) ----
  const int qg = qt * 64 + w * 16 + quad * 4;
  const int rowl0 = w * 16 + quad * 4;
  float mx[4], ssum[4], sle[4], sge[4];
  #pragma unroll
  for (int r = 0; r < 4; r++) mx[r] = -3.0e38f;
  #pragma unroll
  for (int t = 0; t < 32; t++) {
    int k = t * 16 + ln15;
    #pragma unroll
    for (int r = 0; r < 4; r++) {
      int delta = k - (qg + r);
      int bkt = delta < -16 ? 0 : (delta > 16 ? 32 : delta + 16);
      float s = acc[t][r] + gbuf[(rowl0 + r) * 33 + bkt];
      acc[t][r] = s;
      mx[r] = fmaxf(mx[r], s);
    }
  }
  #pragma unroll
  for (int r = 0; r < 4; r++) {
    float m = mx[r];
    #pragma unroll
    for (int off = 1; off < 16; off <<= 1) m = fmaxf(m, __shfl_xor(m, off));
    mx[r] = m;
    ssum[r] = 0.f; sle[r] = 0.f; sge[r] = 0.f;
  }
  #pragma unroll
  for (int t = 0; t < 32; t++) {
    int k = t * 16 + ln15;
    #pragma unroll
    for (int r = 0; r < 4; r++) {
      float p = __expf(acc[t][r] - mx[r]);
      acc[t][r] = p;
      ssum[r] += p;
      int delta = k - (qg + r);
      if (delta <= -16) sle[r] += p;
      if (delta >= 16) sge[r] += p;
    }
  }
  #pragma unroll
  for (int r = 0; r < 4; r++) {
    #pragma unroll
    for (int off = 1; off < 16; off <<= 1) {
      ssum[r] += __shfl_xor(ssum[r], off);
      sle[r] += __shfl_xor(sle[r], off);
      sge[r] += __shfl_xor(sge[r], off);
    }
  }
  float inv[4];
  #pragma unroll
  for (int r = 0; r < 4; r++) inv[r] = 1.f / ssum[r];

  // ---- per-wave P (16 rows), k in two 256-halves; PV + band + top_attn ----
  short* Pm = Pw[w];
  const bf16* vb = vt + (size_t)bh * 64 * 512;
  const int toph = ((bh & 15) == 0);
  const int bg = bh >> 4;
  f32x4 pacc[4];
  #pragma unroll
  for (int nt = 0; nt < 4; nt++) pacc[nt] = (f32x4)(0.0f);

  #pragma unroll
  for (int h = 0; h < 2; h++) {
    // store this half's P (normalized bf16), swizzled 16B groups
    #pragma unroll
    for (int t2 = 0; t2 < 16; t2++) {
      int gg = t2 * 2 + (ln15 >> 3);        // logical group = col>>3
      int slot = gg ^ (quad << 1);          // ((rowL>>2)&3)==quad for rowL=quad*4+r
      #pragma unroll
      for (int r = 0; r < 4; r++) {
        int rowL = quad * 4 + r;
        Pm[rowL * 256 + slot * 8 + (ln15 & 7)] =
            (short)f2us(acc[h * 16 + t2][r] * inv[r]);
      }
    }
    __syncthreads();

    // top_attn (head-0 blocks only): wave writes its own 16 rows, this half
    if (toph) {
      for (int i = ln; i < 16 * 32; i += 64) {
        int rowL = i >> 5, gg = i & 31;
        int slot = gg ^ (((rowL >> 2) & 3) << 1);
        bf16x8 u = *(bf16x8*)&Pm[rowL * 256 + slot * 8];
        size_t o = (size_t)4194304 + (size_t)bg * 262144 +
                   (size_t)(qt * 64 + w * 16 + rowL) * 512 + h * 256 + gg * 8;
        if (isbf) {
          *(bf16x8*)((bf16*)dout + o) = u;
        } else {
          float4 f0 = make_float4(us2f((unsigned short)u[0]), us2f((unsigned short)u[1]),
                                  us2f((unsigned short)u[2]), us2f((unsigned short)u[3]));
          float4 f1 = make_float4(us2f((unsigned short)u[4]), us2f((unsigned short)u[5]),
                                  us2f((unsigned short)u[6]), us2f((unsigned short)u[7]));
          *(float4*)((float*)dout + o) = f0;
          *(float4*)((float*)dout + o + 4) = f1;
        }
      }
    }

    // PV over this half: A from Pm (own rows), V fragments from global
    {
      const int rsw = ((ln15 >> 2) & 3) << 1;
      #pragma unroll
      for (int kk = 0; kk < 8; kk++) {
        int gg = kk * 4 + quad;
        bf16x8 a = *(bf16x8*)&Pm[ln15 * 256 + ((gg ^ rsw) * 8)];
        int k0 = h * 256 + kk * 32;
        #pragma unroll
        for (int nt = 0; nt < 4; nt++) {
          bf16x8 b = *(const bf16x8*)(vb + (size_t)(nt * 16 + ln15) * 512 + k0 + quad * 8);
          pacc[nt] = mfma_bf16(a, b, pacc[nt]);
        }
      }
    }

    // diagonal band of arel@rel for k in this half (rel from LDS)
    for (int rr = 1; rr < 32; rr++) {
      float av[4];
      #pragma unroll
      for (int r = 0; r < 4; r++) {
        int k = qg + r + rr - 16;
        av[r] = 0.f;
        if (k >= h * 256 && k < (h + 1) * 256) {
          int kl = k - h * 256;
          int rowL = quad * 4 + r;
          int slot = (kl >> 3) ^ (quad << 1);
          av[r] = us2f((unsigned short)Pm[rowL * 256 + slot * 8 + (kl & 7)]);
        }
      }
      #pragma unroll
      for (int nt = 0; nt < 4; nt++) {
        float relv = relbuf[rr * 64 + nt * 16 + ln15];
        #pragma unroll
        for (int r = 0; r < 4; r++) pacc[nt][r] += av[r] * relv;
      }
    }
    __syncthreads();   // before overwriting Pm with next half
  }

  // sle/sge terms (buckets 0 and 32)
  #pragma unroll
  for (int nt = 0; nt < 4; nt++) {
    float r0v = relbuf[nt * 16 + ln15];
    float r32v = relbuf[32 * 64 + nt * 16 + ln15];
    #pragma unroll
    for (int r = 0; r < 4; r++)
      pacc[nt][r] += sle[r] * inv[r] * r0v + sge[r] * inv[r] * r32v;
  }

  // ctx write (slot 0 layout [bl*512+s][1024])
  const int bl = bh >> 4, head = bh & 15;
  #pragma unroll
  for (int r = 0; r < 4; r++) {
    int s = qt * 64 + rowl0 + r;
    #pragma unroll
    for (int nt = 0; nt < 4; nt++)
      ctx[((size_t)bl * 512 + s) * 1024 + head * 64 + nt * 16 + ln15] =
          __float2bfloat16(pacc[nt][r]);
  }
}

// ---------------------------------------------------------------------------
// Edge h-projections, z-batched over 4 views (blockIdx.y).
// ---------------------------------------------------------------------------
__global__ __launch_bounds__(256)
void hv_k(const bf16* __restrict__ vt, const void* __restrict__ att_w,
          const void* __restrict__ att_b, float* __restrict__ h0,
          float* __restrict__ h1, const int* __restrict__ dflag)
{
  const int i0s[4] = {6, 0, 2, 4};
  const int i1s[4] = {7, 1, 3, 5};
  const int z = blockIdx.y;
  const int i0 = i0s[z], i1 = i1s[z];
  __shared__ float w0[64], w1[64];
  const int tid = threadIdx.x;
  const int bh = blockIdx.x;
  const int isbf = *dflag;
  if (tid < 64) {
    w0[tid] = ldx(att_w, i0 * 64 + tid, isbf);
    w1[tid] = ldx(att_w, i1 * 64 + tid, isbf);
  }
  __syncthreads();
  const bf16* vb = vt + (size_t)bh * 64 * 512 + tid * 2;
  float a00 = 0, a01 = 0, a10 = 0, a11 = 0;
  for (int d = 0; d < 64; d++) {
    ushort2 u = *(const ushort2*)(vb + (size_t)d * 512);
    float f0 = us2f(u.x), f1 = us2f(u.y);
    a00 += f0 * w0[d]; a10 += f1 * w0[d];
    a01 += f0 * w1[d]; a11 += f1 * w1[d];
  }
  float b0 = ldx(att_b, i0, isbf), b1 = ldx(att_b, i1, isbf);
  float* p0 = h0 + (size_t)z * 65536 + (size_t)bh * 512 + tid * 2;
  float* p1 = h1 + (size_t)z * 65536 + (size_t)bh * 512 + tid * 2;
  p0[0] = a00 + b0; p0[1] = a10 + b0;
  p1[0] = a01 + b1; p1[1] = a11 + b1;
}

// ---------------------------------------------------------------------------
// Fused edge view, z-batched over 4 views. Round-6 structure, but the mask
// comes from 1 MB packed bit-planes (L2-resident) instead of grh int32
// (159 MB HBM fetch = the round-6 bottleneck). One byte load per row-lane;
// diagonal/eye rule pre-folded by mask_pack_k. Softmax/PV unchanged.
// ---------------------------------------------------------------------------
__global__ __launch_bounds__(256)
void edge_fused_k(const float* __restrict__ h0, const float* __restrict__ h1,
                  const unsigned char* __restrict__ maskp,
                  const bf16* __restrict__ vt, bf16* __restrict__ ctx5)
{
  __shared__ short P[32 * 512];   // 32 KB
  const int tid = threadIdx.x;
  const int w = tid >> 6, ln = tid & 63;
  const int ln15 = ln & 15, quad = ln >> 4;
  const int bh = blockIdx.x, qt = blockIdx.y, view = blockIdx.z;
  const int bl = bh >> 4;
  bf16* ctx = ctx5 + (size_t)(1 + view) * 4194304;

  // ---- phase 1: rows w*8 .. w*8+7, one full wave per row ----
  const int kb = ln * 8;
  {
    const float* hjp = h1 + (size_t)view * 65536 + (size_t)bh * 512 + kb;
    float4 hA = *(const float4*)hjp;
    float4 hB = *(const float4*)(hjp + 4);
    float hjv[8] = {hA.x, hA.y, hA.z, hA.w, hB.x, hB.y, hB.z, hB.w};
    const float* h0b = h0 + (size_t)view * 65536 + (size_t)bh * 512 + qt * 32 + w * 8;
    // mask byte for (view, bl, qi=qt*32+w*8+rr, k-block ln): bit j -> k=ln*8+j
    const unsigned char* mrow = maskp + (size_t)view * 262144 + (size_t)bl * 32768
                                + (size_t)(qt * 32 + w * 8) * 64 + ln;
    unsigned int mb = mrow[0];
    #pragma unroll 2
    for (int rr = 0; rr < 8; rr++) {
      unsigned int mbn = mrow[(rr < 7 ? rr + 1 : rr) * 64];
      int r = w * 8 + rr;              // local row in P, 0..31
      float hi = h0b[rr];
      float e[8];
      float m = -3.0e38f;
      #pragma unroll
      for (int j = 0; j < 8; j++) {
        float ej = hi + hjv[j];
        ej = ej >= 0.f ? ej : 0.01f * ej;
        e[j] = ((mb >> j) & 1) ? ej : NEGV;
        m = fmaxf(m, e[j]);
      }
      #pragma unroll
      for (int off = 32; off; off >>= 1) m = fmaxf(m, __shfl_xor(m, off));
      float ssum = 0.f;
      #pragma unroll
      for (int j = 0; j < 8; j++) { e[j] = __expf(e[j] - m); ssum += e[j]; }
      #pragma unroll
      for (int off = 32; off; off >>= 1) ssum += __shfl_xor(ssum, off);
      float inv = 1.f / ssum;
      bf16x8 pv;
      #pragma unroll
      for (int j = 0; j < 8; j++) pv[j] = (short)f2us(e[j] * inv);
      *(bf16x8*)&P[r * 512 + ((ln ^ (r & 7)) * 8)] = pv;
      mb = mbn;
    }
  }
  __syncthreads();

  // ---- phase 2: ctx[rows, d] = P @ V^T, V straight from global ----
  const bf16* vb = vt + (size_t)bh * 64 * 512;
  const int m0 = (w >> 1) * 16, d0 = (w & 1) * 32;
  f32x4 acc[2];
  acc[0] = (f32x4)(0.0f); acc[1] = (f32x4)(0.0f);

  const int ra = m0 + ln15;
  const int rsw = ra & 7;
  #pragma unroll 4
  for (int k0 = 0; k0 < 512; k0 += 32) {
    int gsel = (k0 >> 3) + quad;
    bf16x8 a = *(bf16x8*)&P[ra * 512 + ((gsel ^ rsw) * 8)];
    #pragma unroll
    for (int nt = 0; nt < 2; nt++) {
      bf16x8 b = *(const bf16x8*)(vb + (size_t)(d0 + nt * 16 + ln15) * 512 + k0 + quad * 8);
      acc[nt] = mfma_bf16(a, b, acc[nt]);
    }
  }

  const int head = bh & 15;
  #pragma unroll
  for (int r = 0; r < 4; r++) {
    int s = qt * 32 + m0 + quad * 4 + r;
    #pragma unroll
    for (int nt = 0; nt < 2; nt++)
      ctx[((size_t)bl * 512 + s) * 1024 + head * 64 + d0 + nt * 16 + ln15] =
          __float2bfloat16(acc[nt][r]);
  }
}

// ---------------------------------------------------------------------------
extern "C" void kernel_launch(void* const* d_in, const int* in_sizes, int n_in,
                              void* d_out, int out_size, void* d_ws, size_t ws_size,
                              hipStream_t stream)
{
  const void* key   = d_in[0];
  const void* value = d_in[1];
  const void* query = d_in[2];
  const int*  grh   = (const int*)d_in[3];
  const void* Wq = d_in[5];
  const void* bq = d_in[6];
  const void* Wk = d_in[7];
  const void* bk = d_in[8];
  const void* Wv = d_in[9];
  const void* bv = d_in[10];
  const void* rel_emb = d_in[11];
  const void* att_w = d_in[12];
  const void* att_b = d_in[13];
  const void* gate_w = d_in[14];
  const void* gate_b = d_in[15];
  const void* sub_w = d_in[16];
  const void* sub_b = d_in[17];

  // workspace layout (floats) — ~148 MB incl. 1 MB mask planes
  int* dflag = (int*)d_ws;
  float* base = (float*)d_ws;
  bf16* qbf = (bf16*)(base + 16);
  bf16* kbf = (bf16*)(base + 16 + 2097152);
  bf16* vtb = (bf16*)(base + 16 + 2 * 2097152);
  bf16* Wt  = (bf16*)(base + 16 + 3 * 2097152);
  float* G  = base + 16 + 3 * 2097152 + 6815744;
  float* h0 = G + 2162688;
  float* h1 = h0 + 262144;
  bf16* ctx5   = (bf16*)(h1 + 262144);
  bf16* gated5 = ctx5 + 5ull * 4194304;
  unsigned char* maskp = (unsigned char*)(gated5 + 5ull * 4194304);

  detect_k<<<dim3(1), dim3(64), 0, stream>>>(Wq, dflag);

  // pack grh -> 1 MB of per-view adjacency bit-planes (read grh ONCE)
  mask_pack_k<<<dim3(1024), dim3(256), 0, stream>>>(grh, maskp);

  // all 13 weight transposes in one launch
  wtrans_all_k<<<dim3(13 * 256), dim3(256), 0, stream>>>(
      Wq, Wk, Wv, gate_w, sub_w, Wt, dflag);

  // QKV projections batched (z: 0=q scaled, 1=k, 2=v transposed)
  qkv_gemm_k<<<dim3(32, 8, 3), dim3(256), 0, stream>>>(
      query, key, value, Wt, bq, bk, bv, qbf, kbf, vtb, dflag);

  qrel_k<<<dim3(16384), dim3(256), 0, stream>>>(qbf, rel_emb, G, dflag);

  // main view fully fused -> ctx5 slot 0 (+ top_attn to d_out)
  score_fused_k<<<dim3(128, 8), dim3(256), 0, stream>>>(
      qbf, kbf, G, vtb, rel_emb, ctx5, d_out, dflag);

  // edge views: h projections (4 views batched), then fused softmax+PV
  hv_k<<<dim3(128, 4), dim3(256), 0, stream>>>(vtb, att_w, att_b, h0, h1, dflag);
  edge_fused_k<<<dim3(128, 16, 4), dim3(256), 0, stream>>>(
      h0, h1, maskp, vtb, ctx5);

  // 5 gate GEMMs batched, then one K=5120 sub GEMM straight to d_out
  gate_gemm_k<<<dim3(32, 8, 5), dim3(256), 0, stream>>>(
      ctx5, Wt, gate_b, gated5, dflag);
  sub_gemm_k<<<dim3(32, 8), dim3(256), 0, stream>>>(
      gated5, Wt, sub_b, d_out, dflag);
}

// Round 8
// 829.310 us; speedup vs baseline: 1.2347x; 1.0304x over previous
//
#include <hip/hip_runtime.h>
#include <hip/hip_bf16.h>

typedef __hip_bfloat16 bf16;
typedef __attribute__((ext_vector_type(8))) short bf16x8;
typedef __attribute__((ext_vector_type(4))) float f32x4;

#define B_ 8
#define S_ 512
#define D_ 1024
#define H_ 16
#define NEGV -9.0e15f
#define WSL 1048576ull

__device__ __forceinline__ float bf2f(bf16 x) { return __bfloat162float(x); }
__device__ __forceinline__ float us2f(unsigned short u) {
  union { unsigned int i; float f; } c; c.i = ((unsigned int)u) << 16; return c.f;
}
__device__ __forceinline__ unsigned short f2us(float f) {
  bf16 h = __float2bfloat16(f);
  unsigned short u; __builtin_memcpy(&u, &h, 2); return u;
}
__device__ __forceinline__ float ldx(const void* p, size_t i, int isbf) {
  return isbf ? bf2f(((const bf16*)p)[i]) : ((const float*)p)[i];
}
struct F4 { float x, y, z, w; };
__device__ __forceinline__ F4 ld4(const void* p, size_t i, int isbf) {
  F4 r;
  if (isbf) {
    ushort4 u = *(const ushort4*)((const bf16*)p + i);
    r.x = us2f(u.x); r.y = us2f(u.y); r.z = us2f(u.z); r.w = us2f(u.w);
  } else {
    float4 d = *(const float4*)((const float*)p + i);
    r.x = d.x; r.y = d.y; r.z = d.z; r.w = d.w;
  }
  return r;
}
// 8 consecutive elements as bf16x8; converts if source is f32
__device__ __forceinline__ bf16x8 ld8bf(const void* p, size_t i, int isbf) {
  if (isbf) return *(const bf16x8*)((const bf16*)p + i);
  float4 a = *(const float4*)((const float*)p + i);
  float4 b = *(const float4*)((const float*)p + i + 4);
  bf16x8 r;
  r[0] = (short)f2us(a.x); r[1] = (short)f2us(a.y);
  r[2] = (short)f2us(a.z); r[3] = (short)f2us(a.w);
  r[4] = (short)f2us(b.x); r[5] = (short)f2us(b.y);
  r[6] = (short)f2us(b.z); r[7] = (short)f2us(b.w);
  return r;
}
__device__ __forceinline__ f32x4 mfma_bf16(bf16x8 a, bf16x8 b, f32x4 c) {
  return __builtin_amdgcn_mfma_f32_16x16x32_bf16(a, b, c, 0, 0, 0);
}

// Dtype detector (round-3 verified: picks f32 on this harness).
__global__ void detect_k(const void* __restrict__ w, int* __restrict__ flag)
{
  if (threadIdx.x == 0 && blockIdx.x == 0) {
    const unsigned short* u = (const unsigned short*)w;
    int sane = 0;
    for (int i = 0; i < 1024; i += 2) {
      float a = fabsf(us2f(u[i]));
      if (a == 0.f || (a > 9.5e-7f && a < 8.f)) sane++;
    }
    *flag = (sane > 256) ? 1 : 0;
  }
}

// ---------------------------------------------------------------------------
// Mask bit-planes (round-7 verified): grh -> 1 MB packed adjacency bits.
// ---------------------------------------------------------------------------
__global__ __launch_bounds__(256)
void mask_pack_k(const int* __restrict__ grh, unsigned char* __restrict__ maskp)
{
  int t = blockIdx.x * 256 + threadIdx.x;     // [0, 8*512*64)
  int byte = t & 63, qi = (t >> 6) & 511, bl = t >> 15;
  const int* g = grh + ((size_t)bl * 512 + qi) * 512 + byte * 8;
  int4 a = *(const int4*)g;
  int4 b = *(const int4*)(g + 4);
  int gs[8] = {a.x, a.y, a.z, a.w, b.x, b.y, b.z, b.w};
  unsigned int m0 = 0, m1 = 0, m2 = 0, m3 = 0;
  #pragma unroll
  for (int j = 0; j < 8; j++) {
    int k = byte * 8 + j;
    int diag = (k == qi);
    m0 |= (unsigned int)(gs[j] > 1) << j;
    m1 |= (unsigned int)(gs[j] == (diag ? 4 : 2)) << j;
    m2 |= (unsigned int)(gs[j] == (diag ? 4 : 3)) << j;
    m3 |= (unsigned int)(gs[j] == 4) << j;
  }
  size_t o = (size_t)bl * 32768 + (size_t)qi * 64 + byte;
  maskp[o]          = (unsigned char)m0;
  maskp[o + 262144] = (unsigned char)m1;
  maskp[o + 524288] = (unsigned char)m2;
  maskp[o + 786432] = (unsigned char)m3;
}

// ---------------------------------------------------------------------------
// ALL 13 weight transposes in one launch (round-3 verified).
// ---------------------------------------------------------------------------
__global__ __launch_bounds__(256)
void wtrans_all_k(const void* __restrict__ Wq, const void* __restrict__ Wk,
                  const void* __restrict__ Wv, const void* __restrict__ gate_w,
                  const void* __restrict__ sub_w, bf16* __restrict__ Wt,
                  const int* __restrict__ dflag)
{
  const int isbf = *dflag;
  const int slot = blockIdx.x >> 8;
  const int blk = blockIdx.x & 255;
  const int gsrc[5] = {0, 5, 1, 2, 3};
  const void* W;
  size_t woff;
  if (slot < 3)      { W = slot == 0 ? Wq : (slot == 1 ? Wk : Wv); woff = 0; }
  else if (slot < 8) { W = gate_w; woff = (size_t)gsrc[slot - 3] * WSL; }
  else               { W = sub_w;  woff = (size_t)(slot - 8) * WSL; }
  bf16* out = Wt + (size_t)slot * WSL;

  __shared__ float t[64][68];
  const int tid = threadIdx.x;
  const int nt = blk & 15, kt = blk >> 4;
  {
    int r = tid >> 4, c4 = (tid & 15) * 4;
    #pragma unroll
    for (int i = 0; i < 4; i++) {
      int rr = r + i * 16;
      F4 v = ld4(W, woff + (size_t)(kt * 64 + rr) * 1024 + nt * 64 + c4, isbf);
      *(float4*)&t[rr][c4] = make_float4(v.x, v.y, v.z, v.w);
    }
  }
  __syncthreads();
  {
    int n = tid >> 4, k4 = (tid & 15) * 4;
    #pragma unroll
    for (int i = 0; i < 4; i++) {
      int nn = n + i * 16;
      ushort4 u;
      u.x = f2us(t[k4 + 0][nn]); u.y = f2us(t[k4 + 1][nn]);
      u.z = f2us(t[k4 + 2][nn]); u.w = f2us(t[k4 + 3][nn]);
      *(ushort4*)(out + (size_t)(nt * 64 + nn) * 1024 + kt * 64 + k4) = u;
    }
  }
}

// ---------------------------------------------------------------------------
// QKV projections, z-batched (z=0:q scaled, z=1:k, z=2:v transposed).
// ---------------------------------------------------------------------------
__global__ __launch_bounds__(256)
void qkv_gemm_k(const void* __restrict__ Aq, const void* __restrict__ Ak,
                const void* __restrict__ Av, const bf16* __restrict__ Wt,
                const void* __restrict__ bqp, const void* __restrict__ bkp,
                const void* __restrict__ bvp, bf16* __restrict__ qbf,
                bf16* __restrict__ kbf, bf16* __restrict__ vtb,
                const int* __restrict__ dflag)
{
  const int isbf = *dflag;
  const int z = blockIdx.z;
  const void* A = z == 0 ? Aq : (z == 1 ? Ak : Av);
  const void* bias = z == 0 ? bqp : (z == 1 ? bkp : bvp);
  bf16* outB = z == 0 ? qbf : (z == 1 ? kbf : vtb);
  const bf16* Wz = Wt + (size_t)z * WSL;
  const float scale = z == 0 ? 0.125f : 1.0f;
  const int vtrans = (z == 2);

  __shared__ short As[128 * 64];
  __shared__ short Bs[128 * 64];
  const int tid = threadIdx.x;
  const int w = tid >> 6, ln = tid & 63;
  const int ln15 = ln & 15, quad = ln >> 4;
  const int wm = (w & 1) * 64, wn = (w >> 1) * 64;
  const int bm = blockIdx.x * 128, bn = blockIdx.y * 128;
  const int r0 = tid >> 3, g0 = tid & 7;
  f32x4 acc[4][4];
  #pragma unroll
  for (int mt = 0; mt < 4; mt++)
    #pragma unroll
    for (int nt = 0; nt < 4; nt++) acc[mt][nt] = (f32x4)(0.0f);

  for (int k0 = 0; k0 < 1024; k0 += 64) {
    #pragma unroll
    for (int i = 0; i < 4; i++) {
      int r = r0 + i * 32;
      int gsw = ((g0 ^ (r & 7)) * 8);
      bf16x8 av = ld8bf(A, (size_t)(bm + r) * 1024 + k0 + g0 * 8, isbf);
      *(bf16x8*)&As[r * 64 + gsw] = av;
      bf16x8 bv = *(const bf16x8*)(Wz + (size_t)(bn + r) * 1024 + k0 + g0 * 8);
      *(bf16x8*)&Bs[r * 64 + gsw] = bv;
    }
    __syncthreads();
    #pragma unroll
    for (int s = 0; s < 2; s++) {
      bf16x8 af[4], bfr[4];
      #pragma unroll
      for (int t = 0; t < 4; t++) {
        int ra = wm + t * 16 + ln15;
        af[t] = *(bf16x8*)&As[ra * 64 + (((s * 4 + quad) ^ (ra & 7)) * 8)];
        int rb = wn + t * 16 + ln15;
        bfr[t] = *(bf16x8*)&Bs[rb * 64 + (((s * 4 + quad) ^ (rb & 7)) * 8)];
      }
      #pragma unroll
      for (int mt = 0; mt < 4; mt++)
        #pragma unroll
        for (int nt = 0; nt < 4; nt++)
          acc[mt][nt] = mfma_bf16(af[mt], bfr[nt], acc[mt][nt]);
    }
    __syncthreads();
  }

  #pragma unroll
  for (int nt = 0; nt < 4; nt++) {
    int col = bn + wn + nt * 16 + ln15;
    float bv = ldx(bias, col, isbf);
    #pragma unroll
    for (int mt = 0; mt < 4; mt++) {
      #pragma unroll
      for (int r = 0; r < 4; r++) {
        int row = bm + wm + mt * 16 + quad * 4 + r;
        float v = (acc[mt][nt][r] + bv) * scale;
        int bb = row >> 9, s = row & 511;
        int h = col >> 6, d0 = col & 63;
        size_t o = vtrans ? (((size_t)(bb * 16 + h) * 64 + d0) * 512 + s)
                          : (((size_t)(bb * 16 + h) * 512 + s) * 64 + d0);
        outB[o] = __float2bfloat16(v);
      }
    }
  }
}

// ---------------------------------------------------------------------------
// Gate GEMMs, z-batched over 5 views (main + 4 edge).
// ---------------------------------------------------------------------------
__global__ __launch_bounds__(256)
void gate_gemm_k(const bf16* __restrict__ ctx5, const bf16* __restrict__ Wt,
                 const void* __restrict__ gate_b, bf16* __restrict__ gated5,
                 const int* __restrict__ dflag)
{
  const int isbf = *dflag;
  const int z = blockIdx.z;
  const int gsel[5] = {0, 5, 1, 2, 3};
  const bf16* A = ctx5 + (size_t)z * 4194304;
  bf16* outB = gated5 + (size_t)z * 4194304;
  const bf16* Wz = Wt + (size_t)(3 + z) * WSL;
  const size_t boff = (size_t)gsel[z] * 1024;

  __shared__ short As[128 * 64];
  __shared__ short Bs[128 * 64];
  const int tid = threadIdx.x;
  const int w = tid >> 6, ln = tid & 63;
  const int ln15 = ln & 15, quad = ln >> 4;
  const int wm = (w & 1) * 64, wn = (w >> 1) * 64;
  const int bm = blockIdx.x * 128, bn = blockIdx.y * 128;
  const int r0 = tid >> 3, g0 = tid & 7;
  f32x4 acc[4][4];
  #pragma unroll
  for (int mt = 0; mt < 4; mt++)
    #pragma unroll
    for (int nt = 0; nt < 4; nt++) acc[mt][nt] = (f32x4)(0.0f);

  for (int k0 = 0; k0 < 1024; k0 += 64) {
    #pragma unroll
    for (int i = 0; i < 4; i++) {
      int r = r0 + i * 32;
      int gsw = ((g0 ^ (r & 7)) * 8);
      bf16x8 av = *(const bf16x8*)(A + (size_t)(bm + r) * 1024 + k0 + g0 * 8);
      *(bf16x8*)&As[r * 64 + gsw] = av;
      bf16x8 bv = *(const bf16x8*)(Wz + (size_t)(bn + r) * 1024 + k0 + g0 * 8);
      *(bf16x8*)&Bs[r * 64 + gsw] = bv;
    }
    __syncthreads();
    #pragma unroll
    for (int s = 0; s < 2; s++) {
      bf16x8 af[4], bfr[4];
      #pragma unroll
      for (int t = 0; t < 4; t++) {
        int ra = wm + t * 16 + ln15;
        af[t] = *(bf16x8*)&As[ra * 64 + (((s * 4 + quad) ^ (ra & 7)) * 8)];
        int rb = wn + t * 16 + ln15;
        bfr[t] = *(bf16x8*)&Bs[rb * 64 + (((s * 4 + quad) ^ (rb & 7)) * 8)];
      }
      #pragma unroll
      for (int mt = 0; mt < 4; mt++)
        #pragma unroll
        for (int nt = 0; nt < 4; nt++)
          acc[mt][nt] = mfma_bf16(af[mt], bfr[nt], acc[mt][nt]);
    }
    __syncthreads();
  }

  #pragma unroll
  for (int nt = 0; nt < 4; nt++) {
    int col = bn + wn + nt * 16 + ln15;
    float bv = ldx(gate_b, boff + col, isbf);
    #pragma unroll
    for (int mt = 0; mt < 4; mt++) {
      #pragma unroll
      for (int r = 0; r < 4; r++) {
        int row = bm + wm + mt * 16 + quad * 4 + r;
        float v = acc[mt][nt][r] + bv;
        float x = bf2f(A[(size_t)row * 1024 + col]);
        outB[(size_t)row * 1024 + col] = __float2bfloat16(x / (1.f + __expf(-v)));
      }
    }
  }
}

// ---------------------------------------------------------------------------
// Final sub GEMM: out = [gated_0|...|gated_4](4096x5120) @ sub_w + sub_b.
// ---------------------------------------------------------------------------
__global__ __launch_bounds__(256)
void sub_gemm_k(const bf16* __restrict__ gated5, const bf16* __restrict__ Wt,
                const void* __restrict__ sub_b, void* __restrict__ dout,
                const int* __restrict__ dflag)
{
  const int isbf = *dflag;
  __shared__ short As[128 * 64];
  __shared__ short Bs[128 * 64];
  const int tid = threadIdx.x;
  const int w = tid >> 6, ln = tid & 63;
  const int ln15 = ln & 15, quad = ln >> 4;
  const int wm = (w & 1) * 64, wn = (w >> 1) * 64;
  const int bm = blockIdx.x * 128, bn = blockIdx.y * 128;
  const int r0 = tid >> 3, g0 = tid & 7;
  f32x4 acc[4][4];
  #pragma unroll
  for (int mt = 0; mt < 4; mt++)
    #pragma unroll
    for (int nt = 0; nt < 4; nt++) acc[mt][nt] = (f32x4)(0.0f);

  for (int k0 = 0; k0 < 5120; k0 += 64) {
    const int slot = k0 >> 10, kk = k0 & 1023;
    const bf16* Ab = gated5 + (size_t)slot * 4194304;
    const bf16* Wz = Wt + (size_t)(8 + slot) * WSL;
    #pragma unroll
    for (int i = 0; i < 4; i++) {
      int r = r0 + i * 32;
      int gsw = ((g0 ^ (r & 7)) * 8);
      bf16x8 av = *(const bf16x8*)(Ab + (size_t)(bm + r) * 1024 + kk + g0 * 8);
      *(bf16x8*)&As[r * 64 + gsw] = av;
      bf16x8 bv = *(const bf16x8*)(Wz + (size_t)(bn + r) * 1024 + kk + g0 * 8);
      *(bf16x8*)&Bs[r * 64 + gsw] = bv;
    }
    __syncthreads();
    #pragma unroll
    for (int s = 0; s < 2; s++) {
      bf16x8 af[4], bfr[4];
      #pragma unroll
      for (int t = 0; t < 4; t++) {
        int ra = wm + t * 16 + ln15;
        af[t] = *(bf16x8*)&As[ra * 64 + (((s * 4 + quad) ^ (ra & 7)) * 8)];
        int rb = wn + t * 16 + ln15;
        bfr[t] = *(bf16x8*)&Bs[rb * 64 + (((s * 4 + quad) ^ (rb & 7)) * 8)];
      }
      #pragma unroll
      for (int mt = 0; mt < 4; mt++)
        #pragma unroll
        for (int nt = 0; nt < 4; nt++)
          acc[mt][nt] = mfma_bf16(af[mt], bfr[nt], acc[mt][nt]);
    }
    __syncthreads();
  }

  #pragma unroll
  for (int nt = 0; nt < 4; nt++) {
    int col = bn + wn + nt * 16 + ln15;
    float bv = ldx(sub_b, col, isbf);
    #pragma unroll
    for (int mt = 0; mt < 4; mt++) {
      #pragma unroll
      for (int r = 0; r < 4; r++) {
        int row = bm + wm + mt * 16 + quad * 4 + r;
        float v = acc[mt][nt][r] + bv;
        size_t o = (size_t)row * 1024 + col;
        if (isbf) ((bf16*)dout)[o] = __float2bfloat16(v);
        else      ((float*)dout)[o] = v;
      }
    }
  }
}

// ---------------------------------------------------------------------------
// G[row][r] = q_row . rel_emb[r] (bf16 q). One wave per row.
// ---------------------------------------------------------------------------
__global__ __launch_bounds__(256)
void qrel_k(const bf16* __restrict__ qbf, const void* __restrict__ rel_emb,
            float* __restrict__ G, const int* __restrict__ dflag)
{
  const int isbf = *dflag;
  __shared__ float rel[33][65];
  __shared__ float qw[4][64];
  const int tid = threadIdx.x;
  for (int i = tid; i < 33 * 64; i += 256)
    rel[i >> 6][i & 63] = ldx(rel_emb, i, isbf);
  const int wv = tid >> 6, lane = tid & 63;
  const size_t row = (size_t)blockIdx.x * 4 + wv;
  qw[wv][lane] = bf2f(qbf[row * 64 + lane]);
  __syncthreads();
  if (lane < 33) {
    float s = 0.f;
    #pragma unroll
    for (int d = 0; d < 64; d++) s += qw[wv][d] * rel[lane][d];
    G[row * 33 + lane] = s;
  }
}

// ---------------------------------------------------------------------------
// Fully fused main view v5: 32 rows/block, grid (128,16). Wave w owns rows
// (w>>1)*16 and k-col half (w&1)*256 -> QK accumulator acc[16] = 64 VGPRs
// (round-7 post-mortem: true need at acc[32] was ~190 > the allocator's 128
// pick -> ~59 MB partial spill; halving the live accumulator makes the
// kernel genuinely fit in 128). Cross-wave softmax via LDS stats exchange:
// partial row-max -> global max (exact same value as single-wave version,
// so exp inputs are bit-identical) -> partial sums -> totals. P (32x512)
// stored normalized with the verified XOR swizzle (q2 = quad<<1 holds for
// both row groups since rowg in {0,16}); PV splits d per wave (pacc[2]).
// LDS 46.5 KB -> 3 blocks/CU.
// ---------------------------------------------------------------------------
__global__ __launch_bounds__(256, 2)
void score_fused_k(const bf16* __restrict__ qbf, const bf16* __restrict__ kbf,
                   const float* __restrict__ G, const bf16* __restrict__ vt,
                   const void* __restrict__ rel_emb, bf16* __restrict__ ctx,
                   void* __restrict__ dout, const int* __restrict__ dflag)
{
  __shared__ short P[32 * 512];       // 32 KB, normalized bf16 P
  __shared__ float gbuf[32 * 33];     // 4224 B
  __shared__ float relbuf[33 * 64];   // 8448 B
  __shared__ float smax[4][16];       // per-wave partial row max
  __shared__ float ssumS[4][16];      // per-wave partial row sums
  __shared__ float sleS[4][16];
  __shared__ float sgeS[4][16];
  const int tid = threadIdx.x;
  const int w = tid >> 6, ln = tid & 63;
  const int ln15 = ln & 15, quad = ln >> 4;
  const int rowg = (w >> 1) * 16;     // row group base (0 or 16)
  const int ch = w & 1;               // k-col half (0 or 1)
  const int bh = blockIdx.x, qt = blockIdx.y;
  const size_t qrow0 = (size_t)bh * 512 + qt * 32;
  const int isbf = *dflag;

  // stage G (32 rows) + rel into LDS (valid after barrier #1)
  for (int i = tid; i < 32 * 33; i += 256) {
    int r = i / 33, c = i - r * 33;
    gbuf[i] = G[(qrow0 + r) * 33 + c];
  }
  for (int i = tid; i < 33 * 64; i += 256)
    relbuf[i] = ldx(rel_emb, i, isbf);

  // ---- QK^T for my rows x my col-half: fragments straight from global ----
  const bf16* qrow = qbf + (qrow0 + rowg + ln15) * 64;
  bf16x8 af0 = *(const bf16x8*)(qrow + quad * 8);
  bf16x8 af1 = *(const bf16x8*)(qrow + 32 + quad * 8);
  const bf16* kb = kbf + (size_t)bh * 512 * 64;
  f32x4 acc[16];
  #pragma unroll
  for (int t = 0; t < 16; t++) acc[t] = (f32x4)(0.0f);
  #pragma unroll
  for (int t = 0; t < 16; t++) {
    const bf16* kr = kb + (size_t)(ch * 256 + t * 16 + ln15) * 64 + quad * 8;
    bf16x8 b0 = *(const bf16x8*)kr;
    bf16x8 b1 = *(const bf16x8*)(kr + 32);
    acc[t] = mfma_bf16(af0, b0, acc[t]);
    acc[t] = mfma_bf16(af1, b1, acc[t]);
  }
  __syncthreads();   // #1: gbuf/relbuf valid

  // ---- rel bias + partial row max over my half ----
  const int qg = qt * 32 + rowg + quad * 4;        // global q of row r=0
  const int rowl0 = rowg + quad * 4;               // local row base
  float mx[4], ssum[4], sle[4], sge[4], inv[4];
  #pragma unroll
  for (int r = 0; r < 4; r++) mx[r] = -3.0e38f;
  #pragma unroll
  for (int t = 0; t < 16; t++) {
    int k = ch * 256 + t * 16 + ln15;
    #pragma unroll
    for (int r = 0; r < 4; r++) {
      int delta = k - (qg + r);
      int bkt = delta < -16 ? 0 : (delta > 16 ? 32 : delta + 16);
      float s = acc[t][r] + gbuf[(rowl0 + r) * 33 + bkt];
      acc[t][r] = s;
      mx[r] = fmaxf(mx[r], s);
    }
  }
  #pragma unroll
  for (int r = 0; r < 4; r++) {
    float m = mx[r];
    #pragma unroll
    for (int off = 1; off < 16; off <<= 1) m = fmaxf(m, __shfl_xor(m, off));
    mx[r] = m;
  }
  if (ln15 == 0) {
    #pragma unroll
    for (int r = 0; r < 4; r++) smax[w][quad * 4 + r] = mx[r];
  }
  __syncthreads();   // #2: partner partial max visible
  #pragma unroll
  for (int r = 0; r < 4; r++) {
    mx[r] = fmaxf(mx[r], smax[w ^ 1][quad * 4 + r]);   // exact global max
    ssum[r] = 0.f; sle[r] = 0.f; sge[r] = 0.f;
  }

  // ---- exp + partial sums over my half ----
  #pragma unroll
  for (int t = 0; t < 16; t++) {
    int k = ch * 256 + t * 16 + ln15;
    #pragma unroll
    for (int r = 0; r < 4; r++) {
      float p = __expf(acc[t][r] - mx[r]);
      acc[t][r] = p;
      ssum[r] += p;
      int delta = k - (qg + r);
      if (delta <= -16) sle[r] += p;
      if (delta >= 16) sge[r] += p;
    }
  }
  #pragma unroll
  for (int r = 0; r < 4; r++) {
    #pragma unroll
    for (int off = 1; off < 16; off <<= 1) {
      ssum[r] += __shfl_xor(ssum[r], off);
      sle[r] += __shfl_xor(sle[r], off);
      sge[r] += __shfl_xor(sge[r], off);
    }
  }
  if (ln15 == 0) {
    #pragma unroll
    for (int r = 0; r < 4; r++) {
      ssumS[w][quad * 4 + r] = ssum[r];
      sleS[w][quad * 4 + r] = sle[r];
      sgeS[w][quad * 4 + r] = sge[r];
    }
  }
  __syncthreads();   // #3: partner partial sums visible
  #pragma unroll
  for (int r = 0; r < 4; r++) {
    float tot = ssum[r] + ssumS[w ^ 1][quad * 4 + r];
    sle[r] += sleS[w ^ 1][quad * 4 + r];
    sge[r] += sgeS[w ^ 1][quad * 4 + r];
    inv[r] = 1.f / tot;
  }

  // ---- store normalized P (my 16 rows x my 256 cols), XOR swizzle ----
  // row rowL stored with q2 = ((rowL>>2)&3)<<1 == quad<<1 (rowg in {0,16}).
  #pragma unroll
  for (int t2 = 0; t2 < 16; t2++) {
    int gg = t2 * 2 + (ln15 >> 3);          // group within my half, 0..31
    int slot = gg ^ (quad << 1);
    #pragma unroll
    for (int r = 0; r < 4; r++) {
      int rowL = rowl0 + r;
      P[rowL * 512 + ch * 256 + slot * 8 + (ln15 & 7)] =
          (short)f2us(acc[t2][r] * inv[r]);
    }
  }
  __syncthreads();   // #4: full P tile valid

  // ---- top_attn (head-0 blocks): all threads, 32 rows x 512 cols ----
  if ((bh & 15) == 0) {
    const int bg = bh >> 4;
    for (int i = tid; i < 32 * 64; i += 256) {
      int rowL = i >> 6, g = i & 63;
      int chg = g >> 5, gg = g & 31;
      int slot = gg ^ (((rowL >> 2) & 3) << 1);
      bf16x8 u = *(bf16x8*)&P[rowL * 512 + chg * 256 + slot * 8];
      size_t o = (size_t)4194304 + (size_t)bg * 262144 +
                 (size_t)(qt * 32 + rowL) * 512 + g * 8;
      if (isbf) {
        *(bf16x8*)((bf16*)dout + o) = u;
      } else {
        float4 f0 = make_float4(us2f((unsigned short)u[0]), us2f((unsigned short)u[1]),
                                us2f((unsigned short)u[2]), us2f((unsigned short)u[3]));
        float4 f1 = make_float4(us2f((unsigned short)u[4]), us2f((unsigned short)u[5]),
                                us2f((unsigned short)u[6]), us2f((unsigned short)u[7]));
        *(float4*)((float*)dout + o) = f0;
        *(float4*)((float*)dout + o + 4) = f1;
      }
    }
  }

  // ---- PV: my rows (rowg..+15) x my d-half (ch*32..+31), all 512 k ----
  const bf16* vb = vt + (size_t)bh * 64 * 512;
  f32x4 pacc[2];
  pacc[0] = (f32x4)(0.0f); pacc[1] = (f32x4)(0.0f);
  const int ra = rowg + ln15;
  const int rsw = ((ln15 >> 2) & 3) << 1;   // q2 of row ra
  #pragma unroll
  for (int h2 = 0; h2 < 2; h2++) {
    #pragma unroll
    for (int kk = 0; kk < 8; kk++) {
      int gg = kk * 4 + quad;
      bf16x8 a = *(bf16x8*)&P[ra * 512 + h2 * 256 + ((gg ^ rsw) * 8)];
      int k0 = h2 * 256 + kk * 32;
      #pragma unroll
      for (int nt2 = 0; nt2 < 2; nt2++) {
        int dcol = ch * 32 + nt2 * 16 + ln15;
        bf16x8 b = *(const bf16x8*)(vb + (size_t)dcol * 512 + k0 + quad * 8);
        pacc[nt2] = mfma_bf16(a, b, pacc[nt2]);
      }
    }
  }

  // ---- diagonal band of arel@rel (rel from LDS, normalized P from LDS) ----
  for (int rr = 1; rr < 32; rr++) {
    float av[4];
    #pragma unroll
    for (int r = 0; r < 4; r++) {
      int k = qg + r + rr - 16;
      av[r] = 0.f;
      if (k >= 0 && k < 512) {
        int g = k >> 3, chg = g >> 5, gg = g & 31;
        int slot = gg ^ (quad << 1);
        av[r] = us2f((unsigned short)P[(rowl0 + r) * 512 + chg * 256 +
                                       slot * 8 + (k & 7)]);
      }
    }
    #pragma unroll
    for (int nt2 = 0; nt2 < 2; nt2++) {
      float relv = relbuf[rr * 64 + ch * 32 + nt2 * 16 + ln15];
      #pragma unroll
      for (int r = 0; r < 4; r++) pacc[nt2][r] += av[r] * relv;
    }
  }

  // sle/sge terms (buckets 0 and 32)
  #pragma unroll
  for (int nt2 = 0; nt2 < 2; nt2++) {
    float r0v = relbuf[ch * 32 + nt2 * 16 + ln15];
    float r32v = relbuf[32 * 64 + ch * 32 + nt2 * 16 + ln15];
    #pragma unroll
    for (int r = 0; r < 4; r++)
      pacc[nt2][r] += sle[r] * inv[r] * r0v + sge[r] * inv[r] * r32v;
  }

  // ctx write (slot 0 layout [bl*512+s][1024]); my rows x my d-half
  const int bl = bh >> 4, head = bh & 15;
  #pragma unroll
  for (int r = 0; r < 4; r++) {
    int s = qt * 32 + rowl0 + r;
    #pragma unroll
    for (int nt2 = 0; nt2 < 2; nt2++)
      ctx[((size_t)bl * 512 + s) * 1024 + head * 64 + ch * 32 + nt2 * 16 + ln15] =
          __float2bfloat16(pacc[nt2][r]);
  }
}

// ---------------------------------------------------------------------------
// Edge h-projections, z-batched over 4 views (blockIdx.y).
// ---------------------------------------------------------------------------
__global__ __launch_bounds__(256)
void hv_k(const bf16* __restrict__ vt, const void* __restrict__ att_w,
          const void* __restrict__ att_b, float* __restrict__ h0,
          float* __restrict__ h1, const int* __restrict__ dflag)
{
  const int i0s[4] = {6, 0, 2, 4};
  const int i1s[4] = {7, 1, 3, 5};
  const int z = blockIdx.y;
  const int i0 = i0s[z], i1 = i1s[z];
  __shared__ float w0[64], w1[64];
  const int tid = threadIdx.x;
  const int bh = blockIdx.x;
  const int isbf = *dflag;
  if (tid < 64) {
    w0[tid] = ldx(att_w, i0 * 64 + tid, isbf);
    w1[tid] = ldx(att_w, i1 * 64 + tid, isbf);
  }
  __syncthreads();
  const bf16* vb = vt + (size_t)bh * 64 * 512 + tid * 2;
  float a00 = 0, a01 = 0, a10 = 0, a11 = 0;
  for (int d = 0; d < 64; d++) {
    ushort2 u = *(const ushort2*)(vb + (size_t)d * 512);
    float f0 = us2f(u.x), f1 = us2f(u.y);
    a00 += f0 * w0[d]; a10 += f1 * w0[d];
    a01 += f0 * w1[d]; a11 += f1 * w1[d];
  }
  float b0 = ldx(att_b, i0, isbf), b1 = ldx(att_b, i1, isbf);
  float* p0 = h0 + (size_t)z * 65536 + (size_t)bh * 512 + tid * 2;
  float* p1 = h1 + (size_t)z * 65536 + (size_t)bh * 512 + tid * 2;
  p0[0] = a00 + b0; p0[1] = a10 + b0;
  p1[0] = a01 + b1; p1[1] = a11 + b1;
}

// ---------------------------------------------------------------------------
// Fused edge view, z-batched over 4 views (round-7 verified: packed masks).
// ---------------------------------------------------------------------------
__global__ __launch_bounds__(256)
void edge_fused_k(const float* __restrict__ h0, const float* __restrict__ h1,
                  const unsigned char* __restrict__ maskp,
                  const bf16* __restrict__ vt, bf16* __restrict__ ctx5)
{
  __shared__ short P[32 * 512];   // 32 KB
  const int tid = threadIdx.x;
  const int w = tid >> 6, ln = tid & 63;
  const int ln15 = ln & 15, quad = ln >> 4;
  const int bh = blockIdx.x, qt = blockIdx.y, view = blockIdx.z;
  const int bl = bh >> 4;
  bf16* ctx = ctx5 + (size_t)(1 + view) * 4194304;

  // ---- phase 1: rows w*8 .. w*8+7, one full wave per row ----
  const int kb = ln * 8;
  {
    const float* hjp = h1 + (size_t)view * 65536 + (size_t)bh * 512 + kb;
    float4 hA = *(const float4*)hjp;
    float4 hB = *(const float4*)(hjp + 4);
    float hjv[8] = {hA.x, hA.y, hA.z, hA.w, hB.x, hB.y, hB.z, hB.w};
    const float* h0b = h0 + (size_t)view * 65536 + (size_t)bh * 512 + qt * 32 + w * 8;
    const unsigned char* mrow = maskp + (size_t)view * 262144 + (size_t)bl * 32768
                                + (size_t)(qt * 32 + w * 8) * 64 + ln;
    unsigned int mb = mrow[0];
    #pragma unroll 2
    for (int rr = 0; rr < 8; rr++) {
      unsigned int mbn = mrow[(rr < 7 ? rr + 1 : rr) * 64];
      int r = w * 8 + rr;              // local row in P, 0..31
      float hi = h0b[rr];
      float e[8];
      float m = -3.0e38f;
      #pragma unroll
      for (int j = 0; j < 8; j++) {
        float ej = hi + hjv[j];
        ej = ej >= 0.f ? ej : 0.01f * ej;
        e[j] = ((mb >> j) & 1) ? ej : NEGV;
        m = fmaxf(m, e[j]);
      }
      #pragma unroll
      for (int off = 32; off; off >>= 1) m = fmaxf(m, __shfl_xor(m, off));
      float ssum = 0.f;
      #pragma unroll
      for (int j = 0; j < 8; j++) { e[j] = __expf(e[j] - m); ssum += e[j]; }
      #pragma unroll
      for (int off = 32; off; off >>= 1) ssum += __shfl_xor(ssum, off);
      float inv = 1.f / ssum;
      bf16x8 pv;
      #pragma unroll
      for (int j = 0; j < 8; j++) pv[j] = (short)f2us(e[j] * inv);
      *(bf16x8*)&P[r * 512 + ((ln ^ (r & 7)) * 8)] = pv;
      mb = mbn;
    }
  }
  __syncthreads();

  // ---- phase 2: ctx[rows, d] = P @ V^T, V straight from global ----
  const bf16* vb = vt + (size_t)bh * 64 * 512;
  const int m0 = (w >> 1) * 16, d0 = (w & 1) * 32;
  f32x4 acc[2];
  acc[0] = (f32x4)(0.0f); acc[1] = (f32x4)(0.0f);

  const int ra = m0 + ln15;
  const int rsw = ra & 7;
  #pragma unroll 4
  for (int k0 = 0; k0 < 512; k0 += 32) {
    int gsel = (k0 >> 3) + quad;
    bf16x8 a = *(bf16x8*)&P[ra * 512 + ((gsel ^ rsw) * 8)];
    #pragma unroll
    for (int nt = 0; nt < 2; nt++) {
      bf16x8 b = *(const bf16x8*)(vb + (size_t)(d0 + nt * 16 + ln15) * 512 + k0 + quad * 8);
      acc[nt] = mfma_bf16(a, b, acc[nt]);
    }
  }

  const int head = bh & 15;
  #pragma unroll
  for (int r = 0; r < 4; r++) {
    int s = qt * 32 + m0 + quad * 4 + r;
    #pragma unroll
    for (int nt = 0; nt < 2; nt++)
      ctx[((size_t)bl * 512 + s) * 1024 + head * 64 + d0 + nt * 16 + ln15] =
          __float2bfloat16(acc[nt][r]);
  }
}

// ---------------------------------------------------------------------------
extern "C" void kernel_launch(void* const* d_in, const int* in_sizes, int n_in,
                              void* d_out, int out_size, void* d_ws, size_t ws_size,
                              hipStream_t stream)
{
  const void* key   = d_in[0];
  const void* value = d_in[1];
  const void* query = d_in[2];
  const int*  grh   = (const int*)d_in[3];
  const void* Wq = d_in[5];
  const void* bq = d_in[6];
  const void* Wk = d_in[7];
  const void* bk = d_in[8];
  const void* Wv = d_in[9];
  const void* bv = d_in[10];
  const void* rel_emb = d_in[11];
  const void* att_w = d_in[12];
  const void* att_b = d_in[13];
  const void* gate_w = d_in[14];
  const void* gate_b = d_in[15];
  const void* sub_w = d_in[16];
  const void* sub_b = d_in[17];

  // workspace layout (floats) — ~148 MB incl. 1 MB mask planes
  int* dflag = (int*)d_ws;
  float* base = (float*)d_ws;
  bf16* qbf = (bf16*)(base + 16);
  bf16* kbf = (bf16*)(base + 16 + 2097152);
  bf16* vtb = (bf16*)(base + 16 + 2 * 2097152);
  bf16* Wt  = (bf16*)(base + 16 + 3 * 2097152);
  float* G  = base + 16 + 3 * 2097152 + 6815744;
  float* h0 = G + 2162688;
  float* h1 = h0 + 262144;
  bf16* ctx5   = (bf16*)(h1 + 262144);
  bf16* gated5 = ctx5 + 5ull * 4194304;
  unsigned char* maskp = (unsigned char*)(gated5 + 5ull * 4194304);

  detect_k<<<dim3(1), dim3(64), 0, stream>>>(Wq, dflag);

  // pack grh -> 1 MB of per-view adjacency bit-planes (read grh ONCE)
  mask_pack_k<<<dim3(1024), dim3(256), 0, stream>>>(grh, maskp);

  // all 13 weight transposes in one launch
  wtrans_all_k<<<dim3(13 * 256), dim3(256), 0, stream>>>(
      Wq, Wk, Wv, gate_w, sub_w, Wt, dflag);

  // QKV projections batched (z: 0=q scaled, 1=k, 2=v transposed)
  qkv_gemm_k<<<dim3(32, 8, 3), dim3(256), 0, stream>>>(
      query, key, value, Wt, bq, bk, bv, qbf, kbf, vtb, dflag);

  qrel_k<<<dim3(16384), dim3(256), 0, stream>>>(qbf, rel_emb, G, dflag);

  // main view fully fused -> ctx5 slot 0 (+ top_attn to d_out)
  score_fused_k<<<dim3(128, 16), dim3(256), 0, stream>>>(
      qbf, kbf, G, vtb, rel_emb, ctx5, d_out, dflag);

  // edge views: h projections (4 views batched), then fused softmax+PV
  hv_k<<<dim3(128, 4), dim3(256), 0, stream>>>(vtb, att_w, att_b, h0, h1, dflag);
  edge_fused_k<<<dim3(128, 16, 4), dim3(256), 0, stream>>>(
      h0, h1, maskp, vtb, ctx5);

  // 5 gate GEMMs batched, then one K=5120 sub GEMM straight to d_out
  gate_gemm_k<<<dim3(32, 8, 5), dim3(256), 0, stream>>>(
      ctx5, Wt, gate_b, gated5, dflag);
  sub_gemm_k<<<dim3(32, 8), dim3(256), 0, stream>>>(
      gated5, Wt, sub_b, d_out, dflag);
}

// Round 9
// 756.354 us; speedup vs baseline: 1.3538x; 1.0965x over previous
//
#include <hip/hip_runtime.h>
#include <hip/hip_bf16.h>

typedef __hip_bfloat16 bf16;
typedef __attribute__((ext_vector_type(8))) short bf16x8;
typedef __attribute__((ext_vector_type(4))) float f32x4;

#define B_ 8
#define S_ 512
#define D_ 1024
#define H_ 16
#define NEGV -9.0e15f
#define WSL 1048576ull

__device__ __forceinline__ float bf2f(bf16 x) { return __bfloat162float(x); }
__device__ __forceinline__ float us2f(unsigned short u) {
  union { unsigned int i; float f; } c; c.i = ((unsigned int)u) << 16; return c.f;
}
__device__ __forceinline__ unsigned short f2us(float f) {
  bf16 h = __float2bfloat16(f);
  unsigned short u; __builtin_memcpy(&u, &h, 2); return u;
}
__device__ __forceinline__ float ldx(const void* p, size_t i, int isbf) {
  return isbf ? bf2f(((const bf16*)p)[i]) : ((const float*)p)[i];
}
struct F4 { float x, y, z, w; };
__device__ __forceinline__ F4 ld4(const void* p, size_t i, int isbf) {
  F4 r;
  if (isbf) {
    ushort4 u = *(const ushort4*)((const bf16*)p + i);
    r.x = us2f(u.x); r.y = us2f(u.y); r.z = us2f(u.z); r.w = us2f(u.w);
  } else {
    float4 d = *(const float4*)((const float*)p + i);
    r.x = d.x; r.y = d.y; r.z = d.z; r.w = d.w;
  }
  return r;
}
// 8 consecutive elements as bf16x8; converts if source is f32
__device__ __forceinline__ bf16x8 ld8bf(const void* p, size_t i, int isbf) {
  if (isbf) return *(const bf16x8*)((const bf16*)p + i);
  float4 a = *(const float4*)((const float*)p + i);
  float4 b = *(const float4*)((const float*)p + i + 4);
  bf16x8 r;
  r[0] = (short)f2us(a.x); r[1] = (short)f2us(a.y);
  r[2] = (short)f2us(a.z); r[3] = (short)f2us(a.w);
  r[4] = (short)f2us(b.x); r[5] = (short)f2us(b.y);
  r[6] = (short)f2us(b.z); r[7] = (short)f2us(b.w);
  return r;
}
__device__ __forceinline__ f32x4 mfma_bf16(bf16x8 a, bf16x8 b, f32x4 c) {
  return __builtin_amdgcn_mfma_f32_16x16x32_bf16(a, b, c, 0, 0, 0);
}
// Async global->LDS, 16B/lane. HW writes lane i at ldsbase + i*16 (linear);
// source address is per-lane, carrying the XOR swizzle (rule #21 pattern:
// linear dest + pre-swizzled source + swizzled read = verified LDS image).
__device__ __forceinline__ void gload16(const bf16* g, short* l) {
  __builtin_amdgcn_global_load_lds(
      (const __attribute__((address_space(1))) void*)g,
      (__attribute__((address_space(3))) void*)l, 16, 0, 0);
}

// Dtype detector (round-3 verified: picks f32 on this harness).
__global__ void detect_k(const void* __restrict__ w, int* __restrict__ flag)
{
  if (threadIdx.x == 0 && blockIdx.x == 0) {
    const unsigned short* u = (const unsigned short*)w;
    int sane = 0;
    for (int i = 0; i < 1024; i += 2) {
      float a = fabsf(us2f(u[i]));
      if (a == 0.f || (a > 9.5e-7f && a < 8.f)) sane++;
    }
    *flag = (sane > 256) ? 1 : 0;
  }
}

// ---------------------------------------------------------------------------
// QKV input convert: query/key/value (external dtype) -> contiguous bf16
// [z][4096][1024]. Same f2us rounding ld8bf applied inside the old GEMM, so
// numerics are bit-identical; enables global_load_lds staging of A.
// ---------------------------------------------------------------------------
__global__ __launch_bounds__(256)
void cvt_k(const void* __restrict__ q, const void* __restrict__ k,
           const void* __restrict__ v, bf16* __restrict__ out,
           const int* __restrict__ dflag)
{
  const int isbf = *dflag;
  const int z = blockIdx.y;
  const void* src = z == 0 ? q : (z == 1 ? k : v);
  size_t i = ((size_t)blockIdx.x * 256 + threadIdx.x) * 8;
  bf16x8 r = ld8bf(src, i, isbf);
  *(bf16x8*)(out + (size_t)z * 4194304 + i) = r;
}

// ---------------------------------------------------------------------------
// Mask bit-planes (round-7 verified): grh -> 1 MB packed adjacency bits.
// ---------------------------------------------------------------------------
__global__ __launch_bounds__(256)
void mask_pack_k(const int* __restrict__ grh, unsigned char* __restrict__ maskp)
{
  int t = blockIdx.x * 256 + threadIdx.x;     // [0, 8*512*64)
  int byte = t & 63, qi = (t >> 6) & 511, bl = t >> 15;
  const int* g = grh + ((size_t)bl * 512 + qi) * 512 + byte * 8;
  int4 a = *(const int4*)g;
  int4 b = *(const int4*)(g + 4);
  int gs[8] = {a.x, a.y, a.z, a.w, b.x, b.y, b.z, b.w};
  unsigned int m0 = 0, m1 = 0, m2 = 0, m3 = 0;
  #pragma unroll
  for (int j = 0; j < 8; j++) {
    int k = byte * 8 + j;
    int diag = (k == qi);
    m0 |= (unsigned int)(gs[j] > 1) << j;
    m1 |= (unsigned int)(gs[j] == (diag ? 4 : 2)) << j;
    m2 |= (unsigned int)(gs[j] == (diag ? 4 : 3)) << j;
    m3 |= (unsigned int)(gs[j] == 4) << j;
  }
  size_t o = (size_t)bl * 32768 + (size_t)qi * 64 + byte;
  maskp[o]          = (unsigned char)m0;
  maskp[o + 262144] = (unsigned char)m1;
  maskp[o + 524288] = (unsigned char)m2;
  maskp[o + 786432] = (unsigned char)m3;
}

// ---------------------------------------------------------------------------
// ALL 13 weight transposes in one launch (round-3 verified).
// ---------------------------------------------------------------------------
__global__ __launch_bounds__(256)
void wtrans_all_k(const void* __restrict__ Wq, const void* __restrict__ Wk,
                  const void* __restrict__ Wv, const void* __restrict__ gate_w,
                  const void* __restrict__ sub_w, bf16* __restrict__ Wt,
                  const int* __restrict__ dflag)
{
  const int isbf = *dflag;
  const int slot = blockIdx.x >> 8;
  const int blk = blockIdx.x & 255;
  const int gsrc[5] = {0, 5, 1, 2, 3};
  const void* W;
  size_t woff;
  if (slot < 3)      { W = slot == 0 ? Wq : (slot == 1 ? Wk : Wv); woff = 0; }
  else if (slot < 8) { W = gate_w; woff = (size_t)gsrc[slot - 3] * WSL; }
  else               { W = sub_w;  woff = (size_t)(slot - 8) * WSL; }
  bf16* out = Wt + (size_t)slot * WSL;

  __shared__ float t[64][68];
  const int tid = threadIdx.x;
  const int nt = blk & 15, kt = blk >> 4;
  {
    int r = tid >> 4, c4 = (tid & 15) * 4;
    #pragma unroll
    for (int i = 0; i < 4; i++) {
      int rr = r + i * 16;
      F4 v = ld4(W, woff + (size_t)(kt * 64 + rr) * 1024 + nt * 64 + c4, isbf);
      *(float4*)&t[rr][c4] = make_float4(v.x, v.y, v.z, v.w);
    }
  }
  __syncthreads();
  {
    int n = tid >> 4, k4 = (tid & 15) * 4;
    #pragma unroll
    for (int i = 0; i < 4; i++) {
      int nn = n + i * 16;
      ushort4 u;
      u.x = f2us(t[k4 + 0][nn]); u.y = f2us(t[k4 + 1][nn]);
      u.z = f2us(t[k4 + 2][nn]); u.w = f2us(t[k4 + 3][nn]);
      *(ushort4*)(out + (size_t)(nt * 64 + nn) * 1024 + kt * 64 + k4) = u;
    }
  }
}

// ---------------------------------------------------------------------------
// QKV projections, z-batched; A pre-converted bf16; async gload16 staging
// (round-8 post-mortem: old synchronous staging left MfmaUtil=VALUBusy=6%,
// pure latency-bound at 164 TF). LDS image identical to the verified XOR
// swizzle: linear dest + pre-swizzled source; compute/read side untouched.
// ---------------------------------------------------------------------------
__global__ __launch_bounds__(256)
void qkv_gemm_k(const bf16* __restrict__ qkvb, const bf16* __restrict__ Wt,
                const void* __restrict__ bqp, const void* __restrict__ bkp,
                const void* __restrict__ bvp, bf16* __restrict__ qbf,
                bf16* __restrict__ kbf, bf16* __restrict__ vtb,
                const int* __restrict__ dflag)
{
  const int isbf = *dflag;
  const int z = blockIdx.z;
  const bf16* A = qkvb + (size_t)z * 4194304;
  const void* bias = z == 0 ? bqp : (z == 1 ? bkp : bvp);
  bf16* outB = z == 0 ? qbf : (z == 1 ? kbf : vtb);
  const bf16* Wz = Wt + (size_t)z * WSL;
  const float scale = z == 0 ? 0.125f : 1.0f;
  const int vtrans = (z == 2);

  __shared__ short As[128 * 64];
  __shared__ short Bs[128 * 64];
  const int tid = threadIdx.x;
  const int w = tid >> 6, ln = tid & 63;
  const int ln15 = ln & 15, quad = ln >> 4;
  const int wm = (w & 1) * 64, wn = (w >> 1) * 64;
  const int bm = blockIdx.x * 128, bn = blockIdx.y * 128;
  const int rbase = w * 8 + (ln >> 3);            // row within 32-chunk
  const int goff = ((ln & 7) ^ (ln >> 3)) * 8;    // pre-swizzled src group
  f32x4 acc[4][4];
  #pragma unroll
  for (int mt = 0; mt < 4; mt++)
    #pragma unroll
    for (int nt = 0; nt < 4; nt++) acc[mt][nt] = (f32x4)(0.0f);

  for (int k0 = 0; k0 < 1024; k0 += 64) {
    #pragma unroll
    for (int i = 0; i < 4; i++) {
      int r = i * 32 + rbase;
      gload16(A + (size_t)(bm + r) * 1024 + k0 + goff,
              &As[(i * 32 + w * 8) * 64]);
      gload16(Wz + (size_t)(bn + r) * 1024 + k0 + goff,
              &Bs[(i * 32 + w * 8) * 64]);
    }
    __syncthreads();
    #pragma unroll
    for (int s = 0; s < 2; s++) {
      bf16x8 af[4], bfr[4];
      #pragma unroll
      for (int t = 0; t < 4; t++) {
        int ra = wm + t * 16 + ln15;
        af[t] = *(bf16x8*)&As[ra * 64 + (((s * 4 + quad) ^ (ra & 7)) * 8)];
        int rb = wn + t * 16 + ln15;
        bfr[t] = *(bf16x8*)&Bs[rb * 64 + (((s * 4 + quad) ^ (rb & 7)) * 8)];
      }
      #pragma unroll
      for (int mt = 0; mt < 4; mt++)
        #pragma unroll
        for (int nt = 0; nt < 4; nt++)
          acc[mt][nt] = mfma_bf16(af[mt], bfr[nt], acc[mt][nt]);
    }
    __syncthreads();
  }

  #pragma unroll
  for (int nt = 0; nt < 4; nt++) {
    int col = bn + wn + nt * 16 + ln15;
    float bv = ldx(bias, col, isbf);
    #pragma unroll
    for (int mt = 0; mt < 4; mt++) {
      #pragma unroll
      for (int r = 0; r < 4; r++) {
        int row = bm + wm + mt * 16 + quad * 4 + r;
        float v = (acc[mt][nt][r] + bv) * scale;
        int bb = row >> 9, s = row & 511;
        int h = col >> 6, d0 = col & 63;
        size_t o = vtrans ? (((size_t)(bb * 16 + h) * 64 + d0) * 512 + s)
                          : (((size_t)(bb * 16 + h) * 512 + s) * 64 + d0);
        outB[o] = __float2bfloat16(v);
      }
    }
  }
}

// ---------------------------------------------------------------------------
// Gate GEMMs, z-batched over 5 views; async gload16 staging.
// ---------------------------------------------------------------------------
__global__ __launch_bounds__(256)
void gate_gemm_k(const bf16* __restrict__ ctx5, const bf16* __restrict__ Wt,
                 const void* __restrict__ gate_b, bf16* __restrict__ gated5,
                 const int* __restrict__ dflag)
{
  const int isbf = *dflag;
  const int z = blockIdx.z;
  const int gsel[5] = {0, 5, 1, 2, 3};
  const bf16* A = ctx5 + (size_t)z * 4194304;
  bf16* outB = gated5 + (size_t)z * 4194304;
  const bf16* Wz = Wt + (size_t)(3 + z) * WSL;
  const size_t boff = (size_t)gsel[z] * 1024;

  __shared__ short As[128 * 64];
  __shared__ short Bs[128 * 64];
  const int tid = threadIdx.x;
  const int w = tid >> 6, ln = tid & 63;
  const int ln15 = ln & 15, quad = ln >> 4;
  const int wm = (w & 1) * 64, wn = (w >> 1) * 64;
  const int bm = blockIdx.x * 128, bn = blockIdx.y * 128;
  const int rbase = w * 8 + (ln >> 3);
  const int goff = ((ln & 7) ^ (ln >> 3)) * 8;
  f32x4 acc[4][4];
  #pragma unroll
  for (int mt = 0; mt < 4; mt++)
    #pragma unroll
    for (int nt = 0; nt < 4; nt++) acc[mt][nt] = (f32x4)(0.0f);

  for (int k0 = 0; k0 < 1024; k0 += 64) {
    #pragma unroll
    for (int i = 0; i < 4; i++) {
      int r = i * 32 + rbase;
      gload16(A + (size_t)(bm + r) * 1024 + k0 + goff,
              &As[(i * 32 + w * 8) * 64]);
      gload16(Wz + (size_t)(bn + r) * 1024 + k0 + goff,
              &Bs[(i * 32 + w * 8) * 64]);
    }
    __syncthreads();
    #pragma unroll
    for (int s = 0; s < 2; s++) {
      bf16x8 af[4], bfr[4];
      #pragma unroll
      for (int t = 0; t < 4; t++) {
        int ra = wm + t * 16 + ln15;
        af[t] = *(bf16x8*)&As[ra * 64 + (((s * 4 + quad) ^ (ra & 7)) * 8)];
        int rb = wn + t * 16 + ln15;
        bfr[t] = *(bf16x8*)&Bs[rb * 64 + (((s * 4 + quad) ^ (rb & 7)) * 8)];
      }
      #pragma unroll
      for (int mt = 0; mt < 4; mt++)
        #pragma unroll
        for (int nt = 0; nt < 4; nt++)
          acc[mt][nt] = mfma_bf16(af[mt], bfr[nt], acc[mt][nt]);
    }
    __syncthreads();
  }

  #pragma unroll
  for (int nt = 0; nt < 4; nt++) {
    int col = bn + wn + nt * 16 + ln15;
    float bv = ldx(gate_b, boff + col, isbf);
    #pragma unroll
    for (int mt = 0; mt < 4; mt++) {
      #pragma unroll
      for (int r = 0; r < 4; r++) {
        int row = bm + wm + mt * 16 + quad * 4 + r;
        float v = acc[mt][nt][r] + bv;
        float x = bf2f(A[(size_t)row * 1024 + col]);
        outB[(size_t)row * 1024 + col] = __float2bfloat16(x / (1.f + __expf(-v)));
      }
    }
  }
}

// ---------------------------------------------------------------------------
// Final sub GEMM: out = [gated_0|...|gated_4] @ sub_w + sub_b; gload16.
// ---------------------------------------------------------------------------
__global__ __launch_bounds__(256)
void sub_gemm_k(const bf16* __restrict__ gated5, const bf16* __restrict__ Wt,
                const void* __restrict__ sub_b, void* __restrict__ dout,
                const int* __restrict__ dflag)
{
  const int isbf = *dflag;
  __shared__ short As[128 * 64];
  __shared__ short Bs[128 * 64];
  const int tid = threadIdx.x;
  const int w = tid >> 6, ln = tid & 63;
  const int ln15 = ln & 15, quad = ln >> 4;
  const int wm = (w & 1) * 64, wn = (w >> 1) * 64;
  const int bm = blockIdx.x * 128, bn = blockIdx.y * 128;
  const int rbase = w * 8 + (ln >> 3);
  const int goff = ((ln & 7) ^ (ln >> 3)) * 8;
  f32x4 acc[4][4];
  #pragma unroll
  for (int mt = 0; mt < 4; mt++)
    #pragma unroll
    for (int nt = 0; nt < 4; nt++) acc[mt][nt] = (f32x4)(0.0f);

  for (int k0 = 0; k0 < 5120; k0 += 64) {
    const int slot = k0 >> 10, kk = k0 & 1023;
    const bf16* Ab = gated5 + (size_t)slot * 4194304;
    const bf16* Wz = Wt + (size_t)(8 + slot) * WSL;
    #pragma unroll
    for (int i = 0; i < 4; i++) {
      int r = i * 32 + rbase;
      gload16(Ab + (size_t)(bm + r) * 1024 + kk + goff,
              &As[(i * 32 + w * 8) * 64]);
      gload16(Wz + (size_t)(bn + r) * 1024 + kk + goff,
              &Bs[(i * 32 + w * 8) * 64]);
    }
    __syncthreads();
    #pragma unroll
    for (int s = 0; s < 2; s++) {
      bf16x8 af[4], bfr[4];
      #pragma unroll
      for (int t = 0; t < 4; t++) {
        int ra = wm + t * 16 + ln15;
        af[t] = *(bf16x8*)&As[ra * 64 + (((s * 4 + quad) ^ (ra & 7)) * 8)];
        int rb = wn + t * 16 + ln15;
        bfr[t] = *(bf16x8*)&Bs[rb * 64 + (((s * 4 + quad) ^ (rb & 7)) * 8)];
      }
      #pragma unroll
      for (int mt = 0; mt < 4; mt++)
        #pragma unroll
        for (int nt = 0; nt < 4; nt++)
          acc[mt][nt] = mfma_bf16(af[mt], bfr[nt], acc[mt][nt]);
    }
    __syncthreads();
  }

  #pragma unroll
  for (int nt = 0; nt < 4; nt++) {
    int col = bn + wn + nt * 16 + ln15;
    float bv = ldx(sub_b, col, isbf);
    #pragma unroll
    for (int mt = 0; mt < 4; mt++) {
      #pragma unroll
      for (int r = 0; r < 4; r++) {
        int row = bm + wm + mt * 16 + quad * 4 + r;
        float v = acc[mt][nt][r] + bv;
        size_t o = (size_t)row * 1024 + col;
        if (isbf) ((bf16*)dout)[o] = __float2bfloat16(v);
        else      ((float*)dout)[o] = v;
      }
    }
  }
}

// ---------------------------------------------------------------------------
// G[row][r] = q_row . rel_emb[r] (bf16 q). One wave per row.
// ---------------------------------------------------------------------------
__global__ __launch_bounds__(256)
void qrel_k(const bf16* __restrict__ qbf, const void* __restrict__ rel_emb,
            float* __restrict__ G, const int* __restrict__ dflag)
{
  const int isbf = *dflag;
  __shared__ float rel[33][65];
  __shared__ float qw[4][64];
  const int tid = threadIdx.x;
  for (int i = tid; i < 33 * 64; i += 256)
    rel[i >> 6][i & 63] = ldx(rel_emb, i, isbf);
  const int wv = tid >> 6, lane = tid & 63;
  const size_t row = (size_t)blockIdx.x * 4 + wv;
  qw[wv][lane] = bf2f(qbf[row * 64 + lane]);
  __syncthreads();
  if (lane < 33) {
    float s = 0.f;
    #pragma unroll
    for (int d = 0; d < 64; d++) s += qw[wv][d] * rel[lane][d];
    G[row * 33 + lane] = s;
  }
}

// ---------------------------------------------------------------------------
// Fully fused main view v5 (round-8 verified): 32 rows/block, wave = (row
// group, k-half), acc[16], cross-wave softmax via LDS stats exchange.
// ---------------------------------------------------------------------------
__global__ __launch_bounds__(256, 2)
void score_fused_k(const bf16* __restrict__ qbf, const bf16* __restrict__ kbf,
                   const float* __restrict__ G, const bf16* __restrict__ vt,
                   const void* __restrict__ rel_emb, bf16* __restrict__ ctx,
                   void* __restrict__ dout, const int* __restrict__ dflag)
{
  __shared__ short P[32 * 512];       // 32 KB, normalized bf16 P
  __shared__ float gbuf[32 * 33];     // 4224 B
  __shared__ float relbuf[33 * 64];   // 8448 B
  __shared__ float smax[4][16];       // per-wave partial row max
  __shared__ float ssumS[4][16];      // per-wave partial row sums
  __shared__ float sleS[4][16];
  __shared__ float sgeS[4][16];
  const int tid = threadIdx.x;
  const int w = tid >> 6, ln = tid & 63;
  const int ln15 = ln & 15, quad = ln >> 4;
  const int rowg = (w >> 1) * 16;     // row group base (0 or 16)
  const int ch = w & 1;               // k-col half (0 or 1)
  const int bh = blockIdx.x, qt = blockIdx.y;
  const size_t qrow0 = (size_t)bh * 512 + qt * 32;
  const int isbf = *dflag;

  // stage G (32 rows) + rel into LDS (valid after barrier #1)
  for (int i = tid; i < 32 * 33; i += 256) {
    int r = i / 33, c = i - r * 33;
    gbuf[i] = G[(qrow0 + r) * 33 + c];
  }
  for (int i = tid; i < 33 * 64; i += 256)
    relbuf[i] = ldx(rel_emb, i, isbf);

  // ---- QK^T for my rows x my col-half: fragments straight from global ----
  const bf16* qrow = qbf + (qrow0 + rowg + ln15) * 64;
  bf16x8 af0 = *(const bf16x8*)(qrow + quad * 8);
  bf16x8 af1 = *(const bf16x8*)(qrow + 32 + quad * 8);
  const bf16* kb = kbf + (size_t)bh * 512 * 64;
  f32x4 acc[16];
  #pragma unroll
  for (int t = 0; t < 16; t++) acc[t] = (f32x4)(0.0f);
  #pragma unroll
  for (int t = 0; t < 16; t++) {
    const bf16* kr = kb + (size_t)(ch * 256 + t * 16 + ln15) * 64 + quad * 8;
    bf16x8 b0 = *(const bf16x8*)kr;
    bf16x8 b1 = *(const bf16x8*)(kr + 32);
    acc[t] = mfma_bf16(af0, b0, acc[t]);
    acc[t] = mfma_bf16(af1, b1, acc[t]);
  }
  __syncthreads();   // #1: gbuf/relbuf valid

  // ---- rel bias + partial row max over my half ----
  const int qg = qt * 32 + rowg + quad * 4;        // global q of row r=0
  const int rowl0 = rowg + quad * 4;               // local row base
  float mx[4], ssum[4], sle[4], sge[4], inv[4];
  #pragma unroll
  for (int r = 0; r < 4; r++) mx[r] = -3.0e38f;
  #pragma unroll
  for (int t = 0; t < 16; t++) {
    int k = ch * 256 + t * 16 + ln15;
    #pragma unroll
    for (int r = 0; r < 4; r++) {
      int delta = k - (qg + r);
      int bkt = delta < -16 ? 0 : (delta > 16 ? 32 : delta + 16);
      float s = acc[t][r] + gbuf[(rowl0 + r) * 33 + bkt];
      acc[t][r] = s;
      mx[r] = fmaxf(mx[r], s);
    }
  }
  #pragma unroll
  for (int r = 0; r < 4; r++) {
    float m = mx[r];
    #pragma unroll
    for (int off = 1; off < 16; off <<= 1) m = fmaxf(m, __shfl_xor(m, off));
    mx[r] = m;
  }
  if (ln15 == 0) {
    #pragma unroll
    for (int r = 0; r < 4; r++) smax[w][quad * 4 + r] = mx[r];
  }
  __syncthreads();   // #2: partner partial max visible
  #pragma unroll
  for (int r = 0; r < 4; r++) {
    mx[r] = fmaxf(mx[r], smax[w ^ 1][quad * 4 + r]);   // exact global max
    ssum[r] = 0.f; sle[r] = 0.f; sge[r] = 0.f;
  }

  // ---- exp + partial sums over my half ----
  #pragma unroll
  for (int t = 0; t < 16; t++) {
    int k = ch * 256 + t * 16 + ln15;
    #pragma unroll
    for (int r = 0; r < 4; r++) {
      float p = __expf(acc[t][r] - mx[r]);
      acc[t][r] = p;
      ssum[r] += p;
      int delta = k - (qg + r);
      if (delta <= -16) sle[r] += p;
      if (delta >= 16) sge[r] += p;
    }
  }
  #pragma unroll
  for (int r = 0; r < 4; r++) {
    #pragma unroll
    for (int off = 1; off < 16; off <<= 1) {
      ssum[r] += __shfl_xor(ssum[r], off);
      sle[r] += __shfl_xor(sle[r], off);
      sge[r] += __shfl_xor(sge[r], off);
    }
  }
  if (ln15 == 0) {
    #pragma unroll
    for (int r = 0; r < 4; r++) {
      ssumS[w][quad * 4 + r] = ssum[r];
      sleS[w][quad * 4 + r] = sle[r];
      sgeS[w][quad * 4 + r] = sge[r];
    }
  }
  __syncthreads();   // #3: partner partial sums visible
  #pragma unroll
  for (int r = 0; r < 4; r++) {
    float tot = ssum[r] + ssumS[w ^ 1][quad * 4 + r];
    sle[r] += sleS[w ^ 1][quad * 4 + r];
    sge[r] += sgeS[w ^ 1][quad * 4 + r];
    inv[r] = 1.f / tot;
  }

  // ---- store normalized P (my 16 rows x my 256 cols), XOR swizzle ----
  #pragma unroll
  for (int t2 = 0; t2 < 16; t2++) {
    int gg = t2 * 2 + (ln15 >> 3);          // group within my half, 0..31
    int slot = gg ^ (quad << 1);
    #pragma unroll
    for (int r = 0; r < 4; r++) {
      int rowL = rowl0 + r;
      P[rowL * 512 + ch * 256 + slot * 8 + (ln15 & 7)] =
          (short)f2us(acc[t2][r] * inv[r]);
    }
  }
  __syncthreads();   // #4: full P tile valid

  // ---- top_attn (head-0 blocks): all threads, 32 rows x 512 cols ----
  if ((bh & 15) == 0) {
    const int bg = bh >> 4;
    for (int i = tid; i < 32 * 64; i += 256) {
      int rowL = i >> 6, g = i & 63;
      int chg = g >> 5, gg = g & 31;
      int slot = gg ^ (((rowL >> 2) & 3) << 1);
      bf16x8 u = *(bf16x8*)&P[rowL * 512 + chg * 256 + slot * 8];
      size_t o = (size_t)4194304 + (size_t)bg * 262144 +
                 (size_t)(qt * 32 + rowL) * 512 + g * 8;
      if (isbf) {
        *(bf16x8*)((bf16*)dout + o) = u;
      } else {
        float4 f0 = make_float4(us2f((unsigned short)u[0]), us2f((unsigned short)u[1]),
                                us2f((unsigned short)u[2]), us2f((unsigned short)u[3]));
        float4 f1 = make_float4(us2f((unsigned short)u[4]), us2f((unsigned short)u[5]),
                                us2f((unsigned short)u[6]), us2f((unsigned short)u[7]));
        *(float4*)((float*)dout + o) = f0;
        *(float4*)((float*)dout + o + 4) = f1;
      }
    }
  }

  // ---- PV: my rows (rowg..+15) x my d-half (ch*32..+31), all 512 k ----
  const bf16* vb = vt + (size_t)bh * 64 * 512;
  f32x4 pacc[2];
  pacc[0] = (f32x4)(0.0f); pacc[1] = (f32x4)(0.0f);
  const int ra = rowg + ln15;
  const int rsw = ((ln15 >> 2) & 3) << 1;   // q2 of row ra
  #pragma unroll
  for (int h2 = 0; h2 < 2; h2++) {
    #pragma unroll
    for (int kk = 0; kk < 8; kk++) {
      int gg = kk * 4 + quad;
      bf16x8 a = *(bf16x8*)&P[ra * 512 + h2 * 256 + ((gg ^ rsw) * 8)];
      int k0 = h2 * 256 + kk * 32;
      #pragma unroll
      for (int nt2 = 0; nt2 < 2; nt2++) {
        int dcol = ch * 32 + nt2 * 16 + ln15;
        bf16x8 b = *(const bf16x8*)(vb + (size_t)dcol * 512 + k0 + quad * 8);
        pacc[nt2] = mfma_bf16(a, b, pacc[nt2]);
      }
    }
  }

  // ---- diagonal band of arel@rel (rel from LDS, normalized P from LDS) ----
  for (int rr = 1; rr < 32; rr++) {
    float av[4];
    #pragma unroll
    for (int r = 0; r < 4; r++) {
      int k = qg + r + rr - 16;
      av[r] = 0.f;
      if (k >= 0 && k < 512) {
        int g = k >> 3, chg = g >> 5, gg = g & 31;
        int slot = gg ^ (quad << 1);
        av[r] = us2f((unsigned short)P[(rowl0 + r) * 512 + chg * 256 +
                                       slot * 8 + (k & 7)]);
      }
    }
    #pragma unroll
    for (int nt2 = 0; nt2 < 2; nt2++) {
      float relv = relbuf[rr * 64 + ch * 32 + nt2 * 16 + ln15];
      #pragma unroll
      for (int r = 0; r < 4; r++) pacc[nt2][r] += av[r] * relv;
    }
  }

  // sle/sge terms (buckets 0 and 32)
  #pragma unroll
  for (int nt2 = 0; nt2 < 2; nt2++) {
    float r0v = relbuf[ch * 32 + nt2 * 16 + ln15];
    float r32v = relbuf[32 * 64 + ch * 32 + nt2 * 16 + ln15];
    #pragma unroll
    for (int r = 0; r < 4; r++)
      pacc[nt2][r] += sle[r] * inv[r] * r0v + sge[r] * inv[r] * r32v;
  }

  // ctx write (slot 0 layout [bl*512+s][1024]); my rows x my d-half
  const int bl = bh >> 4, head = bh & 15;
  #pragma unroll
  for (int r = 0; r < 4; r++) {
    int s = qt * 32 + rowl0 + r;
    #pragma unroll
    for (int nt2 = 0; nt2 < 2; nt2++)
      ctx[((size_t)bl * 512 + s) * 1024 + head * 64 + ch * 32 + nt2 * 16 + ln15] =
          __float2bfloat16(pacc[nt2][r]);
  }
}

// ---------------------------------------------------------------------------
// Edge h-projections, z-batched over 4 views (blockIdx.y).
// ---------------------------------------------------------------------------
__global__ __launch_bounds__(256)
void hv_k(const bf16* __restrict__ vt, const void* __restrict__ att_w,
          const void* __restrict__ att_b, float* __restrict__ h0,
          float* __restrict__ h1, const int* __restrict__ dflag)
{
  const int i0s[4] = {6, 0, 2, 4};
  const int i1s[4] = {7, 1, 3, 5};
  const int z = blockIdx.y;
  const int i0 = i0s[z], i1 = i1s[z];
  __shared__ float w0[64], w1[64];
  const int tid = threadIdx.x;
  const int bh = blockIdx.x;
  const int isbf = *dflag;
  if (tid < 64) {
    w0[tid] = ldx(att_w, i0 * 64 + tid, isbf);
    w1[tid] = ldx(att_w, i1 * 64 + tid, isbf);
  }
  __syncthreads();
  const bf16* vb = vt + (size_t)bh * 64 * 512 + tid * 2;
  float a00 = 0, a01 = 0, a10 = 0, a11 = 0;
  for (int d = 0; d < 64; d++) {
    ushort2 u = *(const ushort2*)(vb + (size_t)d * 512);
    float f0 = us2f(u.x), f1 = us2f(u.y);
    a00 += f0 * w0[d]; a10 += f1 * w0[d];
    a01 += f0 * w1[d]; a11 += f1 * w1[d];
  }
  float b0 = ldx(att_b, i0, isbf), b1 = ldx(att_b, i1, isbf);
  float* p0 = h0 + (size_t)z * 65536 + (size_t)bh * 512 + tid * 2;
  float* p1 = h1 + (size_t)z * 65536 + (size_t)bh * 512 + tid * 2;
  p0[0] = a00 + b0; p0[1] = a10 + b0;
  p1[0] = a01 + b1; p1[1] = a11 + b1;
}

// ---------------------------------------------------------------------------
// Fused edge view, z-batched over 4 views (round-7 verified: packed masks).
// ---------------------------------------------------------------------------
__global__ __launch_bounds__(256)
void edge_fused_k(const float* __restrict__ h0, const float* __restrict__ h1,
                  const unsigned char* __restrict__ maskp,
                  const bf16* __restrict__ vt, bf16* __restrict__ ctx5)
{
  __shared__ short P[32 * 512];   // 32 KB
  const int tid = threadIdx.x;
  const int w = tid >> 6, ln = tid & 63;
  const int ln15 = ln & 15, quad = ln >> 4;
  const int bh = blockIdx.x, qt = blockIdx.y, view = blockIdx.z;
  const int bl = bh >> 4;
  bf16* ctx = ctx5 + (size_t)(1 + view) * 4194304;

  // ---- phase 1: rows w*8 .. w*8+7, one full wave per row ----
  const int kb = ln * 8;
  {
    const float* hjp = h1 + (size_t)view * 65536 + (size_t)bh * 512 + kb;
    float4 hA = *(const float4*)hjp;
    float4 hB = *(const float4*)(hjp + 4);
    float hjv[8] = {hA.x, hA.y, hA.z, hA.w, hB.x, hB.y, hB.z, hB.w};
    const float* h0b = h0 + (size_t)view * 65536 + (size_t)bh * 512 + qt * 32 + w * 8;
    const unsigned char* mrow = maskp + (size_t)view * 262144 + (size_t)bl * 32768
                                + (size_t)(qt * 32 + w * 8) * 64 + ln;
    unsigned int mb = mrow[0];
    #pragma unroll 2
    for (int rr = 0; rr < 8; rr++) {
      unsigned int mbn = mrow[(rr < 7 ? rr + 1 : rr) * 64];
      int r = w * 8 + rr;              // local row in P, 0..31
      float hi = h0b[rr];
      float e[8];
      float m = -3.0e38f;
      #pragma unroll
      for (int j = 0; j < 8; j++) {
        float ej = hi + hjv[j];
        ej = ej >= 0.f ? ej : 0.01f * ej;
        e[j] = ((mb >> j) & 1) ? ej : NEGV;
        m = fmaxf(m, e[j]);
      }
      #pragma unroll
      for (int off = 32; off; off >>= 1) m = fmaxf(m, __shfl_xor(m, off));
      float ssum = 0.f;
      #pragma unroll
      for (int j = 0; j < 8; j++) { e[j] = __expf(e[j] - m); ssum += e[j]; }
      #pragma unroll
      for (int off = 32; off; off >>= 1) ssum += __shfl_xor(ssum, off);
      float inv = 1.f / ssum;
      bf16x8 pv;
      #pragma unroll
      for (int j = 0; j < 8; j++) pv[j] = (short)f2us(e[j] * inv);
      *(bf16x8*)&P[r * 512 + ((ln ^ (r & 7)) * 8)] = pv;
      mb = mbn;
    }
  }
  __syncthreads();

  // ---- phase 2: ctx[rows, d] = P @ V^T, V straight from global ----
  const bf16* vb = vt + (size_t)bh * 64 * 512;
  const int m0 = (w >> 1) * 16, d0 = (w & 1) * 32;
  f32x4 acc[2];
  acc[0] = (f32x4)(0.0f); acc[1] = (f32x4)(0.0f);

  const int ra = m0 + ln15;
  const int rsw = ra & 7;
  #pragma unroll 4
  for (int k0 = 0; k0 < 512; k0 += 32) {
    int gsel = (k0 >> 3) + quad;
    bf16x8 a = *(bf16x8*)&P[ra * 512 + ((gsel ^ rsw) * 8)];
    #pragma unroll
    for (int nt = 0; nt < 2; nt++) {
      bf16x8 b = *(const bf16x8*)(vb + (size_t)(d0 + nt * 16 + ln15) * 512 + k0 + quad * 8);
      acc[nt] = mfma_bf16(a, b, acc[nt]);
    }
  }

  const int head = bh & 15;
  #pragma unroll
  for (int r = 0; r < 4; r++) {
    int s = qt * 32 + m0 + quad * 4 + r;
    #pragma unroll
    for (int nt = 0; nt < 2; nt++)
      ctx[((size_t)bl * 512 + s) * 1024 + head * 64 + d0 + nt * 16 + ln15] =
          __float2bfloat16(acc[nt][r]);
  }
}

// ---------------------------------------------------------------------------
extern "C" void kernel_launch(void* const* d_in, const int* in_sizes, int n_in,
                              void* d_out, int out_size, void* d_ws, size_t ws_size,
                              hipStream_t stream)
{
  const void* key   = d_in[0];
  const void* value = d_in[1];
  const void* query = d_in[2];
  const int*  grh   = (const int*)d_in[3];
  const void* Wq = d_in[5];
  const void* bq = d_in[6];
  const void* Wk = d_in[7];
  const void* bk = d_in[8];
  const void* Wv = d_in[9];
  const void* bv = d_in[10];
  const void* rel_emb = d_in[11];
  const void* att_w = d_in[12];
  const void* att_b = d_in[13];
  const void* gate_w = d_in[14];
  const void* gate_b = d_in[15];
  const void* sub_w = d_in[16];
  const void* sub_b = d_in[17];

  // workspace layout (floats) — ~131 MB incl. mask planes + qkvb
  int* dflag = (int*)d_ws;
  float* base = (float*)d_ws;
  bf16* qbf = (bf16*)(base + 16);
  bf16* kbf = (bf16*)(base + 16 + 2097152);
  bf16* vtb = (bf16*)(base + 16 + 2 * 2097152);
  bf16* Wt  = (bf16*)(base + 16 + 3 * 2097152);
  float* G  = base + 16 + 3 * 2097152 + 6815744;
  float* h0 = G + 2162688;
  float* h1 = h0 + 262144;
  bf16* ctx5   = (bf16*)(h1 + 262144);
  bf16* gated5 = ctx5 + 5ull * 4194304;
  unsigned char* maskp = (unsigned char*)(gated5 + 5ull * 4194304);
  bf16* qkvb = (bf16*)(maskp + 1048576);

  detect_k<<<dim3(1), dim3(64), 0, stream>>>(Wq, dflag);

  // pack grh -> 1 MB of per-view adjacency bit-planes (read grh ONCE)
  mask_pack_k<<<dim3(1024), dim3(256), 0, stream>>>(grh, maskp);

  // convert q/k/v inputs -> bf16 (enables async LDS staging in qkv GEMM)
  cvt_k<<<dim3(2048, 3), dim3(256), 0, stream>>>(query, key, value, qkvb, dflag);

  // all 13 weight transposes in one launch
  wtrans_all_k<<<dim3(13 * 256), dim3(256), 0, stream>>>(
      Wq, Wk, Wv, gate_w, sub_w, Wt, dflag);

  // QKV projections batched (z: 0=q scaled, 1=k, 2=v transposed)
  qkv_gemm_k<<<dim3(32, 8, 3), dim3(256), 0, stream>>>(
      qkvb, Wt, bq, bk, bv, qbf, kbf, vtb, dflag);

  qrel_k<<<dim3(16384), dim3(256), 0, stream>>>(qbf, rel_emb, G, dflag);

  // main view fully fused -> ctx5 slot 0 (+ top_attn to d_out)
  score_fused_k<<<dim3(128, 16), dim3(256), 0, stream>>>(
      qbf, kbf, G, vtb, rel_emb, ctx5, d_out, dflag);

  // edge views: h projections (4 views batched), then fused softmax+PV
  hv_k<<<dim3(128, 4), dim3(256), 0, stream>>>(vtb, att_w, att_b, h0, h1, dflag);
  edge_fused_k<<<dim3(128, 16, 4), dim3(256), 0, stream>>>(
      h0, h1, maskp, vtb, ctx5);

  // 5 gate GEMMs batched, then one K=5120 sub GEMM straight to d_out
  gate_gemm_k<<<dim3(32, 8, 5), dim3(256), 0, stream>>>(
      ctx5, Wt, gate_b, gated5, dflag);
  sub_gemm_k<<<dim3(32, 8), dim3(256), 0, stream>>>(
      gated5, Wt, sub_b, d_out, dflag);
}

// Round 10
// 753.449 us; speedup vs baseline: 1.3590x; 1.0039x over previous
//
#include <hip/hip_runtime.h>
#include <hip/hip_bf16.h>

typedef __hip_bfloat16 bf16;
typedef __attribute__((ext_vector_type(8))) short bf16x8;
typedef __attribute__((ext_vector_type(4))) float f32x4;

#define B_ 8
#define S_ 512
#define D_ 1024
#define H_ 16
#define NEGV -9.0e15f
#define WSL 1048576ull

__device__ __forceinline__ float bf2f(bf16 x) { return __bfloat162float(x); }
__device__ __forceinline__ float us2f(unsigned short u) {
  union { unsigned int i; float f; } c; c.i = ((unsigned int)u) << 16; return c.f;
}
__device__ __forceinline__ unsigned short f2us(float f) {
  bf16 h = __float2bfloat16(f);
  unsigned short u; __builtin_memcpy(&u, &h, 2); return u;
}
__device__ __forceinline__ float ldx(const void* p, size_t i, int isbf) {
  return isbf ? bf2f(((const bf16*)p)[i]) : ((const float*)p)[i];
}
struct F4 { float x, y, z, w; };
__device__ __forceinline__ F4 ld4(const void* p, size_t i, int isbf) {
  F4 r;
  if (isbf) {
    ushort4 u = *(const ushort4*)((const bf16*)p + i);
    r.x = us2f(u.x); r.y = us2f(u.y); r.z = us2f(u.z); r.w = us2f(u.w);
  } else {
    float4 d = *(const float4*)((const float*)p + i);
    r.x = d.x; r.y = d.y; r.z = d.z; r.w = d.w;
  }
  return r;
}
// 8 consecutive elements as bf16x8; converts if source is f32
__device__ __forceinline__ bf16x8 ld8bf(const void* p, size_t i, int isbf) {
  if (isbf) return *(const bf16x8*)((const bf16*)p + i);
  float4 a = *(const float4*)((const float*)p + i);
  float4 b = *(const float4*)((const float*)p + i + 4);
  bf16x8 r;
  r[0] = (short)f2us(a.x); r[1] = (short)f2us(a.y);
  r[2] = (short)f2us(a.z); r[3] = (short)f2us(a.w);
  r[4] = (short)f2us(b.x); r[5] = (short)f2us(b.y);
  r[6] = (short)f2us(b.z); r[7] = (short)f2us(b.w);
  return r;
}
__device__ __forceinline__ f32x4 mfma_bf16(bf16x8 a, bf16x8 b, f32x4 c) {
  return __builtin_amdgcn_mfma_f32_16x16x32_bf16(a, b, c, 0, 0, 0);
}
// Async global->LDS, 16B/lane. HW writes lane i at ldsbase + i*16 (linear);
// source address is per-lane, carrying the XOR swizzle (rule #21 pattern:
// linear dest + pre-swizzled source + swizzled read = verified LDS image).
__device__ __forceinline__ void gload16(const bf16* g, short* l) {
  __builtin_amdgcn_global_load_lds(
      (const __attribute__((address_space(1))) void*)g,
      (__attribute__((address_space(3))) void*)l, 16, 0, 0);
}

// Dtype detector (round-3 verified: picks f32 on this harness).
__global__ void detect_k(const void* __restrict__ w, int* __restrict__ flag)
{
  if (threadIdx.x == 0 && blockIdx.x == 0) {
    const unsigned short* u = (const unsigned short*)w;
    int sane = 0;
    for (int i = 0; i < 1024; i += 2) {
      float a = fabsf(us2f(u[i]));
      if (a == 0.f || (a > 9.5e-7f && a < 8.f)) sane++;
    }
    *flag = (sane > 256) ? 1 : 0;
  }
}

// ---------------------------------------------------------------------------
// QKV input convert: query/key/value (external dtype) -> contiguous bf16
// [z][4096][1024]. Same f2us rounding the GEMM applied; bit-identical.
// ---------------------------------------------------------------------------
__global__ __launch_bounds__(256)
void cvt_k(const void* __restrict__ q, const void* __restrict__ k,
           const void* __restrict__ v, bf16* __restrict__ out,
           const int* __restrict__ dflag)
{
  const int isbf = *dflag;
  const int z = blockIdx.y;
  const void* src = z == 0 ? q : (z == 1 ? k : v);
  size_t i = ((size_t)blockIdx.x * 256 + threadIdx.x) * 8;
  bf16x8 r = ld8bf(src, i, isbf);
  *(bf16x8*)(out + (size_t)z * 4194304 + i) = r;
}

// ---------------------------------------------------------------------------
// Mask bit-planes (round-7 verified): grh -> 1 MB packed adjacency bits.
// ---------------------------------------------------------------------------
__global__ __launch_bounds__(256)
void mask_pack_k(const int* __restrict__ grh, unsigned char* __restrict__ maskp)
{
  int t = blockIdx.x * 256 + threadIdx.x;     // [0, 8*512*64)
  int byte = t & 63, qi = (t >> 6) & 511, bl = t >> 15;
  const int* g = grh + ((size_t)bl * 512 + qi) * 512 + byte * 8;
  int4 a = *(const int4*)g;
  int4 b = *(const int4*)(g + 4);
  int gs[8] = {a.x, a.y, a.z, a.w, b.x, b.y, b.z, b.w};
  unsigned int m0 = 0, m1 = 0, m2 = 0, m3 = 0;
  #pragma unroll
  for (int j = 0; j < 8; j++) {
    int k = byte * 8 + j;
    int diag = (k == qi);
    m0 |= (unsigned int)(gs[j] > 1) << j;
    m1 |= (unsigned int)(gs[j] == (diag ? 4 : 2)) << j;
    m2 |= (unsigned int)(gs[j] == (diag ? 4 : 3)) << j;
    m3 |= (unsigned int)(gs[j] == 4) << j;
  }
  size_t o = (size_t)bl * 32768 + (size_t)qi * 64 + byte;
  maskp[o]          = (unsigned char)m0;
  maskp[o + 262144] = (unsigned char)m1;
  maskp[o + 524288] = (unsigned char)m2;
  maskp[o + 786432] = (unsigned char)m3;
}

// ---------------------------------------------------------------------------
// ALL 13 weight transposes in one launch (round-3 verified).
// ---------------------------------------------------------------------------
__global__ __launch_bounds__(256)
void wtrans_all_k(const void* __restrict__ Wq, const void* __restrict__ Wk,
                  const void* __restrict__ Wv, const void* __restrict__ gate_w,
                  const void* __restrict__ sub_w, bf16* __restrict__ Wt,
                  const int* __restrict__ dflag)
{
  const int isbf = *dflag;
  const int slot = blockIdx.x >> 8;
  const int blk = blockIdx.x & 255;
  const int gsrc[5] = {0, 5, 1, 2, 3};
  const void* W;
  size_t woff;
  if (slot < 3)      { W = slot == 0 ? Wq : (slot == 1 ? Wk : Wv); woff = 0; }
  else if (slot < 8) { W = gate_w; woff = (size_t)gsrc[slot - 3] * WSL; }
  else               { W = sub_w;  woff = (size_t)(slot - 8) * WSL; }
  bf16* out = Wt + (size_t)slot * WSL;

  __shared__ float t[64][68];
  const int tid = threadIdx.x;
  const int nt = blk & 15, kt = blk >> 4;
  {
    int r = tid >> 4, c4 = (tid & 15) * 4;
    #pragma unroll
    for (int i = 0; i < 4; i++) {
      int rr = r + i * 16;
      F4 v = ld4(W, woff + (size_t)(kt * 64 + rr) * 1024 + nt * 64 + c4, isbf);
      *(float4*)&t[rr][c4] = make_float4(v.x, v.y, v.z, v.w);
    }
  }
  __syncthreads();
  {
    int n = tid >> 4, k4 = (tid & 15) * 4;
    #pragma unroll
    for (int i = 0; i < 4; i++) {
      int nn = n + i * 16;
      ushort4 u;
      u.x = f2us(t[k4 + 0][nn]); u.y = f2us(t[k4 + 1][nn]);
      u.z = f2us(t[k4 + 2][nn]); u.w = f2us(t[k4 + 3][nn]);
      *(ushort4*)(out + (size_t)(nt * 64 + nn) * 1024 + kt * 64 + k4) = u;
    }
  }
}

// ---------------------------------------------------------------------------
// QKV projections, z-batched; A pre-converted bf16; async gload16 staging
// (round-9 verified: linear dest + pre-swizzled source).
// ---------------------------------------------------------------------------
__global__ __launch_bounds__(256)
void qkv_gemm_k(const bf16* __restrict__ qkvb, const bf16* __restrict__ Wt,
                const void* __restrict__ bqp, const void* __restrict__ bkp,
                const void* __restrict__ bvp, bf16* __restrict__ qbf,
                bf16* __restrict__ kbf, bf16* __restrict__ vtb,
                const int* __restrict__ dflag)
{
  const int isbf = *dflag;
  const int z = blockIdx.z;
  const bf16* A = qkvb + (size_t)z * 4194304;
  const void* bias = z == 0 ? bqp : (z == 1 ? bkp : bvp);
  bf16* outB = z == 0 ? qbf : (z == 1 ? kbf : vtb);
  const bf16* Wz = Wt + (size_t)z * WSL;
  const float scale = z == 0 ? 0.125f : 1.0f;
  const int vtrans = (z == 2);

  __shared__ short As[128 * 64];
  __shared__ short Bs[128 * 64];
  const int tid = threadIdx.x;
  const int w = tid >> 6, ln = tid & 63;
  const int ln15 = ln & 15, quad = ln >> 4;
  const int wm = (w & 1) * 64, wn = (w >> 1) * 64;
  const int bm = blockIdx.x * 128, bn = blockIdx.y * 128;
  const int rbase = w * 8 + (ln >> 3);            // row within 32-chunk
  const int goff = ((ln & 7) ^ (ln >> 3)) * 8;    // pre-swizzled src group
  f32x4 acc[4][4];
  #pragma unroll
  for (int mt = 0; mt < 4; mt++)
    #pragma unroll
    for (int nt = 0; nt < 4; nt++) acc[mt][nt] = (f32x4)(0.0f);

  for (int k0 = 0; k0 < 1024; k0 += 64) {
    #pragma unroll
    for (int i = 0; i < 4; i++) {
      int r = i * 32 + rbase;
      gload16(A + (size_t)(bm + r) * 1024 + k0 + goff,
              &As[(i * 32 + w * 8) * 64]);
      gload16(Wz + (size_t)(bn + r) * 1024 + k0 + goff,
              &Bs[(i * 32 + w * 8) * 64]);
    }
    __syncthreads();
    #pragma unroll
    for (int s = 0; s < 2; s++) {
      bf16x8 af[4], bfr[4];
      #pragma unroll
      for (int t = 0; t < 4; t++) {
        int ra = wm + t * 16 + ln15;
        af[t] = *(bf16x8*)&As[ra * 64 + (((s * 4 + quad) ^ (ra & 7)) * 8)];
        int rb = wn + t * 16 + ln15;
        bfr[t] = *(bf16x8*)&Bs[rb * 64 + (((s * 4 + quad) ^ (rb & 7)) * 8)];
      }
      #pragma unroll
      for (int mt = 0; mt < 4; mt++)
        #pragma unroll
        for (int nt = 0; nt < 4; nt++)
          acc[mt][nt] = mfma_bf16(af[mt], bfr[nt], acc[mt][nt]);
    }
    __syncthreads();
  }

  #pragma unroll
  for (int nt = 0; nt < 4; nt++) {
    int col = bn + wn + nt * 16 + ln15;
    float bv = ldx(bias, col, isbf);
    #pragma unroll
    for (int mt = 0; mt < 4; mt++) {
      #pragma unroll
      for (int r = 0; r < 4; r++) {
        int row = bm + wm + mt * 16 + quad * 4 + r;
        float v = (acc[mt][nt][r] + bv) * scale;
        int bb = row >> 9, s = row & 511;
        int h = col >> 6, d0 = col & 63;
        size_t o = vtrans ? (((size_t)(bb * 16 + h) * 64 + d0) * 512 + s)
                          : (((size_t)(bb * 16 + h) * 512 + s) * 64 + d0);
        outB[o] = __float2bfloat16(v);
      }
    }
  }
}

// ---------------------------------------------------------------------------
// Gate GEMMs, z-batched over 5 views; async gload16 staging.
// ---------------------------------------------------------------------------
__global__ __launch_bounds__(256)
void gate_gemm_k(const bf16* __restrict__ ctx5, const bf16* __restrict__ Wt,
                 const void* __restrict__ gate_b, bf16* __restrict__ gated5,
                 const int* __restrict__ dflag)
{
  const int isbf = *dflag;
  const int z = blockIdx.z;
  const int gsel[5] = {0, 5, 1, 2, 3};
  const bf16* A = ctx5 + (size_t)z * 4194304;
  bf16* outB = gated5 + (size_t)z * 4194304;
  const bf16* Wz = Wt + (size_t)(3 + z) * WSL;
  const size_t boff = (size_t)gsel[z] * 1024;

  __shared__ short As[128 * 64];
  __shared__ short Bs[128 * 64];
  const int tid = threadIdx.x;
  const int w = tid >> 6, ln = tid & 63;
  const int ln15 = ln & 15, quad = ln >> 4;
  const int wm = (w & 1) * 64, wn = (w >> 1) * 64;
  const int bm = blockIdx.x * 128, bn = blockIdx.y * 128;
  const int rbase = w * 8 + (ln >> 3);
  const int goff = ((ln & 7) ^ (ln >> 3)) * 8;
  f32x4 acc[4][4];
  #pragma unroll
  for (int mt = 0; mt < 4; mt++)
    #pragma unroll
    for (int nt = 0; nt < 4; nt++) acc[mt][nt] = (f32x4)(0.0f);

  for (int k0 = 0; k0 < 1024; k0 += 64) {
    #pragma unroll
    for (int i = 0; i < 4; i++) {
      int r = i * 32 + rbase;
      gload16(A + (size_t)(bm + r) * 1024 + k0 + goff,
              &As[(i * 32 + w * 8) * 64]);
      gload16(Wz + (size_t)(bn + r) * 1024 + k0 + goff,
              &Bs[(i * 32 + w * 8) * 64]);
    }
    __syncthreads();
    #pragma unroll
    for (int s = 0; s < 2; s++) {
      bf16x8 af[4], bfr[4];
      #pragma unroll
      for (int t = 0; t < 4; t++) {
        int ra = wm + t * 16 + ln15;
        af[t] = *(bf16x8*)&As[ra * 64 + (((s * 4 + quad) ^ (ra & 7)) * 8)];
        int rb = wn + t * 16 + ln15;
        bfr[t] = *(bf16x8*)&Bs[rb * 64 + (((s * 4 + quad) ^ (rb & 7)) * 8)];
      }
      #pragma unroll
      for (int mt = 0; mt < 4; mt++)
        #pragma unroll
        for (int nt = 0; nt < 4; nt++)
          acc[mt][nt] = mfma_bf16(af[mt], bfr[nt], acc[mt][nt]);
    }
    __syncthreads();
  }

  #pragma unroll
  for (int nt = 0; nt < 4; nt++) {
    int col = bn + wn + nt * 16 + ln15;
    float bv = ldx(gate_b, boff + col, isbf);
    #pragma unroll
    for (int mt = 0; mt < 4; mt++) {
      #pragma unroll
      for (int r = 0; r < 4; r++) {
        int row = bm + wm + mt * 16 + quad * 4 + r;
        float v = acc[mt][nt][r] + bv;
        float x = bf2f(A[(size_t)row * 1024 + col]);
        outB[(size_t)row * 1024 + col] = __float2bfloat16(x / (1.f + __expf(-v)));
      }
    }
  }
}

// ---------------------------------------------------------------------------
// Final sub GEMM: out = [gated_0|...|gated_4] @ sub_w + sub_b; gload16.
// ---------------------------------------------------------------------------
__global__ __launch_bounds__(256)
void sub_gemm_k(const bf16* __restrict__ gated5, const bf16* __restrict__ Wt,
                const void* __restrict__ sub_b, void* __restrict__ dout,
                const int* __restrict__ dflag)
{
  const int isbf = *dflag;
  __shared__ short As[128 * 64];
  __shared__ short Bs[128 * 64];
  const int tid = threadIdx.x;
  const int w = tid >> 6, ln = tid & 63;
  const int ln15 = ln & 15, quad = ln >> 4;
  const int wm = (w & 1) * 64, wn = (w >> 1) * 64;
  const int bm = blockIdx.x * 128, bn = blockIdx.y * 128;
  const int rbase = w * 8 + (ln >> 3);
  const int goff = ((ln & 7) ^ (ln >> 3)) * 8;
  f32x4 acc[4][4];
  #pragma unroll
  for (int mt = 0; mt < 4; mt++)
    #pragma unroll
    for (int nt = 0; nt < 4; nt++) acc[mt][nt] = (f32x4)(0.0f);

  for (int k0 = 0; k0 < 5120; k0 += 64) {
    const int slot = k0 >> 10, kk = k0 & 1023;
    const bf16* Ab = gated5 + (size_t)slot * 4194304;
    const bf16* Wz = Wt + (size_t)(8 + slot) * WSL;
    #pragma unroll
    for (int i = 0; i < 4; i++) {
      int r = i * 32 + rbase;
      gload16(Ab + (size_t)(bm + r) * 1024 + kk + goff,
              &As[(i * 32 + w * 8) * 64]);
      gload16(Wz + (size_t)(bn + r) * 1024 + kk + goff,
              &Bs[(i * 32 + w * 8) * 64]);
    }
    __syncthreads();
    #pragma unroll
    for (int s = 0; s < 2; s++) {
      bf16x8 af[4], bfr[4];
      #pragma unroll
      for (int t = 0; t < 4; t++) {
        int ra = wm + t * 16 + ln15;
        af[t] = *(bf16x8*)&As[ra * 64 + (((s * 4 + quad) ^ (ra & 7)) * 8)];
        int rb = wn + t * 16 + ln15;
        bfr[t] = *(bf16x8*)&Bs[rb * 64 + (((s * 4 + quad) ^ (rb & 7)) * 8)];
      }
      #pragma unroll
      for (int mt = 0; mt < 4; mt++)
        #pragma unroll
        for (int nt = 0; nt < 4; nt++)
          acc[mt][nt] = mfma_bf16(af[mt], bfr[nt], acc[mt][nt]);
    }
    __syncthreads();
  }

  #pragma unroll
  for (int nt = 0; nt < 4; nt++) {
    int col = bn + wn + nt * 16 + ln15;
    float bv = ldx(sub_b, col, isbf);
    #pragma unroll
    for (int mt = 0; mt < 4; mt++) {
      #pragma unroll
      for (int r = 0; r < 4; r++) {
        int row = bm + wm + mt * 16 + quad * 4 + r;
        float v = acc[mt][nt][r] + bv;
        size_t o = (size_t)row * 1024 + col;
        if (isbf) ((bf16*)dout)[o] = __float2bfloat16(v);
        else      ((float*)dout)[o] = v;
      }
    }
  }
}

// ---------------------------------------------------------------------------
// G[row][r] = q_row . rel_emb[r] (bf16 q). One wave per row.
// ---------------------------------------------------------------------------
__global__ __launch_bounds__(256)
void qrel_k(const bf16* __restrict__ qbf, const void* __restrict__ rel_emb,
            float* __restrict__ G, const int* __restrict__ dflag)
{
  const int isbf = *dflag;
  __shared__ float rel[33][65];
  __shared__ float qw[4][64];
  const int tid = threadIdx.x;
  for (int i = tid; i < 33 * 64; i += 256)
    rel[i >> 6][i & 63] = ldx(rel_emb, i, isbf);
  const int wv = tid >> 6, lane = tid & 63;
  const size_t row = (size_t)blockIdx.x * 4 + wv;
  qw[wv][lane] = bf2f(qbf[row * 64 + lane]);
  __syncthreads();
  if (lane < 33) {
    float s = 0.f;
    #pragma unroll
    for (int d = 0; d < 64; d++) s += qw[wv][d] * rel[lane][d];
    G[row * 33 + lane] = s;
  }
}

// ---------------------------------------------------------------------------
// Fully fused main view v5 (round-8 verified): 32 rows/block, wave = (row
// group, k-half), acc[16], cross-wave softmax via LDS stats exchange.
// ---------------------------------------------------------------------------
__global__ __launch_bounds__(256, 2)
void score_fused_k(const bf16* __restrict__ qbf, const bf16* __restrict__ kbf,
                   const float* __restrict__ G, const bf16* __restrict__ vt,
                   const void* __restrict__ rel_emb, bf16* __restrict__ ctx,
                   void* __restrict__ dout, const int* __restrict__ dflag)
{
  __shared__ short P[32 * 512];       // 32 KB, normalized bf16 P
  __shared__ float gbuf[32 * 33];     // 4224 B
  __shared__ float relbuf[33 * 64];   // 8448 B
  __shared__ float smax[4][16];       // per-wave partial row max
  __shared__ float ssumS[4][16];      // per-wave partial row sums
  __shared__ float sleS[4][16];
  __shared__ float sgeS[4][16];
  const int tid = threadIdx.x;
  const int w = tid >> 6, ln = tid & 63;
  const int ln15 = ln & 15, quad = ln >> 4;
  const int rowg = (w >> 1) * 16;     // row group base (0 or 16)
  const int ch = w & 1;               // k-col half (0 or 1)
  const int bh = blockIdx.x, qt = blockIdx.y;
  const size_t qrow0 = (size_t)bh * 512 + qt * 32;
  const int isbf = *dflag;

  // stage G (32 rows) + rel into LDS (valid after barrier #1)
  for (int i = tid; i < 32 * 33; i += 256) {
    int r = i / 33, c = i - r * 33;
    gbuf[i] = G[(qrow0 + r) * 33 + c];
  }
  for (int i = tid; i < 33 * 64; i += 256)
    relbuf[i] = ldx(rel_emb, i, isbf);

  // ---- QK^T for my rows x my col-half: fragments straight from global ----
  const bf16* qrow = qbf + (qrow0 + rowg + ln15) * 64;
  bf16x8 af0 = *(const bf16x8*)(qrow + quad * 8);
  bf16x8 af1 = *(const bf16x8*)(qrow + 32 + quad * 8);
  const bf16* kb = kbf + (size_t)bh * 512 * 64;
  f32x4 acc[16];
  #pragma unroll
  for (int t = 0; t < 16; t++) acc[t] = (f32x4)(0.0f);
  #pragma unroll
  for (int t = 0; t < 16; t++) {
    const bf16* kr = kb + (size_t)(ch * 256 + t * 16 + ln15) * 64 + quad * 8;
    bf16x8 b0 = *(const bf16x8*)kr;
    bf16x8 b1 = *(const bf16x8*)(kr + 32);
    acc[t] = mfma_bf16(af0, b0, acc[t]);
    acc[t] = mfma_bf16(af1, b1, acc[t]);
  }
  __syncthreads();   // #1: gbuf/relbuf valid

  // ---- rel bias + partial row max over my half ----
  const int qg = qt * 32 + rowg + quad * 4;        // global q of row r=0
  const int rowl0 = rowg + quad * 4;               // local row base
  float mx[4], ssum[4], sle[4], sge[4], inv[4];
  #pragma unroll
  for (int r = 0; r < 4; r++) mx[r] = -3.0e38f;
  #pragma unroll
  for (int t = 0; t < 16; t++) {
    int k = ch * 256 + t * 16 + ln15;
    #pragma unroll
    for (int r = 0; r < 4; r++) {
      int delta = k - (qg + r);
      int bkt = delta < -16 ? 0 : (delta > 16 ? 32 : delta + 16);
      float s = acc[t][r] + gbuf[(rowl0 + r) * 33 + bkt];
      acc[t][r] = s;
      mx[r] = fmaxf(mx[r], s);
    }
  }
  #pragma unroll
  for (int r = 0; r < 4; r++) {
    float m = mx[r];
    #pragma unroll
    for (int off = 1; off < 16; off <<= 1) m = fmaxf(m, __shfl_xor(m, off));
    mx[r] = m;
  }
  if (ln15 == 0) {
    #pragma unroll
    for (int r = 0; r < 4; r++) smax[w][quad * 4 + r] = mx[r];
  }
  __syncthreads();   // #2: partner partial max visible
  #pragma unroll
  for (int r = 0; r < 4; r++) {
    mx[r] = fmaxf(mx[r], smax[w ^ 1][quad * 4 + r]);   // exact global max
    ssum[r] = 0.f; sle[r] = 0.f; sge[r] = 0.f;
  }

  // ---- exp + partial sums over my half ----
  #pragma unroll
  for (int t = 0; t < 16; t++) {
    int k = ch * 256 + t * 16 + ln15;
    #pragma unroll
    for (int r = 0; r < 4; r++) {
      float p = __expf(acc[t][r] - mx[r]);
      acc[t][r] = p;
      ssum[r] += p;
      int delta = k - (qg + r);
      if (delta <= -16) sle[r] += p;
      if (delta >= 16) sge[r] += p;
    }
  }
  #pragma unroll
  for (int r = 0; r < 4; r++) {
    #pragma unroll
    for (int off = 1; off < 16; off <<= 1) {
      ssum[r] += __shfl_xor(ssum[r], off);
      sle[r] += __shfl_xor(sle[r], off);
      sge[r] += __shfl_xor(sge[r], off);
    }
  }
  if (ln15 == 0) {
    #pragma unroll
    for (int r = 0; r < 4; r++) {
      ssumS[w][quad * 4 + r] = ssum[r];
      sleS[w][quad * 4 + r] = sle[r];
      sgeS[w][quad * 4 + r] = sge[r];
    }
  }
  __syncthreads();   // #3: partner partial sums visible
  #pragma unroll
  for (int r = 0; r < 4; r++) {
    float tot = ssum[r] + ssumS[w ^ 1][quad * 4 + r];
    sle[r] += sleS[w ^ 1][quad * 4 + r];
    sge[r] += sgeS[w ^ 1][quad * 4 + r];
    inv[r] = 1.f / tot;
  }

  // ---- store normalized P (my 16 rows x my 256 cols), XOR swizzle ----
  #pragma unroll
  for (int t2 = 0; t2 < 16; t2++) {
    int gg = t2 * 2 + (ln15 >> 3);          // group within my half, 0..31
    int slot = gg ^ (quad << 1);
    #pragma unroll
    for (int r = 0; r < 4; r++) {
      int rowL = rowl0 + r;
      P[rowL * 512 + ch * 256 + slot * 8 + (ln15 & 7)] =
          (short)f2us(acc[t2][r] * inv[r]);
    }
  }
  __syncthreads();   // #4: full P tile valid

  // ---- top_attn (head-0 blocks): all threads, 32 rows x 512 cols ----
  if ((bh & 15) == 0) {
    const int bg = bh >> 4;
    for (int i = tid; i < 32 * 64; i += 256) {
      int rowL = i >> 6, g = i & 63;
      int chg = g >> 5, gg = g & 31;
      int slot = gg ^ (((rowL >> 2) & 3) << 1);
      bf16x8 u = *(bf16x8*)&P[rowL * 512 + chg * 256 + slot * 8];
      size_t o = (size_t)4194304 + (size_t)bg * 262144 +
                 (size_t)(qt * 32 + rowL) * 512 + g * 8;
      if (isbf) {
        *(bf16x8*)((bf16*)dout + o) = u;
      } else {
        float4 f0 = make_float4(us2f((unsigned short)u[0]), us2f((unsigned short)u[1]),
                                us2f((unsigned short)u[2]), us2f((unsigned short)u[3]));
        float4 f1 = make_float4(us2f((unsigned short)u[4]), us2f((unsigned short)u[5]),
                                us2f((unsigned short)u[6]), us2f((unsigned short)u[7]));
        *(float4*)((float*)dout + o) = f0;
        *(float4*)((float*)dout + o + 4) = f1;
      }
    }
  }

  // ---- PV: my rows (rowg..+15) x my d-half (ch*32..+31), all 512 k ----
  const bf16* vb = vt + (size_t)bh * 64 * 512;
  f32x4 pacc[2];
  pacc[0] = (f32x4)(0.0f); pacc[1] = (f32x4)(0.0f);
  const int ra = rowg + ln15;
  const int rsw = ((ln15 >> 2) & 3) << 1;   // q2 of row ra
  #pragma unroll
  for (int h2 = 0; h2 < 2; h2++) {
    #pragma unroll
    for (int kk = 0; kk < 8; kk++) {
      int gg = kk * 4 + quad;
      bf16x8 a = *(bf16x8*)&P[ra * 512 + h2 * 256 + ((gg ^ rsw) * 8)];
      int k0 = h2 * 256 + kk * 32;
      #pragma unroll
      for (int nt2 = 0; nt2 < 2; nt2++) {
        int dcol = ch * 32 + nt2 * 16 + ln15;
        bf16x8 b = *(const bf16x8*)(vb + (size_t)dcol * 512 + k0 + quad * 8);
        pacc[nt2] = mfma_bf16(a, b, pacc[nt2]);
      }
    }
  }

  // ---- diagonal band of arel@rel (rel from LDS, normalized P from LDS) ----
  for (int rr = 1; rr < 32; rr++) {
    float av[4];
    #pragma unroll
    for (int r = 0; r < 4; r++) {
      int k = qg + r + rr - 16;
      av[r] = 0.f;
      if (k >= 0 && k < 512) {
        int g = k >> 3, chg = g >> 5, gg = g & 31;
        int slot = gg ^ (quad << 1);
        av[r] = us2f((unsigned short)P[(rowl0 + r) * 512 + chg * 256 +
                                       slot * 8 + (k & 7)]);
      }
    }
    #pragma unroll
    for (int nt2 = 0; nt2 < 2; nt2++) {
      float relv = relbuf[rr * 64 + ch * 32 + nt2 * 16 + ln15];
      #pragma unroll
      for (int r = 0; r < 4; r++) pacc[nt2][r] += av[r] * relv;
    }
  }

  // sle/sge terms (buckets 0 and 32)
  #pragma unroll
  for (int nt2 = 0; nt2 < 2; nt2++) {
    float r0v = relbuf[ch * 32 + nt2 * 16 + ln15];
    float r32v = relbuf[32 * 64 + ch * 32 + nt2 * 16 + ln15];
    #pragma unroll
    for (int r = 0; r < 4; r++)
      pacc[nt2][r] += sle[r] * inv[r] * r0v + sge[r] * inv[r] * r32v;
  }

  // ctx write (slot 0 layout [bl*512+s][1024]); my rows x my d-half
  const int bl = bh >> 4, head = bh & 15;
  #pragma unroll
  for (int r = 0; r < 4; r++) {
    int s = qt * 32 + rowl0 + r;
    #pragma unroll
    for (int nt2 = 0; nt2 < 2; nt2++)
      ctx[((size_t)bl * 512 + s) * 1024 + head * 64 + ch * 32 + nt2 * 16 + ln15] =
          __float2bfloat16(pacc[nt2][r]);
  }
}

// ---------------------------------------------------------------------------
// Edge h-projections, z-batched over 4 views (blockIdx.y).
// ---------------------------------------------------------------------------
__global__ __launch_bounds__(256)
void hv_k(const bf16* __restrict__ vt, const void* __restrict__ att_w,
          const void* __restrict__ att_b, float* __restrict__ h0,
          float* __restrict__ h1, const int* __restrict__ dflag)
{
  const int i0s[4] = {6, 0, 2, 4};
  const int i1s[4] = {7, 1, 3, 5};
  const int z = blockIdx.y;
  const int i0 = i0s[z], i1 = i1s[z];
  __shared__ float w0[64], w1[64];
  const int tid = threadIdx.x;
  const int bh = blockIdx.x;
  const int isbf = *dflag;
  if (tid < 64) {
    w0[tid] = ldx(att_w, i0 * 64 + tid, isbf);
    w1[tid] = ldx(att_w, i1 * 64 + tid, isbf);
  }
  __syncthreads();
  const bf16* vb = vt + (size_t)bh * 64 * 512 + tid * 2;
  float a00 = 0, a01 = 0, a10 = 0, a11 = 0;
  for (int d = 0; d < 64; d++) {
    ushort2 u = *(const ushort2*)(vb + (size_t)d * 512);
    float f0 = us2f(u.x), f1 = us2f(u.y);
    a00 += f0 * w0[d]; a10 += f1 * w0[d];
    a01 += f0 * w1[d]; a11 += f1 * w1[d];
  }
  float b0 = ldx(att_b, i0, isbf), b1 = ldx(att_b, i1, isbf);
  float* p0 = h0 + (size_t)z * 65536 + (size_t)bh * 512 + tid * 2;
  float* p1 = h1 + (size_t)z * 65536 + (size_t)bh * 512 + tid * 2;
  p0[0] = a00 + b0; p0[1] = a10 + b0;
  p1[0] = a01 + b1; p1[1] = a11 + b1;
}

// ---------------------------------------------------------------------------
// Fused edge view v3: phase 1 batches ALL 8 rows per wave for ILP.
// Round-9 post-mortem: phase 1 was latency-bound on ~16 serial 6-step
// __shfl_xor butterflies (ds_bpermute, ~30-60cy dependent latency each);
// VALU throughput floor is ~30us but kernel ran 150us. Restructure:
// compute masked-lrelu for all 8 rows into e[8][8] regs (compile-time
// indices, rule #20), then ONE batched butterfly for max (6 steps x 8
// independent chains) and one for sum; 64 exps issued as one batch.
// Per-row reduce order unchanged -> bit-identical results.
// ---------------------------------------------------------------------------
__global__ __launch_bounds__(256)
void edge_fused_k(const float* __restrict__ h0, const float* __restrict__ h1,
                  const unsigned char* __restrict__ maskp,
                  const bf16* __restrict__ vt, bf16* __restrict__ ctx5)
{
  __shared__ short P[32 * 512];   // 32 KB
  const int tid = threadIdx.x;
  const int w = tid >> 6, ln = tid & 63;
  const int ln15 = ln & 15, quad = ln >> 4;
  const int bh = blockIdx.x, qt = blockIdx.y, view = blockIdx.z;
  const int bl = bh >> 4;
  bf16* ctx = ctx5 + (size_t)(1 + view) * 4194304;

  // ---- phase 1: rows w*8 .. w*8+7, all 8 batched for ILP ----
  {
    const float* hjp = h1 + (size_t)view * 65536 + (size_t)bh * 512 + ln * 8;
    float4 hA = *(const float4*)hjp;
    float4 hB = *(const float4*)(hjp + 4);
    float hjv[8] = {hA.x, hA.y, hA.z, hA.w, hB.x, hB.y, hB.z, hB.w};
    const float* h0b = h0 + (size_t)view * 65536 + (size_t)bh * 512 + qt * 32 + w * 8;
    const unsigned char* mrow = maskp + (size_t)view * 262144 + (size_t)bl * 32768
                                + (size_t)(qt * 32 + w * 8) * 64 + ln;
    unsigned int mb[8];
    float hi[8];
    #pragma unroll
    for (int rr = 0; rr < 8; rr++) mb[rr] = mrow[rr * 64];
    #pragma unroll
    for (int rr = 0; rr < 8; rr++) hi[rr] = h0b[rr];

    float e[8][8];
    float mx[8], sm[8];
    #pragma unroll
    for (int rr = 0; rr < 8; rr++) {
      float m = -3.0e38f;
      #pragma unroll
      for (int j = 0; j < 8; j++) {
        float ej = hi[rr] + hjv[j];
        ej = ej >= 0.f ? ej : 0.01f * ej;
        e[rr][j] = ((mb[rr] >> j) & 1) ? ej : NEGV;
        m = fmaxf(m, e[rr][j]);
      }
      mx[rr] = m;
    }
    // batched butterfly max: 6 dependent steps, 8 independent chains
    #pragma unroll
    for (int off = 32; off; off >>= 1) {
      #pragma unroll
      for (int rr = 0; rr < 8; rr++)
        mx[rr] = fmaxf(mx[rr], __shfl_xor(mx[rr], off));
    }
    // exp batch + per-lane partial sums
    #pragma unroll
    for (int rr = 0; rr < 8; rr++) {
      float s = 0.f;
      #pragma unroll
      for (int j = 0; j < 8; j++) {
        e[rr][j] = __expf(e[rr][j] - mx[rr]);
        s += e[rr][j];
      }
      sm[rr] = s;
    }
    // batched butterfly sum
    #pragma unroll
    for (int off = 32; off; off >>= 1) {
      #pragma unroll
      for (int rr = 0; rr < 8; rr++)
        sm[rr] += __shfl_xor(sm[rr], off);
    }
    // normalize + store (verified swizzle: group ln ^ (r&7))
    #pragma unroll
    for (int rr = 0; rr < 8; rr++) {
      float inv = 1.f / sm[rr];
      int r = w * 8 + rr;
      bf16x8 pv;
      #pragma unroll
      for (int j = 0; j < 8; j++) pv[j] = (short)f2us(e[rr][j] * inv);
      *(bf16x8*)&P[r * 512 + ((ln ^ (r & 7)) * 8)] = pv;
    }
  }
  __syncthreads();

  // ---- phase 2: ctx[rows, d] = P @ V^T, V straight from global ----
  const bf16* vb = vt + (size_t)bh * 64 * 512;
  const int m0 = (w >> 1) * 16, d0 = (w & 1) * 32;
  f32x4 acc[2];
  acc[0] = (f32x4)(0.0f); acc[1] = (f32x4)(0.0f);

  const int ra = m0 + ln15;
  const int rsw = ra & 7;
  #pragma unroll 4
  for (int k0 = 0; k0 < 512; k0 += 32) {
    int gsel = (k0 >> 3) + quad;
    bf16x8 a = *(bf16x8*)&P[ra * 512 + ((gsel ^ rsw) * 8)];
    #pragma unroll
    for (int nt = 0; nt < 2; nt++) {
      bf16x8 b = *(const bf16x8*)(vb + (size_t)(d0 + nt * 16 + ln15) * 512 + k0 + quad * 8);
      acc[nt] = mfma_bf16(a, b, acc[nt]);
    }
  }

  const int head = bh & 15;
  #pragma unroll
  for (int r = 0; r < 4; r++) {
    int s = qt * 32 + m0 + quad * 4 + r;
    #pragma unroll
    for (int nt = 0; nt < 2; nt++)
      ctx[((size_t)bl * 512 + s) * 1024 + head * 64 + d0 + nt * 16 + ln15] =
          __float2bfloat16(acc[nt][r]);
  }
}

// ---------------------------------------------------------------------------
extern "C" void kernel_launch(void* const* d_in, const int* in_sizes, int n_in,
                              void* d_out, int out_size, void* d_ws, size_t ws_size,
                              hipStream_t stream)
{
  const void* key   = d_in[0];
  const void* value = d_in[1];
  const void* query = d_in[2];
  const int*  grh   = (const int*)d_in[3];
  const void* Wq = d_in[5];
  const void* bq = d_in[6];
  const void* Wk = d_in[7];
  const void* bk = d_in[8];
  const void* Wv = d_in[9];
  const void* bv = d_in[10];
  const void* rel_emb = d_in[11];
  const void* att_w = d_in[12];
  const void* att_b = d_in[13];
  const void* gate_w = d_in[14];
  const void* gate_b = d_in[15];
  const void* sub_w = d_in[16];
  const void* sub_b = d_in[17];

  // workspace layout (floats) — ~131 MB incl. mask planes + qkvb
  int* dflag = (int*)d_ws;
  float* base = (float*)d_ws;
  bf16* qbf = (bf16*)(base + 16);
  bf16* kbf = (bf16*)(base + 16 + 2097152);
  bf16* vtb = (bf16*)(base + 16 + 2 * 2097152);
  bf16* Wt  = (bf16*)(base + 16 + 3 * 2097152);
  float* G  = base + 16 + 3 * 2097152 + 6815744;
  float* h0 = G + 2162688;
  float* h1 = h0 + 262144;
  bf16* ctx5   = (bf16*)(h1 + 262144);
  bf16* gated5 = ctx5 + 5ull * 4194304;
  unsigned char* maskp = (unsigned char*)(gated5 + 5ull * 4194304);
  bf16* qkvb = (bf16*)(maskp + 1048576);

  detect_k<<<dim3(1), dim3(64), 0, stream>>>(Wq, dflag);

  // pack grh -> 1 MB of per-view adjacency bit-planes (read grh ONCE)
  mask_pack_k<<<dim3(1024), dim3(256), 0, stream>>>(grh, maskp);

  // convert q/k/v inputs -> bf16 (enables async LDS staging in qkv GEMM)
  cvt_k<<<dim3(2048, 3), dim3(256), 0, stream>>>(query, key, value, qkvb, dflag);

  // all 13 weight transposes in one launch
  wtrans_all_k<<<dim3(13 * 256), dim3(256), 0, stream>>>(
      Wq, Wk, Wv, gate_w, sub_w, Wt, dflag);

  // QKV projections batched (z: 0=q scaled, 1=k, 2=v transposed)
  qkv_gemm_k<<<dim3(32, 8, 3), dim3(256), 0, stream>>>(
      qkvb, Wt, bq, bk, bv, qbf, kbf, vtb, dflag);

  qrel_k<<<dim3(16384), dim3(256), 0, stream>>>(qbf, rel_emb, G, dflag);

  // main view fully fused -> ctx5 slot 0 (+ top_attn to d_out)
  score_fused_k<<<dim3(128, 16), dim3(256), 0, stream>>>(
      qbf, kbf, G, vtb, rel_emb, ctx5, d_out, dflag);

  // edge views: h projections (4 views batched), then fused softmax+PV
  hv_k<<<dim3(128, 4), dim3(256), 0, stream>>>(vtb, att_w, att_b, h0, h1, dflag);
  edge_fused_k<<<dim3(128, 16, 4), dim3(256), 0, stream>>>(
      h0, h1, maskp, vtb, ctx5);

  // 5 gate GEMMs batched, then one K=5120 sub GEMM straight to d_out
  gate_gemm_k<<<dim3(32, 8, 5), dim3(256), 0, stream>>>(
      ctx5, Wt, gate_b, gated5, dflag);
  sub_gemm_k<<<dim3(32, 8), dim3(256), 0, stream>>>(
      gated5, Wt, sub_b, d_out, dflag);
}